// Round 1
// baseline (49002.527 us; speedup 1.0000x reference)
//
#include <hip/hip_runtime.h>
#include <math.h>

#define NNODE 1024
#define BATCH 16
#define NB    16384   // NNODE*BATCH
#define TT    12

static inline int cdiv(int a, int b) { return (a + b - 1) / b; }

// ---------------------------------------------------------------------------
// GEMM (fp32): C[M,N] = A[M,K] @ B[K,N]; lda=K, ldb=ldc=N.
// 128x128 tile, BK=8, 256 threads, 8x8 per thread (2x2 of 4x4 subtiles).
// blockIdx.z batches independent GEMMs via element strides sA/sB/sC.
// M % 128 == 0, K % 8 == 0, N % 16 == 0 (edges in N handled by guards).
// ---------------------------------------------------------------------------
__global__ __launch_bounds__(256) void gemm_g(
    const float* __restrict__ Ag, const float* __restrict__ Bg, float* __restrict__ Cg,
    int M, int N, int K, long sA, long sB, long sC)
{
    const float* A = Ag + (long)blockIdx.z * sA;
    const float* B = Bg + (long)blockIdx.z * sB;
    float*       C = Cg + (long)blockIdx.z * sC;

    __shared__ float As[8][128];
    __shared__ float Bs[8][128];

    const int bn = blockIdx.x * 128;
    const int bm = blockIdx.y * 128;
    const int tid = threadIdx.x;
    const int tx = tid & 15, ty = tid >> 4;

    const int am = tid >> 1, ak = (tid & 1) * 4;
    const int bk = tid >> 5, bnn = (tid & 31) * 4;

    const float* Aload = A + (long)(bm + am) * K + ak;
    const float* Bload = B + (long)bk * N + bn + bnn;
    const bool bvalid = (bn + bnn) < N;

    float acc[8][8];
#pragma unroll
    for (int i = 0; i < 8; ++i)
#pragma unroll
        for (int j = 0; j < 8; ++j) acc[i][j] = 0.f;

    for (int k0 = 0; k0 < K; k0 += 8) {
        float4 av = *(const float4*)(Aload + k0);
        float4 bv = make_float4(0.f, 0.f, 0.f, 0.f);
        if (bvalid) bv = *(const float4*)(Bload + (long)k0 * N);

        As[ak + 0][am] = av.x;
        As[ak + 1][am] = av.y;
        As[ak + 2][am] = av.z;
        As[ak + 3][am] = av.w;
        *(float4*)&Bs[bk][bnn] = bv;
        __syncthreads();

#pragma unroll
        for (int k = 0; k < 8; ++k) {
            float a[8], b[8];
            *(float4*)&a[0] = *(const float4*)&As[k][ty * 4];
            *(float4*)&a[4] = *(const float4*)&As[k][64 + ty * 4];
            *(float4*)&b[0] = *(const float4*)&Bs[k][tx * 4];
            *(float4*)&b[4] = *(const float4*)&Bs[k][64 + tx * 4];
#pragma unroll
            for (int i = 0; i < 8; ++i)
#pragma unroll
                for (int j = 0; j < 8; ++j) acc[i][j] += a[i] * b[j];
        }
        __syncthreads();
    }

#pragma unroll
    for (int ri = 0; ri < 2; ++ri)
#pragma unroll
        for (int i = 0; i < 4; ++i) {
            int row = bm + ri * 64 + ty * 4 + i;
            float* Cr = C + (long)row * N;
#pragma unroll
            for (int rj = 0; rj < 2; ++rj) {
                int col = bn + rj * 64 + tx * 4;
                if (col < N) {
                    float4 o = make_float4(acc[ri * 4 + i][rj * 4 + 0],
                                           acc[ri * 4 + i][rj * 4 + 1],
                                           acc[ri * 4 + i][rj * 4 + 2],
                                           acc[ri * 4 + i][rj * 4 + 3]);
                    *(float4*)(Cr + col) = o;
                }
            }
        }
}

// ---------------------------------------------------------------------------
// GEMM-W (fp32): C[16384, N] = A_slots[16384, K=5c] @ Bw[K, N] + bias, epilogue.
// A is 5 concatenated slot matrices: A[r, kk] = slots[(kk/c)*16384c + r*c + kk%c].
// 128x64 tile, BK=8, 256 threads, 8x4 per thread. EPI: 1=sigmoid, 2=tanh.
// ---------------------------------------------------------------------------
template <int EPI>
__global__ __launch_bounds__(256) void gemm_w(
    const float* __restrict__ A, const float* __restrict__ Bw, float* __restrict__ C,
    int c, int K, int N, const float* __restrict__ bias)
{
    __shared__ float As[8][128];
    __shared__ float Bs[8][64];

    const long sliceStride = (long)NB * c;
    const int bn = blockIdx.x * 64;
    const int bm = blockIdx.y * 128;
    const int tid = threadIdx.x;
    const int tx = tid & 15, ty = tid >> 4;

    const int am = tid >> 1, ak = (tid & 1) * 4;
    const float* Abase = A + (long)(bm + am) * c;
    int kk = ak;         // global k of first of this thread's 4 A elements
    int s = 0, ccur = ak; // kk = s*c + ccur (c >= 65 > 8 so no initial wrap)

    const int bk = tid >> 5, bn2 = (tid & 31) * 2;

    float acc[8][4];
#pragma unroll
    for (int i = 0; i < 8; ++i)
#pragma unroll
        for (int j = 0; j < 4; ++j) acc[i][j] = 0.f;

    const int ktiles = (K + 7) / 8;
    for (int kt = 0; kt < ktiles; ++kt) {
        int ss = s, cx = ccur;
#pragma unroll
        for (int i = 0; i < 4; ++i) {
            float v = 0.f;
            if (kk + i < K) v = Abase[(long)ss * sliceStride + cx];
            As[ak + i][am] = v;
            cx++;
            if (cx == c) { cx = 0; ss++; }
        }
        kk += 8;
        ccur += 8;
        if (ccur >= c) { ccur -= c; s++; }

        int kb = kt * 8 + bk;
        float2 bv = make_float2(0.f, 0.f);
        if (kb < K) bv = *(const float2*)(Bw + (long)kb * N + bn + bn2);
        Bs[bk][bn2] = bv.x;
        Bs[bk][bn2 + 1] = bv.y;
        __syncthreads();

#pragma unroll
        for (int k = 0; k < 8; ++k) {
            float a0[4], a1[4], b0[4];
            *(float4*)&a0[0] = *(const float4*)&As[k][ty * 4];
            *(float4*)&a1[0] = *(const float4*)&As[k][64 + ty * 4];
            *(float4*)&b0[0] = *(const float4*)&Bs[k][tx * 4];
#pragma unroll
            for (int i = 0; i < 4; ++i)
#pragma unroll
                for (int j = 0; j < 4; ++j) {
                    acc[i][j] += a0[i] * b0[j];
                    acc[4 + i][j] += a1[i] * b0[j];
                }
        }
        __syncthreads();
    }

#pragma unroll
    for (int ri = 0; ri < 2; ++ri)
#pragma unroll
        for (int i = 0; i < 4; ++i) {
            int row = bm + ri * 64 + ty * 4 + i;
            float* Cr = C + (long)row * N + bn + tx * 4;
            float4 o;
            float v0 = acc[ri * 4 + i][0] + bias[bn + tx * 4 + 0];
            float v1 = acc[ri * 4 + i][1] + bias[bn + tx * 4 + 1];
            float v2 = acc[ri * 4 + i][2] + bias[bn + tx * 4 + 2];
            float v3 = acc[ri * 4 + i][3] + bias[bn + tx * 4 + 3];
            if (EPI == 1) {
                v0 = 1.f / (1.f + expf(-v0));
                v1 = 1.f / (1.f + expf(-v1));
                v2 = 1.f / (1.f + expf(-v2));
                v3 = 1.f / (1.f + expf(-v3));
            } else {
                v0 = tanhf(v0); v1 = tanhf(v1); v2 = tanhf(v2); v3 = tanhf(v3);
            }
            o = make_float4(v0, v1, v2, v3);
            *(float4*)Cr = o;
        }
}

// ---------------------------------------------------------------------------
// ne1 = We1 @ Memory, ne2 = We2 @ Memory   (1024x20 @ 20x64)
// ---------------------------------------------------------------------------
__global__ __launch_bounds__(256) void compute_ne(
    const float* __restrict__ We1, const float* __restrict__ We2,
    const float* __restrict__ Mem, float* __restrict__ ne1, float* __restrict__ ne2)
{
    int idx = blockIdx.x * 256 + threadIdx.x;
    if (idx >= 2 * 65536) return;
    int which = idx >> 16;
    int i = idx & 65535;
    int n = i >> 6, d = i & 63;
    const float* We = which ? We2 : We1;
    float acc = 0.f;
#pragma unroll
    for (int k = 0; k < 20; ++k) acc += We[n * 20 + k] * Mem[k * 64 + d];
    (which ? ne2 : ne1)[i] = acc;
}

// ---------------------------------------------------------------------------
// g rows: row<1024 -> g1[n,:] = softmax(relu(ne1[n]·ne2^T)); else g2 (ne2·ne1^T)
// one block (256 thr) per row
// ---------------------------------------------------------------------------
__global__ __launch_bounds__(256) void build_g(
    const float* __restrict__ ne1, const float* __restrict__ ne2, float* __restrict__ g)
{
    int row = blockIdx.x;
    int n = row & 1023;
    const float* qa = (row < 1024) ? ne1 : ne2;
    const float* kb = (row < 1024) ? ne2 : ne1;

    __shared__ float q[64];
    __shared__ float sc[1024];
    __shared__ float red[256];
    int tid = threadIdx.x;
    if (tid < 64) q[tid] = qa[n * 64 + tid];
    __syncthreads();

    for (int m = tid; m < 1024; m += 256) {
        float acc = 0.f;
        const float* kr = kb + m * 64;
#pragma unroll 8
        for (int d = 0; d < 64; ++d) acc += q[d] * kr[d];
        sc[m] = fmaxf(acc, 0.f);
    }
    __syncthreads();

    float mx = -1e30f;
    for (int m = tid; m < 1024; m += 256) mx = fmaxf(mx, sc[m]);
    red[tid] = mx;
    __syncthreads();
    for (int s2 = 128; s2 > 0; s2 >>= 1) {
        if (tid < s2) red[tid] = fmaxf(red[tid], red[tid + s2]);
        __syncthreads();
    }
    mx = red[0];
    __syncthreads();

    float sum = 0.f;
    for (int m = tid; m < 1024; m += 256) {
        float e = expf(sc[m] - mx);
        sc[m] = e;
        sum += e;
    }
    red[tid] = sum;
    __syncthreads();
    for (int s2 = 128; s2 > 0; s2 >>= 1) {
        if (tid < s2) red[tid] += red[tid + s2];
        __syncthreads();
    }
    float inv = 1.f / red[0];
    for (int m = tid; m < 1024; m += 256) g[(long)row * 1024 + m] = sc[m] * inv;
}

// ---------------------------------------------------------------------------
// Effective weights: src W is (6c x cout); dst (5c x cout), slot order
// [X, Y1, Z1, Y2, Z2] -> [W0+W3-W2-W5, W1, W4, 2W2, 2W5]
// ---------------------------------------------------------------------------
__global__ __launch_bounds__(256) void build_weff(
    const float* __restrict__ W, float* __restrict__ dst, int c, int cout)
{
    int idx = blockIdx.x * 256 + threadIdx.x;
    if (idx >= 5 * c * cout) return;
    int rowk = idx / cout, col = idx % cout;
    int s = rowk / c, i = rowk % c;
    float v;
    if (s == 0)
        v = W[(0 * c + i) * cout + col] + W[(3 * c + i) * cout + col]
          - W[(2 * c + i) * cout + col] - W[(5 * c + i) * cout + col];
    else if (s == 1) v = W[(1 * c + i) * cout + col];
    else if (s == 2) v = W[(4 * c + i) * cout + col];
    else if (s == 3) v = 2.f * W[(2 * c + i) * cout + col];
    else             v = 2.f * W[(5 * c + i) * cout + col];
    dst[idx] = v;
}

// ---------------------------------------------------------------------------
// Build concat input into slot0, layout (n, b, cc) flat = (n*16+b)*C + cc.
// Modes: 0/1 enc0 (c=65), 2/3 enc1 (c=128), 4/5 dec0 (c=130), 6/7 dec1 (c=256)
// odd mode = update-path (multiply h by gate z from zr)
// ---------------------------------------------------------------------------
template <int MODE>
__global__ __launch_bounds__(256) void build_xcat(
    float* __restrict__ dst, const float* __restrict__ s1, const float* __restrict__ s2,
    const float* __restrict__ h, const float* __restrict__ zr, int t)
{
    constexpr int C = (MODE < 2) ? 65 : (MODE < 4) ? 128 : (MODE < 6) ? 130 : 256;
    int idx = blockIdx.x * 256 + threadIdx.x;
    if (idx >= NB * C) return;
    int r = idx / C, cc = idx % C;
    int n = r >> 4, b = r & 15;
    float v;
    if (MODE == 0 || MODE == 1) {
        if (cc == 0) v = s1[((long)b * TT + t) * NNODE + n];
        else {
            float hv = h[(long)r * 64 + cc - 1];
            v = (MODE == 1) ? zr[(long)r * 128 + cc - 1] * hv : hv;
        }
    } else if (MODE == 2 || MODE == 3) {
        if (cc < 64) v = s1[(long)r * 64 + cc];
        else {
            float hv = h[(long)r * 64 + cc - 64];
            v = (MODE == 3) ? zr[(long)r * 128 + cc - 64] * hv : hv;
        }
    } else if (MODE == 4 || MODE == 5) {
        if (cc == 0) v = s1[r];
        else if (cc == 1) v = s2[((long)b * TT + t) * NNODE + n];
        else {
            float hv = h[(long)r * 128 + cc - 2];
            v = (MODE == 5) ? zr[(long)r * 256 + cc - 2] * hv : hv;
        }
    } else {
        if (cc < 128) v = s1[(long)r * 128 + cc];
        else {
            float hv = h[(long)r * 128 + cc - 128];
            v = (MODE == 7) ? zr[(long)r * 256 + cc - 128] * hv : hv;
        }
    }
    dst[idx] = v;
}

// h = r*h + (1-r)*hc, r = zr[..., H:2H]
template <int H>
__global__ __launch_bounds__(256) void gru_update(
    float* __restrict__ h, const float* __restrict__ zr, const float* __restrict__ hc)
{
    int idx = blockIdx.x * 256 + threadIdx.x;
    if (idx >= NB * H) return;
    int r = idx / H, i = idx % H;
    float rg = zr[(long)r * 2 * H + H + i];
    h[idx] = rg * h[idx] + (1.f - rg) * hc[idx];
}

// memory attention: htc[r,0:64]=h, htc[r,64:128]=softmax(hWq·Mem^T)@Mem
__global__ __launch_bounds__(64) void attention(
    const float* __restrict__ h, const float* __restrict__ Wq,
    const float* __restrict__ Mem, float* __restrict__ htc)
{
    int r = blockIdx.x;
    int j = threadIdx.x;
    __shared__ float hr[64], q[64], sc[20];
    hr[j] = h[(long)r * 64 + j];
    __syncthreads();
    float acc = 0.f;
#pragma unroll 8
    for (int i = 0; i < 64; ++i) acc += hr[i] * Wq[i * 64 + j];
    q[j] = acc;
    __syncthreads();
    if (j < 20) {
        float a = 0.f;
#pragma unroll 8
        for (int d = 0; d < 64; ++d) a += q[d] * Mem[j * 64 + d];
        sc[j] = a;
    }
    __syncthreads();
    if (j == 0) {
        float mx = sc[0];
        for (int m = 1; m < 20; ++m) mx = fmaxf(mx, sc[m]);
        float s = 0.f;
        for (int m = 0; m < 20; ++m) { sc[m] = expf(sc[m] - mx); s += sc[m]; }
        float inv = 1.f / s;
        for (int m = 0; m < 20; ++m) sc[m] *= inv;
    }
    __syncthreads();
    float v = 0.f;
#pragma unroll
    for (int m = 0; m < 20; ++m) v += sc[m] * Mem[m * 64 + j];
    htc[(long)r * 128 + j] = hr[j];
    htc[(long)r * 128 + 64 + j] = v;
}

// go[r] = h1[r,:]·pw + pb; also scatter into output (B,T,N,1)
__global__ __launch_bounds__(256) void proj_out(
    const float* __restrict__ h1, const float* __restrict__ pw, const float* __restrict__ pb,
    float* __restrict__ go, float* __restrict__ out, int t)
{
    int r = blockIdx.x * 256 + threadIdx.x;
    if (r >= NB) return;
    float acc = pb[0];
    const float* hr = h1 + (long)r * 128;
#pragma unroll 8
    for (int i = 0; i < 128; ++i) acc += hr[i] * pw[i];
    go[r] = acc;
    int n = r >> 4, b = r & 15;
    out[((long)b * TT + t) * NNODE + n] = acc;
}

// ---------------------------------------------------------------------------
// Host orchestration
// ---------------------------------------------------------------------------
static void agcn_chain(const float* g, float* slots, int c,
                       const float* weff, const float* bias, int cout, int epi,
                       float* outbuf, hipStream_t stream)
{
    const int Ncols = BATCH * c;
    const long slotStride = (long)NB * c;

    // [Y1; Z1] = [g1; g2] @ X  -> slots 1,2 (contiguous 2048 rows)
    dim3 grid1(cdiv(Ncols, 128), 16, 1);
    gemm_g<<<grid1, 256, 0, stream>>>(g, slots, slots + slotStride,
                                      2048, Ncols, 1024, 0, 0, 0);
    // Y2 = g1 @ Y1 (z=0), Z2 = g2 @ Z1 (z=1) -> slots 3,4
    dim3 grid2(cdiv(Ncols, 128), 8, 2);
    gemm_g<<<grid2, 256, 0, stream>>>(g, slots + slotStride, slots + 3 * slotStride,
                                      1024, Ncols, 1024,
                                      (long)1024 * 1024, slotStride, slotStride);
    // out = slots @ Weff + bias, epilogue
    dim3 grid3(cout / 64, 128, 1);
    if (epi == 1)
        gemm_w<1><<<grid3, 256, 0, stream>>>(slots, weff, outbuf, c, 5 * c, cout, bias);
    else
        gemm_w<2><<<grid3, 256, 0, stream>>>(slots, weff, outbuf, c, 5 * c, cout, bias);
}

extern "C" void kernel_launch(void* const* d_in, const int* in_sizes, int n_in,
                              void* d_out, int out_size, void* d_ws, size_t ws_size,
                              hipStream_t stream)
{
    const float* x       = (const float*)d_in[0];
    const float* y_cov   = (const float*)d_in[1];
    const float* Memory  = (const float*)d_in[2];
    const float* Wq      = (const float*)d_in[3];
    const float* We1     = (const float*)d_in[4];
    const float* We2     = (const float*)d_in[5];
    const float* e0gw    = (const float*)d_in[6];
    const float* e0gb    = (const float*)d_in[7];
    const float* e0uw    = (const float*)d_in[8];
    const float* e0ub    = (const float*)d_in[9];
    const float* e1gw    = (const float*)d_in[10];
    const float* e1gb    = (const float*)d_in[11];
    const float* e1uw    = (const float*)d_in[12];
    const float* e1ub    = (const float*)d_in[13];
    const float* d0gw    = (const float*)d_in[14];
    const float* d0gb    = (const float*)d_in[15];
    const float* d0uw    = (const float*)d_in[16];
    const float* d0ub    = (const float*)d_in[17];
    const float* d1gw    = (const float*)d_in[18];
    const float* d1gb    = (const float*)d_in[19];
    const float* d1uw    = (const float*)d_in[20];
    const float* d1ub    = (const float*)d_in[21];
    const float* proj_w  = (const float*)d_in[22];
    const float* proj_b  = (const float*)d_in[23];
    float* out = (float*)d_out;

    float* ws = (float*)d_ws;
    size_t off = 0;
    auto alloc = [&](size_t nel) { float* p = ws + off; off += nel; return p; };

    float* g    = alloc(2L * 1024 * 1024);
    float* ne1  = alloc(65536);
    float* ne2  = alloc(65536);
    float* we0g = alloc(5 * 65 * 128);
    float* we0u = alloc(5 * 65 * 64);
    float* we1g = alloc(5 * 128 * 128);
    float* we1u = alloc(5 * 128 * 64);
    float* wd0g = alloc(5 * 130 * 256);
    float* wd0u = alloc(5 * 130 * 128);
    float* wd1g = alloc(5 * 256 * 256);
    float* wd1u = alloc(5 * 256 * 128);
    float* slots = alloc(5L * NB * 256);
    float* zr   = alloc((long)NB * 256);
    float* hc   = alloc((long)NB * 128);
    float* h0e  = alloc((long)NB * 64);
    float* h1e  = alloc((long)NB * 64);
    float* htc  = alloc((long)NB * 128);
    float* dh0  = alloc((long)NB * 128);
    float* dh1  = alloc((long)NB * 128);
    float* gob  = alloc(NB);
    (void)ws_size; (void)in_sizes; (void)n_in; (void)out_size;

    // ---- setup ----
    compute_ne<<<cdiv(2 * 65536, 256), 256, 0, stream>>>(We1, We2, Memory, ne1, ne2);
    build_g<<<2048, 256, 0, stream>>>(ne1, ne2, g);
    build_weff<<<cdiv(5 * 65 * 128, 256), 256, 0, stream>>>(e0gw, we0g, 65, 128);
    build_weff<<<cdiv(5 * 65 * 64, 256), 256, 0, stream>>>(e0uw, we0u, 65, 64);
    build_weff<<<cdiv(5 * 128 * 128, 256), 256, 0, stream>>>(e1gw, we1g, 128, 128);
    build_weff<<<cdiv(5 * 128 * 64, 256), 256, 0, stream>>>(e1uw, we1u, 128, 64);
    build_weff<<<cdiv(5 * 130 * 256, 256), 256, 0, stream>>>(d0gw, wd0g, 130, 256);
    build_weff<<<cdiv(5 * 130 * 128, 256), 256, 0, stream>>>(d0uw, wd0u, 130, 128);
    build_weff<<<cdiv(5 * 256 * 256, 256), 256, 0, stream>>>(d1gw, wd1g, 256, 256);
    build_weff<<<cdiv(5 * 256 * 128, 256), 256, 0, stream>>>(d1uw, wd1u, 256, 128);

    hipMemsetAsync(h0e, 0, (long)NB * 64 * sizeof(float), stream);
    hipMemsetAsync(h1e, 0, (long)NB * 64 * sizeof(float), stream);

    // ---- encoder (two layers interleaved per timestep) ----
    for (int t = 0; t < TT; ++t) {
        // layer 0 (c=65, hid=64)
        build_xcat<0><<<cdiv(NB * 65, 256), 256, 0, stream>>>(slots, x, nullptr, h0e, nullptr, t);
        agcn_chain(g, slots, 65, we0g, e0gb, 128, 1, zr, stream);
        build_xcat<1><<<cdiv(NB * 65, 256), 256, 0, stream>>>(slots, x, nullptr, h0e, zr, t);
        agcn_chain(g, slots, 65, we0u, e0ub, 64, 2, hc, stream);
        gru_update<64><<<cdiv(NB * 64, 256), 256, 0, stream>>>(h0e, zr, hc);
        // layer 1 (c=128, hid=64)
        build_xcat<2><<<cdiv(NB * 128, 256), 256, 0, stream>>>(slots, h0e, nullptr, h1e, nullptr, t);
        agcn_chain(g, slots, 128, we1g, e1gb, 128, 1, zr, stream);
        build_xcat<3><<<cdiv(NB * 128, 256), 256, 0, stream>>>(slots, h0e, nullptr, h1e, zr, t);
        agcn_chain(g, slots, 128, we1u, e1ub, 64, 2, hc, stream);
        gru_update<64><<<cdiv(NB * 64, 256), 256, 0, stream>>>(h1e, zr, hc);
    }

    // ---- memory attention ----
    attention<<<NB, 64, 0, stream>>>(h1e, Wq, Memory, htc);
    hipMemcpyAsync(dh0, htc, (long)NB * 128 * sizeof(float), hipMemcpyDeviceToDevice, stream);
    hipMemcpyAsync(dh1, htc, (long)NB * 128 * sizeof(float), hipMemcpyDeviceToDevice, stream);
    hipMemsetAsync(gob, 0, NB * sizeof(float), stream);

    // ---- decoder ----
    for (int t = 0; t < TT; ++t) {
        // dec0 (c=130, hid=128)
        build_xcat<4><<<cdiv(NB * 130, 256), 256, 0, stream>>>(slots, gob, y_cov, dh0, nullptr, t);
        agcn_chain(g, slots, 130, wd0g, d0gb, 256, 1, zr, stream);
        build_xcat<5><<<cdiv(NB * 130, 256), 256, 0, stream>>>(slots, gob, y_cov, dh0, zr, t);
        agcn_chain(g, slots, 130, wd0u, d0ub, 128, 2, hc, stream);
        gru_update<128><<<cdiv(NB * 128, 256), 256, 0, stream>>>(dh0, zr, hc);
        // dec1 (c=256, hid=128)
        build_xcat<6><<<cdiv(NB * 256, 256), 256, 0, stream>>>(slots, dh0, nullptr, dh1, nullptr, t);
        agcn_chain(g, slots, 256, wd1g, d1gb, 256, 1, zr, stream);
        build_xcat<7><<<cdiv(NB * 256, 256), 256, 0, stream>>>(slots, dh0, nullptr, dh1, zr, t);
        agcn_chain(g, slots, 256, wd1u, d1ub, 128, 2, hc, stream);
        gru_update<128><<<cdiv(NB * 128, 256), 256, 0, stream>>>(dh1, zr, hc);
        // projection + output scatter
        proj_out<<<cdiv(NB, 256), 256, 0, stream>>>(dh1, proj_w, proj_b, gob, out, t);
    }
}

// Round 2
// 20176.149 us; speedup vs baseline: 2.4287x; 2.4287x over previous
//
#include <hip/hip_runtime.h>
#include <math.h>

#define NNODE 1024
#define BATCH 16
#define NB    16384
#define TT    12

typedef __bf16 bf16x8 __attribute__((ext_vector_type(8)));
typedef float  f32x4  __attribute__((ext_vector_type(4)));

static inline int cdiv(int a, int b) { return (a + b - 1) / b; }

// ---------------------------------------------------------------------------
// async global->LDS, 16B per lane, wave-uniform LDS base + lane*16
// ---------------------------------------------------------------------------
__device__ inline void gll16(const void* g, void* l) {
    __builtin_amdgcn_global_load_lds(
        (const __attribute__((address_space(1))) void*)g,
        (__attribute__((address_space(3))) void*)l, 16, 0, 0);
}

// ---------------------------------------------------------------------------
// Split-bf16 GEMM:  D[i][j] = sum_k A[i][k]*B[j][k]  (both operands k-contig,
// i.e. D = A * B^T with A:[M][lda], B:[N][ldb] row-major), 3-pass hi/lo split.
// BM=128, BK=32, 256 threads = 4 waves (2x2), MFMA 16x16x32 bf16.
// EPI 0: split store bf16 hi/lo (Ch/Cl);  1: +bias,sigmoid->Cf;  2: +bias,tanh->Cf
// grid.z batches via element strides zA/zB/zC. nsplit/splitAdd: column-region
// relocation for j>=nsplit (hop1 writes Y1/Z1 into separate T regions).
// ---------------------------------------------------------------------------
template<int BN, int EPI>
__global__ __launch_bounds__(256) void mm_kern(
    const __bf16* __restrict__ Ah, const __bf16* __restrict__ Al, long lda, long zA,
    const __bf16* __restrict__ Bh, const __bf16* __restrict__ Bl, long zB, long ldb,
    int M, int Ksteps,
    __bf16* __restrict__ Ch, __bf16* __restrict__ Cl, float* __restrict__ Cf,
    long ldc, long zC, int nsplit, long splitAdd, const float* __restrict__ bias)
{
    constexpr int WN = BN / 2;          // wave tile cols
    constexpr int NF = WN / 16;         // n-frags per wave (4 or 2)
    constexpr int NP = (BN == 128) ? 8 : 6;  // staging chunks per wave
    // LDS element layout: AH[4][128][8] | AL | BH[4][BN][8] | BL
    __shared__ __bf16 smem[8192 + BN * 64];

    const int bm = blockIdx.y * 128, bn = blockIdx.x * BN;
    const int tid = threadIdx.x, w = tid >> 6, lane = tid & 63;
    const int wr = w >> 1, wc = w & 1;
    const int lgrp = lane >> 4, lrow = lane & 15;

    Ah += (size_t)blockIdx.z * zA;  Al += (size_t)blockIdx.z * zA;
    Bh += (size_t)blockIdx.z * zB;  Bl += (size_t)blockIdx.z * zB;

    const __bf16* sp[NP];
    char* dp[NP];
#pragma unroll
    for (int p = 0; p < NP; ++p) {
        int q = p * 4 + w;
        int tile, qq;
        if (BN == 128) { tile = q >> 3; qq = q & 7; }
        else {
            tile = (q < 8) ? 0 : (q < 16) ? 1 : (q < 20) ? 2 : 3;
            qq = q - ((tile == 0) ? 0 : (tile == 1) ? 8 : (tile == 2) ? 16 : 20);
        }
        bool isA = tile < 2;
        int kg, row;
        if (isA || BN == 128) { kg = qq >> 1; row = (qq & 1) * 64 + lane; }
        else                  { kg = qq;      row = lane; }
        const __bf16* base = (tile == 0) ? Ah : (tile == 1) ? Al : (tile == 2) ? Bh : Bl;
        long ld = isA ? lda : ldb;
        int  rb = isA ? bm : bn;
        sp[p] = base + (size_t)(rb + row) * ld + kg * 8;
        int tb = (tile == 0) ? 0 : (tile == 1) ? 8192 : (tile == 2) ? 16384 : (16384 + BN * 64);
        dp[p] = (char*)smem + tb + qq * 1024;
    }

    f32x4 acc[4][NF];
#pragma unroll
    for (int i = 0; i < 4; ++i)
#pragma unroll
        for (int j = 0; j < NF; ++j)
#pragma unroll
            for (int e = 0; e < 4; ++e) acc[i][j][e] = 0.f;

    for (int kt = 0; kt < Ksteps; ++kt) {
        if (kt) __syncthreads();
#pragma unroll
        for (int p = 0; p < NP; ++p) gll16(sp[p] + kt * 32, dp[p]);
        __syncthreads();   // compiler drains vmcnt before s_barrier

        bf16x8 aH[4], aL[4], bHf[NF], bLf[NF];
#pragma unroll
        for (int mf = 0; mf < 4; ++mf) {
            int row = wr * 64 + mf * 16 + lrow;
            aH[mf] = *(const bf16x8*)(smem + (size_t)(lgrp * 128 + row) * 8);
            aL[mf] = *(const bf16x8*)(smem + 4096 + (size_t)(lgrp * 128 + row) * 8);
        }
#pragma unroll
        for (int nf = 0; nf < NF; ++nf) {
            int col = wc * WN + nf * 16 + lrow;
            bHf[nf] = *(const bf16x8*)(smem + 8192 + (size_t)(lgrp * BN + col) * 8);
            bLf[nf] = *(const bf16x8*)(smem + 8192 + BN * 32 + (size_t)(lgrp * BN + col) * 8);
        }
#pragma unroll
        for (int mf = 0; mf < 4; ++mf)
#pragma unroll
            for (int nf = 0; nf < NF; ++nf) {
                acc[mf][nf] = __builtin_amdgcn_mfma_f32_16x16x32_bf16(aH[mf], bHf[nf], acc[mf][nf], 0, 0, 0);
                acc[mf][nf] = __builtin_amdgcn_mfma_f32_16x16x32_bf16(aH[mf], bLf[nf], acc[mf][nf], 0, 0, 0);
                acc[mf][nf] = __builtin_amdgcn_mfma_f32_16x16x32_bf16(aL[mf], bHf[nf], acc[mf][nf], 0, 0, 0);
            }
    }

    const size_t cz = (size_t)blockIdx.z * zC;
    const long cadj = (bn >= nsplit) ? splitAdd : 0;
#pragma unroll
    for (int mf = 0; mf < 4; ++mf) {
        int gi0 = bm + wr * 64 + mf * 16 + lgrp * 4;
#pragma unroll
        for (int nf = 0; nf < NF; ++nf) {
            int gj = bn + wc * WN + nf * 16 + lrow;
#pragma unroll
            for (int r = 0; r < 4; ++r) {
                int gi = gi0 + r;
                if (gi < M) {
                    float v = acc[mf][nf][r];
                    if (EPI == 0) {
                        size_t cix = cz + (size_t)gi * ldc + gj + cadj;
                        __bf16 h = (__bf16)v;
                        Ch[cix] = h;
                        Cl[cix] = (__bf16)(v - (float)h);
                    } else {
                        v += bias[gj];
                        v = (EPI == 1) ? 1.f / (1.f + expf(-v)) : tanhf(v);
                        Cf[cz + (size_t)gi * ldc + gj] = v;
                    }
                }
            }
        }
    }
}

// ---------------------------------------------------------------------------
// LDS-tiled transpose between RM slots [(n*16+b)][KP] and T slots
// [s][i*16+b][node] (region stride 16c rows). dir 0: RM->T, dir 1: T->RM.
// Tile: 32 kk x 64 node, per-block loops hi then lo. Skip i<iMin.
// ---------------------------------------------------------------------------
__global__ __launch_bounds__(256) void trans_kern(
    __bf16* __restrict__ TH, __bf16* __restrict__ TL,
    __bf16* __restrict__ RH, __bf16* __restrict__ RL,
    int c, int KP, int kk0, int kkEnd, int iMin, int dir)
{
    __shared__ __bf16 tile[32][66];
    const int b = blockIdx.z, nt = blockIdx.y * 64;
    const int kkb = kk0 + blockIdx.x * 32;
    const int t = threadIdx.x;
    const int c16 = 16 * c;

    for (int cp = 0; cp < 2; ++cp) {
        __bf16* Tp = cp ? TL : TH;
        __bf16* Rp = cp ? RL : RH;
        if (dir == 0) {
#pragma unroll
            for (int rep = 0; rep < 8; ++rep) {
                int kk = kkb + (t & 31);
                int nl = rep * 8 + (t >> 5);
                __bf16 v = (__bf16)0.f;
                if (kk < kkEnd) v = Rp[(size_t)((nt + nl) * 16 + b) * KP + kk];
                tile[t & 31][nl] = v;
            }
            __syncthreads();
#pragma unroll
            for (int rep = 0; rep < 8; ++rep) {
                int kkl = rep * 4 + (t >> 6);
                int kk = kkb + kkl;
                int n = nt + (t & 63);
                if (kk < kkEnd) {
                    int s = (kk >= c) + (kk >= 2 * c) + (kk >= 3 * c) + (kk >= 4 * c);
                    int i = kk - s * c;
                    if (i >= iMin)
                        Tp[((size_t)s * c16 + i * 16 + b) * 1024 + n] = tile[kkl][t & 63];
                }
            }
        } else {
#pragma unroll
            for (int rep = 0; rep < 8; ++rep) {
                int kkl = rep * 4 + (t >> 6);
                int kk = kkb + kkl;
                int n = nt + (t & 63);
                __bf16 v = (__bf16)0.f;
                if (kk < kkEnd) {
                    int s = (kk >= c) + (kk >= 2 * c) + (kk >= 3 * c) + (kk >= 4 * c);
                    int i = kk - s * c;
                    if (i >= iMin)
                        v = Tp[((size_t)s * c16 + i * 16 + b) * 1024 + n];
                }
                tile[kkl][t & 63] = v;
            }
            __syncthreads();
#pragma unroll
            for (int rep = 0; rep < 8; ++rep) {
                int kk = kkb + (t & 31);
                int nl = rep * 8 + (t >> 5);
                if (kk < kkEnd) {
                    int s = (kk >= c) + (kk >= 2 * c) + (kk >= 3 * c) + (kk >= 4 * c);
                    int i = kk - s * c;
                    if (i >= iMin)
                        Rp[(size_t)((nt + nl) * 16 + b) * KP + kk] = tile[t & 31][nl];
                }
            }
        }
        __syncthreads();
    }
}

// ---------------------------------------------------------------------------
// Build concat input into RM slot 0 (cols [ccStart,C) + zero pads [5C,KP) when
// ccStart==0), split to bf16 hi/lo. MODE as round 1.
// ---------------------------------------------------------------------------
template<int MODE>
__global__ __launch_bounds__(256) void xcat_kern(
    __bf16* __restrict__ dH, __bf16* __restrict__ dL,
    const float* __restrict__ s1, const float* __restrict__ s2,
    const float* __restrict__ h, const float* __restrict__ zr,
    int t, int ccStart, int width, int KP)
{
    constexpr int C = (MODE < 2) ? 65 : (MODE < 4) ? 128 : (MODE < 6) ? 130 : 256;
    int idx = blockIdx.x * 256 + threadIdx.x;
    if (idx >= NB * width) return;
    int r = idx / width, ww = idx - r * width;
    int hspan = C - ccStart;
    int cc = (ww < hspan) ? (ccStart + ww) : (5 * C + (ww - hspan));
    int n = r >> 4, b = r & 15;
    float v = 0.f;
    if (cc < C) {
        if (MODE == 0 || MODE == 1) {
            if (cc == 0) v = s1[((size_t)b * TT + t) * NNODE + n];
            else { float hv = h[(size_t)r * 64 + cc - 1];
                   v = (MODE == 1) ? zr[(size_t)r * 128 + cc - 1] * hv : hv; }
        } else if (MODE == 2 || MODE == 3) {
            if (cc < 64) v = s1[(size_t)r * 64 + cc];
            else { float hv = h[(size_t)r * 64 + cc - 64];
                   v = (MODE == 3) ? zr[(size_t)r * 128 + cc - 64] * hv : hv; }
        } else if (MODE == 4 || MODE == 5) {
            if (cc == 0) v = s1[r];
            else if (cc == 1) v = s2[((size_t)b * TT + t) * NNODE + n];
            else { float hv = h[(size_t)r * 128 + cc - 2];
                   v = (MODE == 5) ? zr[(size_t)r * 256 + cc - 2] * hv : hv; }
        } else {
            if (cc < 128) v = s1[(size_t)r * 128 + cc];
            else { float hv = h[(size_t)r * 128 + cc - 128];
                   v = (MODE == 7) ? zr[(size_t)r * 256 + cc - 128] * hv : hv; }
        }
    }
    __bf16 hi = (__bf16)v;
    size_t o = (size_t)r * KP + cc;
    dH[o] = hi;
    dL[o] = (__bf16)(v - (float)hi);
}

// ---------------------------------------------------------------------------
// small kernels
// ---------------------------------------------------------------------------
__global__ __launch_bounds__(256) void compute_ne(
    const float* __restrict__ We1, const float* __restrict__ We2,
    const float* __restrict__ Mem, float* __restrict__ ne1, float* __restrict__ ne2)
{
    int idx = blockIdx.x * 256 + threadIdx.x;
    if (idx >= 2 * 65536) return;
    int which = idx >> 16;
    int i = idx & 65535;
    int n = i >> 6, d = i & 63;
    const float* We = which ? We2 : We1;
    float acc = 0.f;
#pragma unroll
    for (int k = 0; k < 20; ++k) acc += We[n * 20 + k] * Mem[k * 64 + d];
    (which ? ne2 : ne1)[i] = acc;
}

__global__ __launch_bounds__(256) void build_g(
    const float* __restrict__ ne1, const float* __restrict__ ne2, float* __restrict__ g)
{
    int row = blockIdx.x;
    int n = row & 1023;
    const float* qa = (row < 1024) ? ne1 : ne2;
    const float* kb = (row < 1024) ? ne2 : ne1;
    __shared__ float q[64];
    __shared__ float sc[1024];
    __shared__ float red[256];
    int tid = threadIdx.x;
    if (tid < 64) q[tid] = qa[n * 64 + tid];
    __syncthreads();
    for (int m = tid; m < 1024; m += 256) {
        float acc = 0.f;
        const float* kr = kb + m * 64;
#pragma unroll 8
        for (int d = 0; d < 64; ++d) acc += q[d] * kr[d];
        sc[m] = fmaxf(acc, 0.f);
    }
    __syncthreads();
    float mx = -1e30f;
    for (int m = tid; m < 1024; m += 256) mx = fmaxf(mx, sc[m]);
    red[tid] = mx;
    __syncthreads();
    for (int s2 = 128; s2 > 0; s2 >>= 1) {
        if (tid < s2) red[tid] = fmaxf(red[tid], red[tid + s2]);
        __syncthreads();
    }
    mx = red[0];
    __syncthreads();
    float sum = 0.f;
    for (int m = tid; m < 1024; m += 256) {
        float e = expf(sc[m] - mx);
        sc[m] = e;
        sum += e;
    }
    red[tid] = sum;
    __syncthreads();
    for (int s2 = 128; s2 > 0; s2 >>= 1) {
        if (tid < s2) red[tid] += red[tid + s2];
        __syncthreads();
    }
    float inv = 1.f / red[0];
    for (int m = tid; m < 1024; m += 256) g[(size_t)row * 1024 + m] = sc[m] * inv;
}

__global__ __launch_bounds__(256) void g_split(
    const float* __restrict__ g, __bf16* __restrict__ gh, __bf16* __restrict__ gl)
{
    int i = blockIdx.x * 256 + threadIdx.x;
    if (i >= 2048 * 1024) return;
    float v = g[i];
    __bf16 h = (__bf16)v;
    gh[i] = h;
    gl[i] = (__bf16)(v - (float)h);
}

// effective weight, transposed [cout][KP], slot order [X,Y1,Z1,Y2,Z2]
__global__ __launch_bounds__(256) void build_weffT(
    const float* __restrict__ W, __bf16* __restrict__ dh, __bf16* __restrict__ dl,
    int c, int cout, int KP)
{
    int idx = blockIdx.x * 256 + threadIdx.x;
    if (idx >= cout * KP) return;
    int o = idx / KP, kk = idx - o * KP;
    float v = 0.f;
    if (kk < 5 * c) {
        int s = (kk >= c) + (kk >= 2 * c) + (kk >= 3 * c) + (kk >= 4 * c);
        int i = kk - s * c;
        if      (s == 0) v = W[(size_t)(0 * c + i) * cout + o] + W[(size_t)(3 * c + i) * cout + o]
                           - W[(size_t)(2 * c + i) * cout + o] - W[(size_t)(5 * c + i) * cout + o];
        else if (s == 1) v = W[(size_t)(1 * c + i) * cout + o];
        else if (s == 2) v = W[(size_t)(4 * c + i) * cout + o];
        else if (s == 3) v = 2.f * W[(size_t)(2 * c + i) * cout + o];
        else             v = 2.f * W[(size_t)(5 * c + i) * cout + o];
    }
    __bf16 h = (__bf16)v;
    dh[idx] = h;
    dl[idx] = (__bf16)(v - (float)h);
}

template <int H>
__global__ __launch_bounds__(256) void gru_update(
    float* __restrict__ h, const float* __restrict__ zr, const float* __restrict__ hc)
{
    int idx = blockIdx.x * 256 + threadIdx.x;
    if (idx >= NB * H) return;
    int r = idx / H, i = idx - r * H;
    float rg = zr[(size_t)r * 2 * H + H + i];
    h[idx] = rg * h[idx] + (1.f - rg) * hc[idx];
}

__global__ __launch_bounds__(64) void attention(
    const float* __restrict__ h, const float* __restrict__ Wq,
    const float* __restrict__ Mem, float* __restrict__ htc)
{
    int r = blockIdx.x;
    int j = threadIdx.x;
    __shared__ float hr[64], q[64], sc[20];
    hr[j] = h[(size_t)r * 64 + j];
    __syncthreads();
    float acc = 0.f;
#pragma unroll 8
    for (int i = 0; i < 64; ++i) acc += hr[i] * Wq[i * 64 + j];
    q[j] = acc;
    __syncthreads();
    if (j < 20) {
        float a = 0.f;
#pragma unroll 8
        for (int d = 0; d < 64; ++d) a += q[d] * Mem[j * 64 + d];
        sc[j] = a;
    }
    __syncthreads();
    if (j == 0) {
        float mx = sc[0];
        for (int m = 1; m < 20; ++m) mx = fmaxf(mx, sc[m]);
        float s = 0.f;
        for (int m = 0; m < 20; ++m) { sc[m] = expf(sc[m] - mx); s += sc[m]; }
        float inv = 1.f / s;
        for (int m = 0; m < 20; ++m) sc[m] *= inv;
    }
    __syncthreads();
    float v = 0.f;
#pragma unroll
    for (int m = 0; m < 20; ++m) v += sc[m] * Mem[m * 64 + j];
    htc[(size_t)r * 128 + j] = hr[j];
    htc[(size_t)r * 128 + 64 + j] = v;
}

__global__ __launch_bounds__(256) void proj_out(
    const float* __restrict__ h1, const float* __restrict__ pw, const float* __restrict__ pb,
    float* __restrict__ go, float* __restrict__ out, int t)
{
    int r = blockIdx.x * 256 + threadIdx.x;
    if (r >= NB) return;
    float acc = pb[0];
    const float* hr = h1 + (size_t)r * 128;
#pragma unroll 8
    for (int i = 0; i < 128; ++i) acc += hr[i] * pw[i];
    go[r] = acc;
    int n = r >> 4, b = r & 15;
    out[((size_t)b * TT + t) * NNODE + n] = acc;
}

// ---------------------------------------------------------------------------
// host
// ---------------------------------------------------------------------------
extern "C" void kernel_launch(void* const* d_in, const int* in_sizes, int n_in,
                              void* d_out, int out_size, void* d_ws, size_t ws_size,
                              hipStream_t stream)
{
    const float* x      = (const float*)d_in[0];
    const float* y_cov  = (const float*)d_in[1];
    const float* Memory = (const float*)d_in[2];
    const float* Wq     = (const float*)d_in[3];
    const float* We1    = (const float*)d_in[4];
    const float* We2    = (const float*)d_in[5];
    const float* e0gw = (const float*)d_in[6];  const float* e0gb = (const float*)d_in[7];
    const float* e0uw = (const float*)d_in[8];  const float* e0ub = (const float*)d_in[9];
    const float* e1gw = (const float*)d_in[10]; const float* e1gb = (const float*)d_in[11];
    const float* e1uw = (const float*)d_in[12]; const float* e1ub = (const float*)d_in[13];
    const float* d0gw = (const float*)d_in[14]; const float* d0gb = (const float*)d_in[15];
    const float* d0uw = (const float*)d_in[16]; const float* d0ub = (const float*)d_in[17];
    const float* d1gw = (const float*)d_in[18]; const float* d1gb = (const float*)d_in[19];
    const float* d1uw = (const float*)d_in[20]; const float* d1ub = (const float*)d_in[21];
    const float* proj_w = (const float*)d_in[22];
    const float* proj_b = (const float*)d_in[23];
    float* out = (float*)d_out;
    (void)in_sizes; (void)n_in; (void)out_size; (void)ws_size;

    char* wsb = (char*)d_ws;
    size_t off = 0;
    auto alloc = [&](size_t bytes) -> void* {
        void* p = wsb + off;
        off += (bytes + 255) & ~(size_t)255;
        return p;
    };

    float*  gf  = (float*) alloc(2048L * 1024 * 4);
    __bf16* gsH = (__bf16*)alloc(2048L * 1024 * 2);
    __bf16* gsL = (__bf16*)alloc(2048L * 1024 * 2);
    float*  ne1 = (float*) alloc(65536L * 4);
    float*  ne2 = (float*) alloc(65536L * 4);
    auto allocWT = [&](int cout, int KP, __bf16** h, __bf16** l) {
        *h = (__bf16*)alloc((size_t)cout * KP * 2);
        *l = (__bf16*)alloc((size_t)cout * KP * 2);
    };
    __bf16 *wE0gH, *wE0gL, *wE0uH, *wE0uL, *wE1gH, *wE1gL, *wE1uH, *wE1uL;
    __bf16 *wD0gH, *wD0gL, *wD0uH, *wD0uL, *wD1gH, *wD1gL, *wD1uH, *wD1uL;
    allocWT(128, 352,  &wE0gH, &wE0gL);  allocWT(64, 352,  &wE0uH, &wE0uL);
    allocWT(128, 640,  &wE1gH, &wE1gL);  allocWT(64, 640,  &wE1uH, &wE1uL);
    allocWT(256, 672,  &wD0gH, &wD0gL);  allocWT(128, 672, &wD0uH, &wD0uL);
    allocWT(256, 1280, &wD1gH, &wD1gL);  allocWT(128, 1280, &wD1uH, &wD1uL);
    __bf16* RMh = (__bf16*)alloc((size_t)NB * 1280 * 2);
    __bf16* RMl = (__bf16*)alloc((size_t)NB * 1280 * 2);
    __bf16* Th  = (__bf16*)alloc((size_t)(5 * 4096 + 128) * 1024 * 2);
    __bf16* Tl  = (__bf16*)alloc((size_t)(5 * 4096 + 128) * 1024 * 2);
    float* zr  = (float*)alloc((size_t)NB * 256 * 4);
    float* hc  = (float*)alloc((size_t)NB * 128 * 4);
    float* h0e = (float*)alloc((size_t)NB * 64 * 4);
    float* h1e = (float*)alloc((size_t)NB * 64 * 4);
    float* dh0 = (float*)alloc((size_t)NB * 128 * 4);
    float* dh1 = (float*)alloc((size_t)NB * 128 * 4);
    float* gob = (float*)alloc((size_t)NB * 4);

    // ---- setup ----
    compute_ne<<<cdiv(2 * 65536, 256), 256, 0, stream>>>(We1, We2, Memory, ne1, ne2);
    build_g<<<2048, 256, 0, stream>>>(ne1, ne2, gf);
    g_split<<<cdiv(2048 * 1024, 256), 256, 0, stream>>>(gf, gsH, gsL);
    build_weffT<<<cdiv(128 * 352, 256), 256, 0, stream>>>(e0gw, wE0gH, wE0gL, 65, 128, 352);
    build_weffT<<<cdiv(64 * 352, 256), 256, 0, stream>>>(e0uw, wE0uH, wE0uL, 65, 64, 352);
    build_weffT<<<cdiv(128 * 640, 256), 256, 0, stream>>>(e1gw, wE1gH, wE1gL, 128, 128, 640);
    build_weffT<<<cdiv(64 * 640, 256), 256, 0, stream>>>(e1uw, wE1uH, wE1uL, 128, 64, 640);
    build_weffT<<<cdiv(256 * 672, 256), 256, 0, stream>>>(d0gw, wD0gH, wD0gL, 130, 256, 672);
    build_weffT<<<cdiv(128 * 672, 256), 256, 0, stream>>>(d0uw, wD0uH, wD0uL, 130, 128, 672);
    build_weffT<<<cdiv(256 * 1280, 256), 256, 0, stream>>>(d1gw, wD1gH, wD1gL, 256, 256, 1280);
    build_weffT<<<cdiv(128 * 1280, 256), 256, 0, stream>>>(d1uw, wD1uH, wD1uL, 256, 128, 1280);
    hipMemsetAsync(h0e, 0, (size_t)NB * 64 * 4, stream);
    hipMemsetAsync(h1e, 0, (size_t)NB * 64 * 4, stream);

    // trans0 -> hop1 -> hop2 -> transback -> gemm_w
    auto agcn_core = [&](int c, int cin2, int KP, const __bf16* wth, const __bf16* wtl,
                         const float* bias, int cout, int epi, float* outf) {
        int Mfull = 16 * c, Moff = 16 * cin2, Mv = Mfull - Moff;
        dim3 t0(cdiv(c - cin2, 32), 16, 16);
        trans_kern<<<t0, 256, 0, stream>>>(Th, Tl, RMh, RMl, c, KP, cin2, c, 0, 0);
        dim3 g1(16, cdiv(Mv, 128), 1);
        mm_kern<128, 0><<<g1, 256, 0, stream>>>(
            Th + (size_t)Moff * 1024, Tl + (size_t)Moff * 1024, 1024, 0,
            gsH, gsL, 0, 1024, Mv, 32,
            Th + (size_t)(Mfull + Moff) * 1024, Tl + (size_t)(Mfull + Moff) * 1024, nullptr,
            1024, 0, 1024, (long)Mfull * 1024 - 1024, nullptr);
        dim3 g2(8, cdiv(Mv, 128), 2);
        mm_kern<128, 0><<<g2, 256, 0, stream>>>(
            Th + (size_t)(Mfull + Moff) * 1024, Tl + (size_t)(Mfull + Moff) * 1024, 1024, (long)Mfull * 1024,
            gsH, gsL, (long)1024 * 1024, 1024, Mv, 32,
            Th + (size_t)(3 * Mfull + Moff) * 1024, Tl + (size_t)(3 * Mfull + Moff) * 1024, nullptr,
            1024, (long)Mfull * 1024, 1 << 30, 0, nullptr);
        dim3 t1(cdiv(4 * c, 32), 16, 16);
        trans_kern<<<t1, 256, 0, stream>>>(Th, Tl, RMh, RMl, c, KP, c, 5 * c, cin2, 1);
        dim3 gw(cout / 64, 128, 1);
        if (epi == 1)
            mm_kern<64, 1><<<gw, 256, 0, stream>>>(RMh, RMl, KP, 0, wth, wtl, 0, KP, NB, KP / 32,
                                                   nullptr, nullptr, outf, cout, 0, 1 << 30, 0, bias);
        else
            mm_kern<64, 2><<<gw, 256, 0, stream>>>(RMh, RMl, KP, 0, wth, wtl, 0, KP, NB, KP / 32,
                                                   nullptr, nullptr, outf, cout, 0, 1 << 30, 0, bias);
    };

    // ---- encoder ----
    for (int t = 0; t < TT; ++t) {
        // enc layer 0 (c=65, cin=1, KP=352)
        xcat_kern<0><<<cdiv(NB * 92, 256), 256, 0, stream>>>(RMh, RMl, x, nullptr, h0e, nullptr, t, 0, 92, 352);
        agcn_core(65, 0, 352, wE0gH, wE0gL, e0gb, 128, 1, zr);
        xcat_kern<1><<<cdiv(NB * 64, 256), 256, 0, stream>>>(RMh, RMl, x, nullptr, h0e, zr, t, 1, 64, 352);
        agcn_core(65, 1, 352, wE0uH, wE0uL, e0ub, 64, 2, hc);
        gru_update<64><<<cdiv(NB * 64, 256), 256, 0, stream>>>(h0e, zr, hc);
        // enc layer 1 (c=128, cin=64, KP=640)
        xcat_kern<2><<<cdiv(NB * 128, 256), 256, 0, stream>>>(RMh, RMl, h0e, nullptr, h1e, nullptr, t, 0, 128, 640);
        agcn_core(128, 0, 640, wE1gH, wE1gL, e1gb, 128, 1, zr);
        xcat_kern<3><<<cdiv(NB * 64, 256), 256, 0, stream>>>(RMh, RMl, h0e, nullptr, h1e, zr, t, 64, 64, 640);
        agcn_core(128, 64, 640, wE1uH, wE1uL, e1ub, 64, 2, hc);
        gru_update<64><<<cdiv(NB * 64, 256), 256, 0, stream>>>(h1e, zr, hc);
    }

    // ---- memory attention ----
    attention<<<NB, 64, 0, stream>>>(h1e, Wq, Memory, dh0);
    hipMemcpyAsync(dh1, dh0, (size_t)NB * 128 * 4, hipMemcpyDeviceToDevice, stream);
    hipMemsetAsync(gob, 0, (size_t)NB * 4, stream);

    // ---- decoder ----
    for (int t = 0; t < TT; ++t) {
        // dec layer 0 (c=130, cin=2, KP=672)
        xcat_kern<4><<<cdiv(NB * 152, 256), 256, 0, stream>>>(RMh, RMl, gob, y_cov, dh0, nullptr, t, 0, 152, 672);
        agcn_core(130, 0, 672, wD0gH, wD0gL, d0gb, 256, 1, zr);
        xcat_kern<5><<<cdiv(NB * 128, 256), 256, 0, stream>>>(RMh, RMl, gob, y_cov, dh0, zr, t, 2, 128, 672);
        agcn_core(130, 2, 672, wD0uH, wD0uL, d0ub, 128, 2, hc);
        gru_update<128><<<cdiv(NB * 128, 256), 256, 0, stream>>>(dh0, zr, hc);
        // dec layer 1 (c=256, cin=128, KP=1280)
        xcat_kern<6><<<cdiv(NB * 256, 256), 256, 0, stream>>>(RMh, RMl, dh0, nullptr, dh1, nullptr, t, 0, 256, 1280);
        agcn_core(256, 0, 1280, wD1gH, wD1gL, d1gb, 256, 1, zr);
        xcat_kern<7><<<cdiv(NB * 128, 256), 256, 0, stream>>>(RMh, RMl, dh0, nullptr, dh1, zr, t, 128, 128, 1280);
        agcn_core(256, 128, 1280, wD1uH, wD1uL, d1ub, 128, 2, hc);
        gru_update<128><<<cdiv(NB * 128, 256), 256, 0, stream>>>(dh1, zr, hc);
        proj_out<<<cdiv(NB, 256), 256, 0, stream>>>(dh1, proj_w, proj_b, gob, out, t);
    }
}

// Round 3
// 17882.799 us; speedup vs baseline: 2.7402x; 1.1282x over previous
//
#include <hip/hip_runtime.h>
#include <math.h>

#define NNODE 1024
#define BATCH 16
#define NB    16384
#define TT    12

typedef __bf16 bf16x8 __attribute__((ext_vector_type(8)));
typedef float  f32x4  __attribute__((ext_vector_type(4)));

static inline int cdiv(int a, int b) { return (a + b - 1) / b; }

// async global->LDS, 16B per lane, wave-uniform LDS base + lane*16
__device__ inline void gll16(const void* g, void* l) {
    __builtin_amdgcn_global_load_lds(
        (const __attribute__((address_space(1))) void*)g,
        (__attribute__((address_space(3))) void*)l, 16, 0, 0);
}

// ---------------------------------------------------------------------------
// Split-bf16 GEMM, 2-phase double-buffered pipeline.
// D[i][j] = sum_k A[i][k]*B[j][k]  (both k-contig), 3-pass hi/lo split.
// BM in {64,128}, BN in {64,128}, BK=32, 256 thr = 4 waves (2x2).
// EPI 0: split-store bf16 hi/lo (Ch/Cl) with nsplit/splitAdd col relocation
// EPI 1: +bias, sigmoid -> Cf
// EPI 3: +bias, tanh, fused GRU: hout = r*hout + (1-r)*hc  (r from zrp)
// grid.z batches via element strides zA/zB/zC.
// ---------------------------------------------------------------------------
template<int BM, int BN, int EPI>
__global__ __launch_bounds__(256) void mm_kern(
    const __bf16* __restrict__ Ah, const __bf16* __restrict__ Al, long lda, long zA,
    const __bf16* __restrict__ Bh, const __bf16* __restrict__ Bl, long zB, long ldb,
    int M, int Ksteps,
    __bf16* __restrict__ Ch, __bf16* __restrict__ Cl, float* __restrict__ Cf,
    long ldc, long zC, int nsplit, long splitAdd,
    const float* __restrict__ bias, const float* __restrict__ zrp,
    float* __restrict__ hout)
{
    constexpr int WM = BM / 2, WN = BN / 2;
    constexpr int MF = WM / 16, NF = WN / 16;
    constexpr int NP = (BM + BN) / 32;     // staging chunks per wave
    constexpr int BUFE = (BM + BN) * 64;   // elements per LDS buffer
    constexpr int nA = BM / 16, nB = BN / 16;
    // buffer layout (elements): AH[BM*32] | AL[BM*32] | BH[BN*32] | BL[BN*32]
    __shared__ __bf16 smem[2 * BUFE];

    const int bm = blockIdx.y * BM, bn = blockIdx.x * BN;
    const int tid = threadIdx.x, w = tid >> 6, lane = tid & 63;
    const int wr = w >> 1, wc = w & 1;
    const int lgrp = lane >> 4, lrow = lane & 15;

    Ah += (size_t)blockIdx.z * zA;  Al += (size_t)blockIdx.z * zA;
    Bh += (size_t)blockIdx.z * zB;  Bl += (size_t)blockIdx.z * zB;

    const __bf16* sp[NP];
    int dpo[NP];
#pragma unroll
    for (int p = 0; p < NP; ++p) {
        int q = p * 4 + w;
        int tile = (q < nA) ? 0 : (q < 2 * nA) ? 1 : (q < 2 * nA + nB) ? 2 : 3;
        int qq = q - ((tile == 0) ? 0 : (tile == 1) ? nA : (tile == 2) ? 2 * nA : 2 * nA + nB);
        int R = (tile < 2) ? BM : BN;
        int kg, row;
        if (R == 128) { kg = qq >> 1; row = (qq & 1) * 64 + lane; }
        else          { kg = qq;      row = lane; }
        const __bf16* base = (tile == 0) ? Ah : (tile == 1) ? Al : (tile == 2) ? Bh : Bl;
        long ld = (tile < 2) ? lda : ldb;
        int  rb = (tile < 2) ? bm : bn;
        sp[p] = base + (size_t)(rb + row) * ld + kg * 8;
        int tbase = (tile == 0) ? 0 : (tile == 1) ? BM * 32 : (tile == 2) ? BM * 64 : (BM * 64 + BN * 32);
        dpo[p] = tbase * 2 + qq * 1024;
    }

    f32x4 acc[MF][NF];
#pragma unroll
    for (int i = 0; i < MF; ++i)
#pragma unroll
        for (int j = 0; j < NF; ++j)
#pragma unroll
            for (int e = 0; e < 4; ++e) acc[i][j][e] = 0.f;

    auto stage = [&](int kt, int bsel) {
        char* lb = (char*)smem + bsel * (BUFE * 2);
#pragma unroll
        for (int p = 0; p < NP; ++p) gll16(sp[p] + (size_t)kt * 32, lb + dpo[p]);
    };

    stage(0, 0);
    __syncthreads();                       // drains vmcnt(0): buf0 ready

    for (int kt = 0; kt < Ksteps; ++kt) {
        const int cur = kt & 1;
        if (kt + 1 < Ksteps) stage(kt + 1, cur ^ 1);   // overlap with compute below
        const __bf16* sb = smem + cur * BUFE;

        bf16x8 aH[MF], aL[MF], bHf[NF], bLf[NF];
#pragma unroll
        for (int mf = 0; mf < MF; ++mf) {
            int row = wr * WM + mf * 16 + lrow;
            aH[mf] = *(const bf16x8*)(sb + (size_t)(lgrp * BM + row) * 8);
            aL[mf] = *(const bf16x8*)(sb + BM * 32 + (size_t)(lgrp * BM + row) * 8);
        }
#pragma unroll
        for (int nf = 0; nf < NF; ++nf) {
            int col = wc * WN + nf * 16 + lrow;
            bHf[nf] = *(const bf16x8*)(sb + BM * 64 + (size_t)(lgrp * BN + col) * 8);
            bLf[nf] = *(const bf16x8*)(sb + BM * 64 + BN * 32 + (size_t)(lgrp * BN + col) * 8);
        }
#pragma unroll
        for (int mf = 0; mf < MF; ++mf)
#pragma unroll
            for (int nf = 0; nf < NF; ++nf) {
                acc[mf][nf] = __builtin_amdgcn_mfma_f32_16x16x32_bf16(aH[mf], bHf[nf], acc[mf][nf], 0, 0, 0);
                acc[mf][nf] = __builtin_amdgcn_mfma_f32_16x16x32_bf16(aH[mf], bLf[nf], acc[mf][nf], 0, 0, 0);
                acc[mf][nf] = __builtin_amdgcn_mfma_f32_16x16x32_bf16(aL[mf], bHf[nf], acc[mf][nf], 0, 0, 0);
            }
        __syncthreads();                   // drain vmcnt (next buf ready) + barrier
    }

    const size_t cz = (size_t)blockIdx.z * zC;
    const long cadj = (bn >= nsplit) ? splitAdd : 0;
#pragma unroll
    for (int mf = 0; mf < MF; ++mf) {
        int gi0 = bm + wr * WM + mf * 16 + lgrp * 4;
#pragma unroll
        for (int nf = 0; nf < NF; ++nf) {
            int gj = bn + wc * WN + nf * 16 + lrow;
#pragma unroll
            for (int r = 0; r < 4; ++r) {
                int gi = gi0 + r;
                if (gi < M) {
                    float v = acc[mf][nf][r];
                    if (EPI == 0) {
                        size_t cix = cz + (size_t)gi * ldc + gj + cadj;
                        __bf16 h = (__bf16)v;
                        Ch[cix] = h;
                        Cl[cix] = (__bf16)(v - (float)h);
                    } else if (EPI == 1) {
                        v += bias[gj];
                        v = 1.f / (1.f + expf(-v));
                        Cf[cz + (size_t)gi * ldc + gj] = v;
                    } else {
                        v += bias[gj];
                        v = tanhf(v);
                        float rg = zrp[(size_t)gi * 2 * ldc + ldc + gj];
                        size_t hix = (size_t)gi * ldc + gj;
                        hout[hix] = rg * hout[hix] + (1.f - rg) * v;
                    }
                }
            }
        }
    }
}

// ---------------------------------------------------------------------------
// LDS-tiled transpose between RM slots [(n*16+b)][KP] and T slots
// [s][i*16+b][node]. dir 0: RM->T, dir 1: T->RM. Skip i<iMin.
// ---------------------------------------------------------------------------
__global__ __launch_bounds__(256) void trans_kern(
    __bf16* __restrict__ TH, __bf16* __restrict__ TL,
    __bf16* __restrict__ RH, __bf16* __restrict__ RL,
    int c, int KP, int kk0, int kkEnd, int iMin, int dir)
{
    __shared__ __bf16 tile[32][66];
    const int b = blockIdx.z, nt = blockIdx.y * 64;
    const int kkb = kk0 + blockIdx.x * 32;
    const int t = threadIdx.x;
    const int c16 = 16 * c;

    for (int cp = 0; cp < 2; ++cp) {
        __bf16* Tp = cp ? TL : TH;
        __bf16* Rp = cp ? RL : RH;
        if (dir == 0) {
#pragma unroll
            for (int rep = 0; rep < 8; ++rep) {
                int kk = kkb + (t & 31);
                int nl = rep * 8 + (t >> 5);
                __bf16 v = (__bf16)0.f;
                if (kk < kkEnd) v = Rp[(size_t)((nt + nl) * 16 + b) * KP + kk];
                tile[t & 31][nl] = v;
            }
            __syncthreads();
#pragma unroll
            for (int rep = 0; rep < 8; ++rep) {
                int kkl = rep * 4 + (t >> 6);
                int kk = kkb + kkl;
                int n = nt + (t & 63);
                if (kk < kkEnd) {
                    int s = (kk >= c) + (kk >= 2 * c) + (kk >= 3 * c) + (kk >= 4 * c);
                    int i = kk - s * c;
                    if (i >= iMin)
                        Tp[((size_t)s * c16 + i * 16 + b) * 1024 + n] = tile[kkl][t & 63];
                }
            }
        } else {
#pragma unroll
            for (int rep = 0; rep < 8; ++rep) {
                int kkl = rep * 4 + (t >> 6);
                int kk = kkb + kkl;
                int n = nt + (t & 63);
                __bf16 v = (__bf16)0.f;
                if (kk < kkEnd) {
                    int s = (kk >= c) + (kk >= 2 * c) + (kk >= 3 * c) + (kk >= 4 * c);
                    int i = kk - s * c;
                    if (i >= iMin)
                        v = Tp[((size_t)s * c16 + i * 16 + b) * 1024 + n];
                }
                tile[kkl][t & 63] = v;
            }
            __syncthreads();
#pragma unroll
            for (int rep = 0; rep < 8; ++rep) {
                int kk = kkb + (t & 31);
                int nl = rep * 8 + (t >> 5);
                if (kk < kkEnd) {
                    int s = (kk >= c) + (kk >= 2 * c) + (kk >= 3 * c) + (kk >= 4 * c);
                    int i = kk - s * c;
                    if (i >= iMin)
                        Rp[(size_t)((nt + nl) * 16 + b) * KP + kk] = tile[t & 31][nl];
                }
            }
        }
        __syncthreads();
    }
}

// ---------------------------------------------------------------------------
// Build concat input into RM slot 0, split to bf16 hi/lo.
// ---------------------------------------------------------------------------
template<int MODE>
__global__ __launch_bounds__(256) void xcat_kern(
    __bf16* __restrict__ dH, __bf16* __restrict__ dL,
    const float* __restrict__ s1, const float* __restrict__ s2,
    const float* __restrict__ h, const float* __restrict__ zr,
    int t, int ccStart, int width, int KP)
{
    constexpr int C = (MODE < 2) ? 65 : (MODE < 4) ? 128 : (MODE < 6) ? 130 : 256;
    int idx = blockIdx.x * 256 + threadIdx.x;
    if (idx >= NB * width) return;
    int r = idx / width, ww = idx - r * width;
    int hspan = C - ccStart;
    int cc = (ww < hspan) ? (ccStart + ww) : (5 * C + (ww - hspan));
    int n = r >> 4, b = r & 15;
    float v = 0.f;
    if (cc < C) {
        if (MODE == 0 || MODE == 1) {
            if (cc == 0) v = s1[((size_t)b * TT + t) * NNODE + n];
            else { float hv = h[(size_t)r * 64 + cc - 1];
                   v = (MODE == 1) ? zr[(size_t)r * 128 + cc - 1] * hv : hv; }
        } else if (MODE == 2 || MODE == 3) {
            if (cc < 64) v = s1[(size_t)r * 64 + cc];
            else { float hv = h[(size_t)r * 64 + cc - 64];
                   v = (MODE == 3) ? zr[(size_t)r * 128 + cc - 64] * hv : hv; }
        } else if (MODE == 4 || MODE == 5) {
            if (cc == 0) v = s1[r];
            else if (cc == 1) v = s2[((size_t)b * TT + t) * NNODE + n];
            else { float hv = h[(size_t)r * 128 + cc - 2];
                   v = (MODE == 5) ? zr[(size_t)r * 256 + cc - 2] * hv : hv; }
        } else {
            if (cc < 128) v = s1[(size_t)r * 128 + cc];
            else { float hv = h[(size_t)r * 128 + cc - 128];
                   v = (MODE == 7) ? zr[(size_t)r * 256 + cc - 128] * hv : hv; }
        }
    }
    __bf16 hi = (__bf16)v;
    size_t o = (size_t)r * KP + cc;
    dH[o] = hi;
    dL[o] = (__bf16)(v - (float)hi);
}

// ---------------------------------------------------------------------------
// small kernels
// ---------------------------------------------------------------------------
__global__ __launch_bounds__(256) void compute_ne(
    const float* __restrict__ We1, const float* __restrict__ We2,
    const float* __restrict__ Mem, float* __restrict__ ne1, float* __restrict__ ne2)
{
    int idx = blockIdx.x * 256 + threadIdx.x;
    if (idx >= 2 * 65536) return;
    int which = idx >> 16;
    int i = idx & 65535;
    int n = i >> 6, d = i & 63;
    const float* We = which ? We2 : We1;
    float acc = 0.f;
#pragma unroll
    for (int k = 0; k < 20; ++k) acc += We[n * 20 + k] * Mem[k * 64 + d];
    (which ? ne2 : ne1)[i] = acc;
}

__global__ __launch_bounds__(256) void build_g(
    const float* __restrict__ ne1, const float* __restrict__ ne2, float* __restrict__ g)
{
    int row = blockIdx.x;
    int n = row & 1023;
    const float* qa = (row < 1024) ? ne1 : ne2;
    const float* kb = (row < 1024) ? ne2 : ne1;
    __shared__ float q[64];
    __shared__ float sc[1024];
    __shared__ float red[256];
    int tid = threadIdx.x;
    if (tid < 64) q[tid] = qa[n * 64 + tid];
    __syncthreads();
    for (int m = tid; m < 1024; m += 256) {
        float acc = 0.f;
        const float* kr = kb + m * 64;
#pragma unroll 8
        for (int d = 0; d < 64; ++d) acc += q[d] * kr[d];
        sc[m] = fmaxf(acc, 0.f);
    }
    __syncthreads();
    float mx = -1e30f;
    for (int m = tid; m < 1024; m += 256) mx = fmaxf(mx, sc[m]);
    red[tid] = mx;
    __syncthreads();
    for (int s2 = 128; s2 > 0; s2 >>= 1) {
        if (tid < s2) red[tid] = fmaxf(red[tid], red[tid + s2]);
        __syncthreads();
    }
    mx = red[0];
    __syncthreads();
    float sum = 0.f;
    for (int m = tid; m < 1024; m += 256) {
        float e = expf(sc[m] - mx);
        sc[m] = e;
        sum += e;
    }
    red[tid] = sum;
    __syncthreads();
    for (int s2 = 128; s2 > 0; s2 >>= 1) {
        if (tid < s2) red[tid] += red[tid + s2];
        __syncthreads();
    }
    float inv = 1.f / red[0];
    for (int m = tid; m < 1024; m += 256) g[(size_t)row * 1024 + m] = sc[m] * inv;
}

__global__ __launch_bounds__(256) void g_split(
    const float* __restrict__ g, __bf16* __restrict__ gh, __bf16* __restrict__ gl)
{
    int i = blockIdx.x * 256 + threadIdx.x;
    if (i >= 2048 * 1024) return;
    float v = g[i];
    __bf16 h = (__bf16)v;
    gh[i] = h;
    gl[i] = (__bf16)(v - (float)h);
}

__global__ __launch_bounds__(256) void build_weffT(
    const float* __restrict__ W, __bf16* __restrict__ dh, __bf16* __restrict__ dl,
    int c, int cout, int KP)
{
    int idx = blockIdx.x * 256 + threadIdx.x;
    if (idx >= cout * KP) return;
    int o = idx / KP, kk = idx - o * KP;
    float v = 0.f;
    if (kk < 5 * c) {
        int s = (kk >= c) + (kk >= 2 * c) + (kk >= 3 * c) + (kk >= 4 * c);
        int i = kk - s * c;
        if      (s == 0) v = W[(size_t)(0 * c + i) * cout + o] + W[(size_t)(3 * c + i) * cout + o]
                           - W[(size_t)(2 * c + i) * cout + o] - W[(size_t)(5 * c + i) * cout + o];
        else if (s == 1) v = W[(size_t)(1 * c + i) * cout + o];
        else if (s == 2) v = W[(size_t)(4 * c + i) * cout + o];
        else if (s == 3) v = 2.f * W[(size_t)(2 * c + i) * cout + o];
        else             v = 2.f * W[(size_t)(5 * c + i) * cout + o];
    }
    __bf16 h = (__bf16)v;
    dh[idx] = h;
    dl[idx] = (__bf16)(v - (float)h);
}

__global__ __launch_bounds__(64) void attention(
    const float* __restrict__ h, const float* __restrict__ Wq,
    const float* __restrict__ Mem, float* __restrict__ htc)
{
    int r = blockIdx.x;
    int j = threadIdx.x;
    __shared__ float hr[64], q[64], sc[20];
    hr[j] = h[(size_t)r * 64 + j];
    __syncthreads();
    float acc = 0.f;
#pragma unroll 8
    for (int i = 0; i < 64; ++i) acc += hr[i] * Wq[i * 64 + j];
    q[j] = acc;
    __syncthreads();
    if (j < 20) {
        float a = 0.f;
#pragma unroll 8
        for (int d = 0; d < 64; ++d) a += q[d] * Mem[j * 64 + d];
        sc[j] = a;
    }
    __syncthreads();
    if (j == 0) {
        float mx = sc[0];
        for (int m = 1; m < 20; ++m) mx = fmaxf(mx, sc[m]);
        float s = 0.f;
        for (int m = 0; m < 20; ++m) { sc[m] = expf(sc[m] - mx); s += sc[m]; }
        float inv = 1.f / s;
        for (int m = 0; m < 20; ++m) sc[m] *= inv;
    }
    __syncthreads();
    float v = 0.f;
#pragma unroll
    for (int m = 0; m < 20; ++m) v += sc[m] * Mem[m * 64 + j];
    htc[(size_t)r * 128 + j] = hr[j];
    htc[(size_t)r * 128 + 64 + j] = v;
}

__global__ __launch_bounds__(256) void proj_out(
    const float* __restrict__ h1, const float* __restrict__ pw, const float* __restrict__ pb,
    float* __restrict__ go, float* __restrict__ out, int t)
{
    int r = blockIdx.x * 256 + threadIdx.x;
    if (r >= NB) return;
    float acc = pb[0];
    const float* hr = h1 + (size_t)r * 128;
#pragma unroll 8
    for (int i = 0; i < 128; ++i) acc += hr[i] * pw[i];
    go[r] = acc;
    int n = r >> 4, b = r & 15;
    out[((size_t)b * TT + t) * NNODE + n] = acc;
}

// ---------------------------------------------------------------------------
// host
// ---------------------------------------------------------------------------
extern "C" void kernel_launch(void* const* d_in, const int* in_sizes, int n_in,
                              void* d_out, int out_size, void* d_ws, size_t ws_size,
                              hipStream_t stream)
{
    const float* x      = (const float*)d_in[0];
    const float* y_cov  = (const float*)d_in[1];
    const float* Memory = (const float*)d_in[2];
    const float* Wq     = (const float*)d_in[3];
    const float* We1    = (const float*)d_in[4];
    const float* We2    = (const float*)d_in[5];
    const float* e0gw = (const float*)d_in[6];  const float* e0gb = (const float*)d_in[7];
    const float* e0uw = (const float*)d_in[8];  const float* e0ub = (const float*)d_in[9];
    const float* e1gw = (const float*)d_in[10]; const float* e1gb = (const float*)d_in[11];
    const float* e1uw = (const float*)d_in[12]; const float* e1ub = (const float*)d_in[13];
    const float* d0gw = (const float*)d_in[14]; const float* d0gb = (const float*)d_in[15];
    const float* d0uw = (const float*)d_in[16]; const float* d0ub = (const float*)d_in[17];
    const float* d1gw = (const float*)d_in[18]; const float* d1gb = (const float*)d_in[19];
    const float* d1uw = (const float*)d_in[20]; const float* d1ub = (const float*)d_in[21];
    const float* proj_w = (const float*)d_in[22];
    const float* proj_b = (const float*)d_in[23];
    float* out = (float*)d_out;
    (void)in_sizes; (void)n_in; (void)out_size; (void)ws_size;

    char* wsb = (char*)d_ws;
    size_t off = 0;
    auto alloc = [&](size_t bytes) -> void* {
        void* p = wsb + off;
        off += (bytes + 255) & ~(size_t)255;
        return p;
    };

    float*  gf  = (float*) alloc(2048L * 1024 * 4);
    __bf16* gsH = (__bf16*)alloc(2048L * 1024 * 2);
    __bf16* gsL = (__bf16*)alloc(2048L * 1024 * 2);
    float*  ne1 = (float*) alloc(65536L * 4);
    float*  ne2 = (float*) alloc(65536L * 4);
    auto allocWT = [&](int cout, int KP, __bf16** h, __bf16** l) {
        *h = (__bf16*)alloc((size_t)cout * KP * 2);
        *l = (__bf16*)alloc((size_t)cout * KP * 2);
    };
    __bf16 *wE0gH, *wE0gL, *wE0uH, *wE0uL, *wE1gH, *wE1gL, *wE1uH, *wE1uL;
    __bf16 *wD0gH, *wD0gL, *wD0uH, *wD0uL, *wD1gH, *wD1gL, *wD1uH, *wD1uL;
    allocWT(128, 352,  &wE0gH, &wE0gL);  allocWT(64, 352,  &wE0uH, &wE0uL);
    allocWT(128, 640,  &wE1gH, &wE1gL);  allocWT(64, 640,  &wE1uH, &wE1uL);
    allocWT(256, 672,  &wD0gH, &wD0gL);  allocWT(128, 672, &wD0uH, &wD0uL);
    allocWT(256, 1280, &wD1gH, &wD1gL);  allocWT(128, 1280, &wD1uH, &wD1uL);
    __bf16* RMh = (__bf16*)alloc((size_t)NB * 1280 * 2);
    __bf16* RMl = (__bf16*)alloc((size_t)NB * 1280 * 2);
    __bf16* Th  = (__bf16*)alloc((size_t)(5 * 4096 + 128) * 1024 * 2);
    __bf16* Tl  = (__bf16*)alloc((size_t)(5 * 4096 + 128) * 1024 * 2);
    float* zr  = (float*)alloc((size_t)NB * 256 * 4);
    float* h0e = (float*)alloc((size_t)NB * 64 * 4);
    float* h1e = (float*)alloc((size_t)NB * 64 * 4);
    float* dh0 = (float*)alloc((size_t)NB * 128 * 4);
    float* dh1 = (float*)alloc((size_t)NB * 128 * 4);
    float* gob = (float*)alloc((size_t)NB * 4);

    // ---- setup ----
    compute_ne<<<cdiv(2 * 65536, 256), 256, 0, stream>>>(We1, We2, Memory, ne1, ne2);
    build_g<<<2048, 256, 0, stream>>>(ne1, ne2, gf);
    g_split<<<cdiv(2048 * 1024, 256), 256, 0, stream>>>(gf, gsH, gsL);
    build_weffT<<<cdiv(128 * 352, 256), 256, 0, stream>>>(e0gw, wE0gH, wE0gL, 65, 128, 352);
    build_weffT<<<cdiv(64 * 352, 256), 256, 0, stream>>>(e0uw, wE0uH, wE0uL, 65, 64, 352);
    build_weffT<<<cdiv(128 * 640, 256), 256, 0, stream>>>(e1gw, wE1gH, wE1gL, 128, 128, 640);
    build_weffT<<<cdiv(64 * 640, 256), 256, 0, stream>>>(e1uw, wE1uH, wE1uL, 128, 64, 640);
    build_weffT<<<cdiv(256 * 672, 256), 256, 0, stream>>>(d0gw, wD0gH, wD0gL, 130, 256, 672);
    build_weffT<<<cdiv(128 * 672, 256), 256, 0, stream>>>(d0uw, wD0uH, wD0uL, 130, 128, 672);
    build_weffT<<<cdiv(256 * 1280, 256), 256, 0, stream>>>(d1gw, wD1gH, wD1gL, 256, 256, 1280);
    build_weffT<<<cdiv(128 * 1280, 256), 256, 0, stream>>>(d1uw, wD1uH, wD1uL, 256, 128, 1280);
    hipMemsetAsync(h0e, 0, (size_t)NB * 64 * 4, stream);
    hipMemsetAsync(h1e, 0, (size_t)NB * 64 * 4, stream);

    // hops (trans0 -> hop1 -> hop2) then trans-back, weight GEMM w/ fused epi
    auto agcn_core = [&](int c, int cin2, int KP, const __bf16* wth, const __bf16* wtl,
                         const float* bias, int cout, int epi, float* zrOrOut, float* hptr) {
        int Mfull = 16 * c, Moff = 16 * cin2, Mv = Mfull - Moff;
        dim3 t0(cdiv(c - cin2, 32), 16, 16);
        trans_kern<<<t0, 256, 0, stream>>>(Th, Tl, RMh, RMl, c, KP, cin2, c, 0, 0);
        const __bf16* A1h = Th + (size_t)Moff * 1024;
        const __bf16* A1l = Tl + (size_t)Moff * 1024;
        __bf16* C1h = Th + (size_t)(Mfull + Moff) * 1024;
        __bf16* C1l = Tl + (size_t)(Mfull + Moff) * 1024;
        __bf16* C2h = Th + (size_t)(3 * Mfull + Moff) * 1024;
        __bf16* C2l = Tl + (size_t)(3 * Mfull + Moff) * 1024;
        if (Mv < 2048) {
            dim3 g1(16, cdiv(Mv, 64), 1);
            mm_kern<64, 128, 0><<<g1, 256, 0, stream>>>(
                A1h, A1l, 1024, 0, gsH, gsL, 0, 1024, Mv, 32,
                C1h, C1l, nullptr, 1024, 0, 1024, (long)Mfull * 1024 - 1024,
                nullptr, nullptr, nullptr);
            dim3 g2(8, cdiv(Mv, 64), 2);
            mm_kern<64, 128, 0><<<g2, 256, 0, stream>>>(
                C1h, C1l, 1024, (long)Mfull * 1024, gsH, gsL, (long)1024 * 1024, 1024, Mv, 32,
                C2h, C2l, nullptr, 1024, (long)Mfull * 1024, 1 << 30, 0,
                nullptr, nullptr, nullptr);
        } else {
            dim3 g1(16, cdiv(Mv, 128), 1);
            mm_kern<128, 128, 0><<<g1, 256, 0, stream>>>(
                A1h, A1l, 1024, 0, gsH, gsL, 0, 1024, Mv, 32,
                C1h, C1l, nullptr, 1024, 0, 1024, (long)Mfull * 1024 - 1024,
                nullptr, nullptr, nullptr);
            dim3 g2(8, cdiv(Mv, 128), 2);
            mm_kern<128, 128, 0><<<g2, 256, 0, stream>>>(
                C1h, C1l, 1024, (long)Mfull * 1024, gsH, gsL, (long)1024 * 1024, 1024, Mv, 32,
                C2h, C2l, nullptr, 1024, (long)Mfull * 1024, 1 << 30, 0,
                nullptr, nullptr, nullptr);
        }
        dim3 t1(cdiv(4 * c, 32), 16, 16);
        trans_kern<<<t1, 256, 0, stream>>>(Th, Tl, RMh, RMl, c, KP, c, 5 * c, cin2, 1);
        if (epi == 1) {
            if (cout == 256) {
                dim3 gw(2, 128, 1);
                mm_kern<128, 128, 1><<<gw, 256, 0, stream>>>(
                    RMh, RMl, KP, 0, wth, wtl, 0, KP, NB, KP / 32,
                    nullptr, nullptr, zrOrOut, cout, 0, 1 << 30, 0, bias, nullptr, nullptr);
            } else {
                dim3 gw(2, 128, 1);
                mm_kern<128, 64, 1><<<gw, 256, 0, stream>>>(
                    RMh, RMl, KP, 0, wth, wtl, 0, KP, NB, KP / 32,
                    nullptr, nullptr, zrOrOut, cout, 0, 1 << 30, 0, bias, nullptr, nullptr);
            }
        } else {   // epi 3: tanh + fused GRU update into hptr
            if (cout == 64) {
                dim3 gw(1, 256, 1);
                mm_kern<64, 64, 3><<<gw, 256, 0, stream>>>(
                    RMh, RMl, KP, 0, wth, wtl, 0, KP, NB, KP / 32,
                    nullptr, nullptr, nullptr, cout, 0, 1 << 30, 0, bias, zrOrOut, hptr);
            } else {
                dim3 gw(2, 128, 1);
                mm_kern<128, 64, 3><<<gw, 256, 0, stream>>>(
                    RMh, RMl, KP, 0, wth, wtl, 0, KP, NB, KP / 32,
                    nullptr, nullptr, nullptr, cout, 0, 1 << 30, 0, bias, zrOrOut, hptr);
            }
        }
    };

    // ---- encoder ----
    for (int t = 0; t < TT; ++t) {
        xcat_kern<0><<<cdiv(NB * 92, 256), 256, 0, stream>>>(RMh, RMl, x, nullptr, h0e, nullptr, t, 0, 92, 352);
        agcn_core(65, 0, 352, wE0gH, wE0gL, e0gb, 128, 1, zr, nullptr);
        xcat_kern<1><<<cdiv(NB * 64, 256), 256, 0, stream>>>(RMh, RMl, x, nullptr, h0e, zr, t, 1, 64, 352);
        agcn_core(65, 1, 352, wE0uH, wE0uL, e0ub, 64, 3, zr, h0e);
        xcat_kern<2><<<cdiv(NB * 128, 256), 256, 0, stream>>>(RMh, RMl, h0e, nullptr, h1e, nullptr, t, 0, 128, 640);
        agcn_core(128, 0, 640, wE1gH, wE1gL, e1gb, 128, 1, zr, nullptr);
        xcat_kern<3><<<cdiv(NB * 64, 256), 256, 0, stream>>>(RMh, RMl, h0e, nullptr, h1e, zr, t, 64, 64, 640);
        agcn_core(128, 64, 640, wE1uH, wE1uL, e1ub, 64, 3, zr, h1e);
    }

    // ---- memory attention ----
    attention<<<NB, 64, 0, stream>>>(h1e, Wq, Memory, dh0);
    hipMemcpyAsync(dh1, dh0, (size_t)NB * 128 * 4, hipMemcpyDeviceToDevice, stream);
    hipMemsetAsync(gob, 0, (size_t)NB * 4, stream);

    // ---- decoder ----
    for (int t = 0; t < TT; ++t) {
        xcat_kern<4><<<cdiv(NB * 152, 256), 256, 0, stream>>>(RMh, RMl, gob, y_cov, dh0, nullptr, t, 0, 152, 672);
        agcn_core(130, 0, 672, wD0gH, wD0gL, d0gb, 256, 1, zr, nullptr);
        xcat_kern<5><<<cdiv(NB * 128, 256), 256, 0, stream>>>(RMh, RMl, gob, y_cov, dh0, zr, t, 2, 128, 672);
        agcn_core(130, 2, 672, wD0uH, wD0uL, d0ub, 128, 3, zr, dh0);
        xcat_kern<6><<<cdiv(NB * 256, 256), 256, 0, stream>>>(RMh, RMl, dh0, nullptr, dh1, nullptr, t, 0, 256, 1280);
        agcn_core(256, 0, 1280, wD1gH, wD1gL, d1gb, 256, 1, zr, nullptr);
        xcat_kern<7><<<cdiv(NB * 128, 256), 256, 0, stream>>>(RMh, RMl, dh0, nullptr, dh1, zr, t, 128, 128, 1280);
        agcn_core(256, 128, 1280, wD1uH, wD1uL, d1ub, 128, 3, zr, dh1);
        proj_out<<<cdiv(NB, 256), 256, 0, stream>>>(dh1, proj_w, proj_b, gob, out, t);
    }
}

// Round 4
// 14282.333 us; speedup vs baseline: 3.4310x; 1.2521x over previous
//
#include <hip/hip_runtime.h>
#include <math.h>

#define NNODE 1024
#define BATCH 16
#define NB    16384
#define TT    12

typedef __bf16 bf16x8 __attribute__((ext_vector_type(8)));
typedef float  f32x4  __attribute__((ext_vector_type(4)));

static inline int cdiv(int a, int b) { return (a + b - 1) / b; }

// async global->LDS, 16B per lane, wave-uniform LDS base + lane*16
__device__ inline void gll16(const void* g, void* l) {
    __builtin_amdgcn_global_load_lds(
        (const __attribute__((address_space(1))) void*)g,
        (__attribute__((address_space(3))) void*)l, 16, 0, 0);
}

// ---------------------------------------------------------------------------
// Split-bf16 GEMM, 2-phase double-buffered pipeline, coalesced staging.
// D[i][j] = sum_k A[i][k]*B[j][k]  (both k-contig), 3-pass hi/lo split.
// LDS per plane: row-major [R][32elem]; 16B k-slot XOR-swizzled via the
// GLOBAL source address (slot ^ ((row>>1)&3)) so gll16 dest stays linear and
// ds_read_b128 is 2-way-conflict-free. One gll16 = 16 rows x 64B segments.
// EPI 0: split-store bf16 hi/lo (Ch/Cl) with nsplit/splitAdd col relocation
// EPI 1: +bias, sigmoid -> Cf
// EPI 3: +bias, tanh, fused GRU: hout = r*hout + (1-r)*hc  (r from zrp)
// ---------------------------------------------------------------------------
template<int BM, int BN, int EPI>
__global__ __launch_bounds__(256) void mm_kern(
    const __bf16* __restrict__ Ah, const __bf16* __restrict__ Al, long lda, long zA,
    const __bf16* __restrict__ Bh, const __bf16* __restrict__ Bl, long zB, long ldb,
    int M, int Ksteps,
    __bf16* __restrict__ Ch, __bf16* __restrict__ Cl, float* __restrict__ Cf,
    long ldc, long zC, int nsplit, long splitAdd,
    const float* __restrict__ bias, const float* __restrict__ zrp,
    float* __restrict__ hout)
{
    constexpr int WM = BM / 2, WN = BN / 2;
    constexpr int MF = WM / 16, NF = WN / 16;
    constexpr int nA = BM / 16, nB = BN / 16;       // 1KB chunks per plane
    constexpr int NP = (2 * nA + 2 * nB) / 4;       // chunks per wave
    constexpr int BUFE = (BM + BN) * 64;            // elems per LDS buffer
    // plane bases (elems): AH=0 | AL=BM*32 | BH=BM*64 | BL=BM*64+BN*32
    __shared__ __bf16 smem[2 * BUFE];

    const int bm = blockIdx.y * BM, bn = blockIdx.x * BN;
    const int tid = threadIdx.x, w = tid >> 6, lane = tid & 63;
    const int wr = w >> 1, wc = w & 1;
    const int lgrp = lane >> 4, lrow = lane & 15;

    Ah += (size_t)blockIdx.z * zA;  Al += (size_t)blockIdx.z * zA;
    Bh += (size_t)blockIdx.z * zB;  Bl += (size_t)blockIdx.z * zB;

    // staging: chunk q covers 16 rows; lane l -> row qq*16+(l>>2),
    // global k-slot = (l&3) ^ ((l>>3)&3)  (the source-side swizzle)
    const int srow = lane >> 2;
    const int kgel = ((lane & 3) ^ ((lane >> 3) & 3)) * 8;
    const __bf16* sp[NP];
    int dpo[NP];
#pragma unroll
    for (int p = 0; p < NP; ++p) {
        int q = p * 4 + w;
        int tile = (q < nA) ? 0 : (q < 2 * nA) ? 1 : (q < 2 * nA + nB) ? 2 : 3;
        int qq = q - ((tile == 0) ? 0 : (tile == 1) ? nA : (tile == 2) ? 2 * nA : 2 * nA + nB);
        const __bf16* base = (tile == 0) ? Ah : (tile == 1) ? Al : (tile == 2) ? Bh : Bl;
        long ld = (tile < 2) ? lda : ldb;
        int  rb = (tile < 2) ? bm : bn;
        sp[p] = base + (size_t)(rb + qq * 16 + srow) * ld + kgel;
        int tbase = (tile == 0) ? 0 : (tile == 1) ? BM * 32 : (tile == 2) ? BM * 64 : (BM * 64 + BN * 32);
        dpo[p] = tbase * 2 + qq * 1024;   // bytes; lane*16 appended by HW
    }

    f32x4 acc[MF][NF];
#pragma unroll
    for (int i = 0; i < MF; ++i)
#pragma unroll
        for (int j = 0; j < NF; ++j)
#pragma unroll
            for (int e = 0; e < 4; ++e) acc[i][j][e] = 0.f;

    auto stage = [&](int kt, int bsel) {
        char* lb = (char*)smem + bsel * (BUFE * 2);
#pragma unroll
        for (int p = 0; p < NP; ++p) gll16(sp[p] + (size_t)kt * 32, lb + dpo[p]);
    };

    stage(0, 0);
    __syncthreads();                       // drains vmcnt(0): buf0 ready

    // read-side swizzled slot offset (elems), lane-constant
    const int slotOff = (lgrp ^ ((lrow >> 1) & 3)) * 8;

    for (int kt = 0; kt < Ksteps; ++kt) {
        const int cur = kt & 1;
        if (kt + 1 < Ksteps) stage(kt + 1, cur ^ 1);   // overlap with compute
        const __bf16* sb = smem + cur * BUFE;

        bf16x8 aH[MF], aL[MF], bHf[NF], bLf[NF];
#pragma unroll
        for (int mf = 0; mf < MF; ++mf) {
            int row = wr * WM + mf * 16 + lrow;
            aH[mf] = *(const bf16x8*)(sb + (size_t)row * 32 + slotOff);
            aL[mf] = *(const bf16x8*)(sb + BM * 32 + (size_t)row * 32 + slotOff);
        }
#pragma unroll
        for (int nf = 0; nf < NF; ++nf) {
            int col = wc * WN + nf * 16 + lrow;
            bHf[nf] = *(const bf16x8*)(sb + BM * 64 + (size_t)col * 32 + slotOff);
            bLf[nf] = *(const bf16x8*)(sb + BM * 64 + BN * 32 + (size_t)col * 32 + slotOff);
        }
#pragma unroll
        for (int mf = 0; mf < MF; ++mf)
#pragma unroll
            for (int nf = 0; nf < NF; ++nf) {
                acc[mf][nf] = __builtin_amdgcn_mfma_f32_16x16x32_bf16(aH[mf], bHf[nf], acc[mf][nf], 0, 0, 0);
                acc[mf][nf] = __builtin_amdgcn_mfma_f32_16x16x32_bf16(aH[mf], bLf[nf], acc[mf][nf], 0, 0, 0);
                acc[mf][nf] = __builtin_amdgcn_mfma_f32_16x16x32_bf16(aL[mf], bHf[nf], acc[mf][nf], 0, 0, 0);
            }
        __syncthreads();                   // drain vmcnt (next buf ready) + barrier
    }

    const size_t cz = (size_t)blockIdx.z * zC;
    const long cadj = (bn >= nsplit) ? splitAdd : 0;
#pragma unroll
    for (int mf = 0; mf < MF; ++mf) {
        int gi0 = bm + wr * WM + mf * 16 + lgrp * 4;
#pragma unroll
        for (int nf = 0; nf < NF; ++nf) {
            int gj = bn + wc * WN + nf * 16 + lrow;
#pragma unroll
            for (int r = 0; r < 4; ++r) {
                int gi = gi0 + r;
                if (gi < M) {
                    float v = acc[mf][nf][r];
                    if (EPI == 0) {
                        size_t cix = cz + (size_t)gi * ldc + gj + cadj;
                        __bf16 h = (__bf16)v;
                        Ch[cix] = h;
                        Cl[cix] = (__bf16)(v - (float)h);
                    } else if (EPI == 1) {
                        v += bias[gj];
                        v = 1.f / (1.f + expf(-v));
                        Cf[cz + (size_t)gi * ldc + gj] = v;
                    } else {
                        v += bias[gj];
                        v = tanhf(v);
                        float rg = zrp[(size_t)gi * 2 * ldc + ldc + gj];
                        size_t hix = (size_t)gi * ldc + gj;
                        hout[hix] = rg * hout[hix] + (1.f - rg) * v;
                    }
                }
            }
        }
    }
}

// ---------------------------------------------------------------------------
// LDS-tiled transpose between RM slots [(n*16+b)][KP] and T slots
// [s][i*16+b][node]. dir 0: RM->T, dir 1: T->RM. Skip i<iMin.
// ---------------------------------------------------------------------------
__global__ __launch_bounds__(256) void trans_kern(
    __bf16* __restrict__ TH, __bf16* __restrict__ TL,
    __bf16* __restrict__ RH, __bf16* __restrict__ RL,
    int c, int KP, int kk0, int kkEnd, int iMin, int dir)
{
    __shared__ __bf16 tile[32][66];
    const int b = blockIdx.z, nt = blockIdx.y * 64;
    const int kkb = kk0 + blockIdx.x * 32;
    const int t = threadIdx.x;
    const int c16 = 16 * c;

    for (int cp = 0; cp < 2; ++cp) {
        __bf16* Tp = cp ? TL : TH;
        __bf16* Rp = cp ? RL : RH;
        if (dir == 0) {
#pragma unroll
            for (int rep = 0; rep < 8; ++rep) {
                int kk = kkb + (t & 31);
                int nl = rep * 8 + (t >> 5);
                __bf16 v = (__bf16)0.f;
                if (kk < kkEnd) v = Rp[(size_t)((nt + nl) * 16 + b) * KP + kk];
                tile[t & 31][nl] = v;
            }
            __syncthreads();
#pragma unroll
            for (int rep = 0; rep < 8; ++rep) {
                int kkl = rep * 4 + (t >> 6);
                int kk = kkb + kkl;
                int n = nt + (t & 63);
                if (kk < kkEnd) {
                    int s = (kk >= c) + (kk >= 2 * c) + (kk >= 3 * c) + (kk >= 4 * c);
                    int i = kk - s * c;
                    if (i >= iMin)
                        Tp[((size_t)s * c16 + i * 16 + b) * 1024 + n] = tile[kkl][t & 63];
                }
            }
        } else {
#pragma unroll
            for (int rep = 0; rep < 8; ++rep) {
                int kkl = rep * 4 + (t >> 6);
                int kk = kkb + kkl;
                int n = nt + (t & 63);
                __bf16 v = (__bf16)0.f;
                if (kk < kkEnd) {
                    int s = (kk >= c) + (kk >= 2 * c) + (kk >= 3 * c) + (kk >= 4 * c);
                    int i = kk - s * c;
                    if (i >= iMin)
                        v = Tp[((size_t)s * c16 + i * 16 + b) * 1024 + n];
                }
                tile[kkl][t & 63] = v;
            }
            __syncthreads();
#pragma unroll
            for (int rep = 0; rep < 8; ++rep) {
                int kk = kkb + (t & 31);
                int nl = rep * 8 + (t >> 5);
                if (kk < kkEnd) {
                    int s = (kk >= c) + (kk >= 2 * c) + (kk >= 3 * c) + (kk >= 4 * c);
                    int i = kk - s * c;
                    if (i >= iMin)
                        Rp[(size_t)((nt + nl) * 16 + b) * KP + kk] = tile[t & 31][nl];
                }
            }
        }
        __syncthreads();
    }
}

// ---------------------------------------------------------------------------
// Build concat input into RM slot 0, split to bf16 hi/lo.
// ---------------------------------------------------------------------------
template<int MODE>
__global__ __launch_bounds__(256) void xcat_kern(
    __bf16* __restrict__ dH, __bf16* __restrict__ dL,
    const float* __restrict__ s1, const float* __restrict__ s2,
    const float* __restrict__ h, const float* __restrict__ zr,
    int t, int ccStart, int width, int KP)
{
    constexpr int C = (MODE < 2) ? 65 : (MODE < 4) ? 128 : (MODE < 6) ? 130 : 256;
    int idx = blockIdx.x * 256 + threadIdx.x;
    if (idx >= NB * width) return;
    int r = idx / width, ww = idx - r * width;
    int hspan = C - ccStart;
    int cc = (ww < hspan) ? (ccStart + ww) : (5 * C + (ww - hspan));
    int n = r >> 4, b = r & 15;
    float v = 0.f;
    if (cc < C) {
        if (MODE == 0 || MODE == 1) {
            if (cc == 0) v = s1[((size_t)b * TT + t) * NNODE + n];
            else { float hv = h[(size_t)r * 64 + cc - 1];
                   v = (MODE == 1) ? zr[(size_t)r * 128 + cc - 1] * hv : hv; }
        } else if (MODE == 2 || MODE == 3) {
            if (cc < 64) v = s1[(size_t)r * 64 + cc];
            else { float hv = h[(size_t)r * 64 + cc - 64];
                   v = (MODE == 3) ? zr[(size_t)r * 128 + cc - 64] * hv : hv; }
        } else if (MODE == 4 || MODE == 5) {
            if (cc == 0) v = s1[r];
            else if (cc == 1) v = s2[((size_t)b * TT + t) * NNODE + n];
            else { float hv = h[(size_t)r * 128 + cc - 2];
                   v = (MODE == 5) ? zr[(size_t)r * 256 + cc - 2] * hv : hv; }
        } else {
            if (cc < 128) v = s1[(size_t)r * 128 + cc];
            else { float hv = h[(size_t)r * 128 + cc - 128];
                   v = (MODE == 7) ? zr[(size_t)r * 256 + cc - 128] * hv : hv; }
        }
    }
    __bf16 hi = (__bf16)v;
    size_t o = (size_t)r * KP + cc;
    dH[o] = hi;
    dL[o] = (__bf16)(v - (float)hi);
}

// ---------------------------------------------------------------------------
// small kernels
// ---------------------------------------------------------------------------
__global__ __launch_bounds__(256) void compute_ne(
    const float* __restrict__ We1, const float* __restrict__ We2,
    const float* __restrict__ Mem, float* __restrict__ ne1, float* __restrict__ ne2)
{
    int idx = blockIdx.x * 256 + threadIdx.x;
    if (idx >= 2 * 65536) return;
    int which = idx >> 16;
    int i = idx & 65535;
    int n = i >> 6, d = i & 63;
    const float* We = which ? We2 : We1;
    float acc = 0.f;
#pragma unroll
    for (int k = 0; k < 20; ++k) acc += We[n * 20 + k] * Mem[k * 64 + d];
    (which ? ne2 : ne1)[i] = acc;
}

__global__ __launch_bounds__(256) void build_g(
    const float* __restrict__ ne1, const float* __restrict__ ne2, float* __restrict__ g)
{
    int row = blockIdx.x;
    int n = row & 1023;
    const float* qa = (row < 1024) ? ne1 : ne2;
    const float* kb = (row < 1024) ? ne2 : ne1;
    __shared__ float q[64];
    __shared__ float sc[1024];
    __shared__ float red[256];
    int tid = threadIdx.x;
    if (tid < 64) q[tid] = qa[n * 64 + tid];
    __syncthreads();
    for (int m = tid; m < 1024; m += 256) {
        float acc = 0.f;
        const float* kr = kb + m * 64;
#pragma unroll 8
        for (int d = 0; d < 64; ++d) acc += q[d] * kr[d];
        sc[m] = fmaxf(acc, 0.f);
    }
    __syncthreads();
    float mx = -1e30f;
    for (int m = tid; m < 1024; m += 256) mx = fmaxf(mx, sc[m]);
    red[tid] = mx;
    __syncthreads();
    for (int s2 = 128; s2 > 0; s2 >>= 1) {
        if (tid < s2) red[tid] = fmaxf(red[tid], red[tid + s2]);
        __syncthreads();
    }
    mx = red[0];
    __syncthreads();
    float sum = 0.f;
    for (int m = tid; m < 1024; m += 256) {
        float e = expf(sc[m] - mx);
        sc[m] = e;
        sum += e;
    }
    red[tid] = sum;
    __syncthreads();
    for (int s2 = 128; s2 > 0; s2 >>= 1) {
        if (tid < s2) red[tid] += red[tid + s2];
        __syncthreads();
    }
    float inv = 1.f / red[0];
    for (int m = tid; m < 1024; m += 256) g[(size_t)row * 1024 + m] = sc[m] * inv;
}

__global__ __launch_bounds__(256) void g_split(
    const float* __restrict__ g, __bf16* __restrict__ gh, __bf16* __restrict__ gl)
{
    int i = blockIdx.x * 256 + threadIdx.x;
    if (i >= 2048 * 1024) return;
    float v = g[i];
    __bf16 h = (__bf16)v;
    gh[i] = h;
    gl[i] = (__bf16)(v - (float)h);
}

__global__ __launch_bounds__(256) void build_weffT(
    const float* __restrict__ W, __bf16* __restrict__ dh, __bf16* __restrict__ dl,
    int c, int cout, int KP)
{
    int idx = blockIdx.x * 256 + threadIdx.x;
    if (idx >= cout * KP) return;
    int o = idx / KP, kk = idx - o * KP;
    float v = 0.f;
    if (kk < 5 * c) {
        int s = (kk >= c) + (kk >= 2 * c) + (kk >= 3 * c) + (kk >= 4 * c);
        int i = kk - s * c;
        if      (s == 0) v = W[(size_t)(0 * c + i) * cout + o] + W[(size_t)(3 * c + i) * cout + o]
                           - W[(size_t)(2 * c + i) * cout + o] - W[(size_t)(5 * c + i) * cout + o];
        else if (s == 1) v = W[(size_t)(1 * c + i) * cout + o];
        else if (s == 2) v = W[(size_t)(4 * c + i) * cout + o];
        else if (s == 3) v = 2.f * W[(size_t)(2 * c + i) * cout + o];
        else             v = 2.f * W[(size_t)(5 * c + i) * cout + o];
    }
    __bf16 h = (__bf16)v;
    dh[idx] = h;
    dl[idx] = (__bf16)(v - (float)h);
}

__global__ __launch_bounds__(64) void attention(
    const float* __restrict__ h, const float* __restrict__ Wq,
    const float* __restrict__ Mem, float* __restrict__ htc)
{
    int r = blockIdx.x;
    int j = threadIdx.x;
    __shared__ float hr[64], q[64], sc[20];
    hr[j] = h[(size_t)r * 64 + j];
    __syncthreads();
    float acc = 0.f;
#pragma unroll 8
    for (int i = 0; i < 64; ++i) acc += hr[i] * Wq[i * 64 + j];
    q[j] = acc;
    __syncthreads();
    if (j < 20) {
        float a = 0.f;
#pragma unroll 8
        for (int d = 0; d < 64; ++d) a += q[d] * Mem[j * 64 + d];
        sc[j] = a;
    }
    __syncthreads();
    if (j == 0) {
        float mx = sc[0];
        for (int m = 1; m < 20; ++m) mx = fmaxf(mx, sc[m]);
        float s = 0.f;
        for (int m = 0; m < 20; ++m) { sc[m] = expf(sc[m] - mx); s += sc[m]; }
        float inv = 1.f / s;
        for (int m = 0; m < 20; ++m) sc[m] *= inv;
    }
    __syncthreads();
    float v = 0.f;
#pragma unroll
    for (int m = 0; m < 20; ++m) v += sc[m] * Mem[m * 64 + j];
    htc[(size_t)r * 128 + j] = hr[j];
    htc[(size_t)r * 128 + 64 + j] = v;
}

__global__ __launch_bounds__(256) void proj_out(
    const float* __restrict__ h1, const float* __restrict__ pw, const float* __restrict__ pb,
    float* __restrict__ go, float* __restrict__ out, int t)
{
    int r = blockIdx.x * 256 + threadIdx.x;
    if (r >= NB) return;
    float acc = pb[0];
    const float* hr = h1 + (size_t)r * 128;
#pragma unroll 8
    for (int i = 0; i < 128; ++i) acc += hr[i] * pw[i];
    go[r] = acc;
    int n = r >> 4, b = r & 15;
    out[((size_t)b * TT + t) * NNODE + n] = acc;
}

// ---------------------------------------------------------------------------
// host
// ---------------------------------------------------------------------------
extern "C" void kernel_launch(void* const* d_in, const int* in_sizes, int n_in,
                              void* d_out, int out_size, void* d_ws, size_t ws_size,
                              hipStream_t stream)
{
    const float* x      = (const float*)d_in[0];
    const float* y_cov  = (const float*)d_in[1];
    const float* Memory = (const float*)d_in[2];
    const float* Wq     = (const float*)d_in[3];
    const float* We1    = (const float*)d_in[4];
    const float* We2    = (const float*)d_in[5];
    const float* e0gw = (const float*)d_in[6];  const float* e0gb = (const float*)d_in[7];
    const float* e0uw = (const float*)d_in[8];  const float* e0ub = (const float*)d_in[9];
    const float* e1gw = (const float*)d_in[10]; const float* e1gb = (const float*)d_in[11];
    const float* e1uw = (const float*)d_in[12]; const float* e1ub = (const float*)d_in[13];
    const float* d0gw = (const float*)d_in[14]; const float* d0gb = (const float*)d_in[15];
    const float* d0uw = (const float*)d_in[16]; const float* d0ub = (const float*)d_in[17];
    const float* d1gw = (const float*)d_in[18]; const float* d1gb = (const float*)d_in[19];
    const float* d1uw = (const float*)d_in[20]; const float* d1ub = (const float*)d_in[21];
    const float* proj_w = (const float*)d_in[22];
    const float* proj_b = (const float*)d_in[23];
    float* out = (float*)d_out;
    (void)in_sizes; (void)n_in; (void)out_size; (void)ws_size;

    char* wsb = (char*)d_ws;
    size_t off = 0;
    auto alloc = [&](size_t bytes) -> void* {
        void* p = wsb + off;
        off += (bytes + 255) & ~(size_t)255;
        return p;
    };

    float*  gf  = (float*) alloc(2048L * 1024 * 4);
    __bf16* gsH = (__bf16*)alloc(2048L * 1024 * 2);
    __bf16* gsL = (__bf16*)alloc(2048L * 1024 * 2);
    float*  ne1 = (float*) alloc(65536L * 4);
    float*  ne2 = (float*) alloc(65536L * 4);
    auto allocWT = [&](int cout, int KP, __bf16** h, __bf16** l) {
        *h = (__bf16*)alloc((size_t)cout * KP * 2);
        *l = (__bf16*)alloc((size_t)cout * KP * 2);
    };
    __bf16 *wE0gH, *wE0gL, *wE0uH, *wE0uL, *wE1gH, *wE1gL, *wE1uH, *wE1uL;
    __bf16 *wD0gH, *wD0gL, *wD0uH, *wD0uL, *wD1gH, *wD1gL, *wD1uH, *wD1uL;
    allocWT(128, 352,  &wE0gH, &wE0gL);  allocWT(64, 352,  &wE0uH, &wE0uL);
    allocWT(128, 640,  &wE1gH, &wE1gL);  allocWT(64, 640,  &wE1uH, &wE1uL);
    allocWT(256, 672,  &wD0gH, &wD0gL);  allocWT(128, 672, &wD0uH, &wD0uL);
    allocWT(256, 1280, &wD1gH, &wD1gL);  allocWT(128, 1280, &wD1uH, &wD1uL);
    __bf16* RMh = (__bf16*)alloc((size_t)NB * 1280 * 2);
    __bf16* RMl = (__bf16*)alloc((size_t)NB * 1280 * 2);
    __bf16* Th  = (__bf16*)alloc((size_t)(5 * 4096 + 128) * 1024 * 2);
    __bf16* Tl  = (__bf16*)alloc((size_t)(5 * 4096 + 128) * 1024 * 2);
    float* zr  = (float*)alloc((size_t)NB * 256 * 4);
    float* h0e = (float*)alloc((size_t)NB * 64 * 4);
    float* h1e = (float*)alloc((size_t)NB * 64 * 4);
    float* dh0 = (float*)alloc((size_t)NB * 128 * 4);
    float* dh1 = (float*)alloc((size_t)NB * 128 * 4);
    float* gob = (float*)alloc((size_t)NB * 4);

    // ---- setup ----
    compute_ne<<<cdiv(2 * 65536, 256), 256, 0, stream>>>(We1, We2, Memory, ne1, ne2);
    build_g<<<2048, 256, 0, stream>>>(ne1, ne2, gf);
    g_split<<<cdiv(2048 * 1024, 256), 256, 0, stream>>>(gf, gsH, gsL);
    build_weffT<<<cdiv(128 * 352, 256), 256, 0, stream>>>(e0gw, wE0gH, wE0gL, 65, 128, 352);
    build_weffT<<<cdiv(64 * 352, 256), 256, 0, stream>>>(e0uw, wE0uH, wE0uL, 65, 64, 352);
    build_weffT<<<cdiv(128 * 640, 256), 256, 0, stream>>>(e1gw, wE1gH, wE1gL, 128, 128, 640);
    build_weffT<<<cdiv(64 * 640, 256), 256, 0, stream>>>(e1uw, wE1uH, wE1uL, 128, 64, 640);
    build_weffT<<<cdiv(256 * 672, 256), 256, 0, stream>>>(d0gw, wD0gH, wD0gL, 130, 256, 672);
    build_weffT<<<cdiv(128 * 672, 256), 256, 0, stream>>>(d0uw, wD0uH, wD0uL, 130, 128, 672);
    build_weffT<<<cdiv(256 * 1280, 256), 256, 0, stream>>>(d1gw, wD1gH, wD1gL, 256, 256, 1280);
    build_weffT<<<cdiv(128 * 1280, 256), 256, 0, stream>>>(d1uw, wD1uH, wD1uL, 256, 128, 1280);
    hipMemsetAsync(h0e, 0, (size_t)NB * 64 * 4, stream);
    hipMemsetAsync(h1e, 0, (size_t)NB * 64 * 4, stream);

    // hops (trans0 -> hop1 -> hop2) then trans-back, weight GEMM w/ fused epi
    auto agcn_core = [&](int c, int cin2, int KP, const __bf16* wth, const __bf16* wtl,
                         const float* bias, int cout, int epi, float* zrOrOut, float* hptr) {
        int Mfull = 16 * c, Moff = 16 * cin2, Mv = Mfull - Moff;
        dim3 t0(cdiv(c - cin2, 32), 16, 16);
        trans_kern<<<t0, 256, 0, stream>>>(Th, Tl, RMh, RMl, c, KP, cin2, c, 0, 0);
        const __bf16* A1h = Th + (size_t)Moff * 1024;
        const __bf16* A1l = Tl + (size_t)Moff * 1024;
        __bf16* C1h = Th + (size_t)(Mfull + Moff) * 1024;
        __bf16* C1l = Tl + (size_t)(Mfull + Moff) * 1024;
        __bf16* C2h = Th + (size_t)(3 * Mfull + Moff) * 1024;
        __bf16* C2l = Tl + (size_t)(3 * Mfull + Moff) * 1024;
        if (Mv < 2048) {
            dim3 g1(16, cdiv(Mv, 64), 1);
            mm_kern<64, 128, 0><<<g1, 256, 0, stream>>>(
                A1h, A1l, 1024, 0, gsH, gsL, 0, 1024, Mv, 32,
                C1h, C1l, nullptr, 1024, 0, 1024, (long)Mfull * 1024 - 1024,
                nullptr, nullptr, nullptr);
            dim3 g2(8, cdiv(Mv, 64), 2);
            mm_kern<64, 128, 0><<<g2, 256, 0, stream>>>(
                C1h, C1l, 1024, (long)Mfull * 1024, gsH, gsL, (long)1024 * 1024, 1024, Mv, 32,
                C2h, C2l, nullptr, 1024, (long)Mfull * 1024, 1 << 30, 0,
                nullptr, nullptr, nullptr);
        } else {
            dim3 g1(16, cdiv(Mv, 128), 1);
            mm_kern<128, 128, 0><<<g1, 256, 0, stream>>>(
                A1h, A1l, 1024, 0, gsH, gsL, 0, 1024, Mv, 32,
                C1h, C1l, nullptr, 1024, 0, 1024, (long)Mfull * 1024 - 1024,
                nullptr, nullptr, nullptr);
            dim3 g2(8, cdiv(Mv, 128), 2);
            mm_kern<128, 128, 0><<<g2, 256, 0, stream>>>(
                C1h, C1l, 1024, (long)Mfull * 1024, gsH, gsL, (long)1024 * 1024, 1024, Mv, 32,
                C2h, C2l, nullptr, 1024, (long)Mfull * 1024, 1 << 30, 0,
                nullptr, nullptr, nullptr);
        }
        dim3 t1(cdiv(4 * c, 32), 16, 16);
        trans_kern<<<t1, 256, 0, stream>>>(Th, Tl, RMh, RMl, c, KP, c, 5 * c, cin2, 1);
        if (epi == 1) {
            if (cout == 256) {
                dim3 gw(2, 128, 1);
                mm_kern<128, 128, 1><<<gw, 256, 0, stream>>>(
                    RMh, RMl, KP, 0, wth, wtl, 0, KP, NB, KP / 32,
                    nullptr, nullptr, zrOrOut, cout, 0, 1 << 30, 0, bias, nullptr, nullptr);
            } else {
                dim3 gw(2, 128, 1);
                mm_kern<128, 64, 1><<<gw, 256, 0, stream>>>(
                    RMh, RMl, KP, 0, wth, wtl, 0, KP, NB, KP / 32,
                    nullptr, nullptr, zrOrOut, cout, 0, 1 << 30, 0, bias, nullptr, nullptr);
            }
        } else {   // epi 3: tanh + fused GRU update into hptr
            if (cout == 64) {
                dim3 gw(1, 256, 1);
                mm_kern<64, 64, 3><<<gw, 256, 0, stream>>>(
                    RMh, RMl, KP, 0, wth, wtl, 0, KP, NB, KP / 32,
                    nullptr, nullptr, nullptr, cout, 0, 1 << 30, 0, bias, zrOrOut, hptr);
            } else {
                dim3 gw(2, 128, 1);
                mm_kern<128, 64, 3><<<gw, 256, 0, stream>>>(
                    RMh, RMl, KP, 0, wth, wtl, 0, KP, NB, KP / 32,
                    nullptr, nullptr, nullptr, cout, 0, 1 << 30, 0, bias, zrOrOut, hptr);
            }
        }
    };

    // ---- encoder ----
    for (int t = 0; t < TT; ++t) {
        xcat_kern<0><<<cdiv(NB * 92, 256), 256, 0, stream>>>(RMh, RMl, x, nullptr, h0e, nullptr, t, 0, 92, 352);
        agcn_core(65, 0, 352, wE0gH, wE0gL, e0gb, 128, 1, zr, nullptr);
        xcat_kern<1><<<cdiv(NB * 64, 256), 256, 0, stream>>>(RMh, RMl, x, nullptr, h0e, zr, t, 1, 64, 352);
        agcn_core(65, 1, 352, wE0uH, wE0uL, e0ub, 64, 3, zr, h0e);
        xcat_kern<2><<<cdiv(NB * 128, 256), 256, 0, stream>>>(RMh, RMl, h0e, nullptr, h1e, nullptr, t, 0, 128, 640);
        agcn_core(128, 0, 640, wE1gH, wE1gL, e1gb, 128, 1, zr, nullptr);
        xcat_kern<3><<<cdiv(NB * 64, 256), 256, 0, stream>>>(RMh, RMl, h0e, nullptr, h1e, zr, t, 64, 64, 640);
        agcn_core(128, 64, 640, wE1uH, wE1uL, e1ub, 64, 3, zr, h1e);
    }

    // ---- memory attention ----
    attention<<<NB, 64, 0, stream>>>(h1e, Wq, Memory, dh0);
    hipMemcpyAsync(dh1, dh0, (size_t)NB * 128 * 4, hipMemcpyDeviceToDevice, stream);
    hipMemsetAsync(gob, 0, (size_t)NB * 4, stream);

    // ---- decoder ----
    for (int t = 0; t < TT; ++t) {
        xcat_kern<4><<<cdiv(NB * 152, 256), 256, 0, stream>>>(RMh, RMl, gob, y_cov, dh0, nullptr, t, 0, 152, 672);
        agcn_core(130, 0, 672, wD0gH, wD0gL, d0gb, 256, 1, zr, nullptr);
        xcat_kern<5><<<cdiv(NB * 128, 256), 256, 0, stream>>>(RMh, RMl, gob, y_cov, dh0, zr, t, 2, 128, 672);
        agcn_core(130, 2, 672, wD0uH, wD0uL, d0ub, 128, 3, zr, dh0);
        xcat_kern<6><<<cdiv(NB * 256, 256), 256, 0, stream>>>(RMh, RMl, dh0, nullptr, dh1, nullptr, t, 0, 256, 1280);
        agcn_core(256, 0, 1280, wD1gH, wD1gL, d1gb, 256, 1, zr, nullptr);
        xcat_kern<7><<<cdiv(NB * 128, 256), 256, 0, stream>>>(RMh, RMl, dh0, nullptr, dh1, zr, t, 128, 128, 1280);
        agcn_core(256, 128, 1280, wD1uH, wD1uL, d1ub, 128, 3, zr, dh1);
        proj_out<<<cdiv(NB, 256), 256, 0, stream>>>(dh1, proj_w, proj_b, gob, out, t);
    }
}

// Round 5
// 12638.812 us; speedup vs baseline: 3.8771x; 1.1300x over previous
//
#include <hip/hip_runtime.h>
#include <math.h>

#define NNODE 1024
#define BATCH 16
#define NB    16384
#define TT    12

typedef __bf16 bf16x8 __attribute__((ext_vector_type(8)));
typedef float  f32x4  __attribute__((ext_vector_type(4)));

static inline int cdiv(int a, int b) { return (a + b - 1) / b; }

// async global->LDS, 16B per lane, wave-uniform LDS base + lane*16
__device__ inline void gll16(const void* g, void* l) {
    __builtin_amdgcn_global_load_lds(
        (const __attribute__((address_space(1))) void*)g,
        (__attribute__((address_space(3))) void*)l, 16, 0, 0);
}

// ---------------------------------------------------------------------------
// Split-bf16 GEMM, counted-vmcnt double-buffered pipeline (T4), coalesced
// staging, XCD-chunked + 2-col band block swizzle for L2 residency of B.
// D[i][j] = sum_k A[i][k]*B[j][k]  (both k-contig), 3-pass hi/lo split.
// LDS per plane: row-major [R][32elem]; 16B k-slot XOR-swizzled via the
// GLOBAL source address so gll16 dest stays linear and ds_read_b128 is
// 2-way-conflict-free.
// EPI 0: split-store bf16 hi/lo (Ch/Cl) with nsplit/splitAdd col relocation
// EPI 1: +bias, sigmoid -> Cf
// EPI 3: +bias, tanh, fused GRU: hout = r*hout + (1-r)*hc  (r from zrp)
// ---------------------------------------------------------------------------
template<int BM, int BN, int EPI>
__global__ __launch_bounds__(256) void mm_kern(
    const __bf16* __restrict__ Ah, const __bf16* __restrict__ Al, long lda, long zA,
    const __bf16* __restrict__ Bh, const __bf16* __restrict__ Bl, long zB, long ldb,
    int M, int Ksteps,
    __bf16* __restrict__ Ch, __bf16* __restrict__ Cl, float* __restrict__ Cf,
    long ldc, long zC, int nsplit, long splitAdd,
    const float* __restrict__ bias, const float* __restrict__ zrp,
    float* __restrict__ hout)
{
    constexpr int WM = BM / 2, WN = BN / 2;
    constexpr int MF = WM / 16, NF = WN / 16;
    constexpr int nA = BM / 16, nB = BN / 16;       // 1KB chunks per plane
    constexpr int NP = (2 * nA + 2 * nB) / 4;       // chunks per wave
    constexpr int BUFE = (BM + BN) * 64;            // elems per LDS buffer
    // plane bases (elems): AH=0 | AL=BM*32 | BH=BM*64 | BL=BM*64+BN*32
    __shared__ __bf16 smem[2 * BUFE];

    // ---- block swizzle: bijective XCD chunking (m204) + 2-col band ----
    const int nwgx = gridDim.x, nwgy = gridDim.y;
    const int nwg = nwgx * nwgy;
    const int lin = blockIdx.y * nwgx + blockIdx.x;
    const int q8 = nwg >> 3, r8 = nwg & 7;
    const int xcd = lin & 7, cidx = lin >> 3;
    const int lin2 = (xcd < r8) ? (xcd * (q8 + 1) + cidx)
                                : (r8 * (q8 + 1) + (xcd - r8) * q8 + cidx);
    const int G = ((nwgx & 1) == 0) ? 2 : 1;        // band width in x
    const int band = G * nwgy;
    const int gb = lin2 / band, rm = lin2 - gb * band;
    const int bxs = gb * G + (rm & (G - 1));
    const int bys = rm / G;

    const int bm = bys * BM, bn = bxs * BN;
    const int tid = threadIdx.x, w = tid >> 6, lane = tid & 63;
    const int wr = w >> 1, wc = w & 1;
    const int lgrp = lane >> 4, lrow = lane & 15;

    Ah += (size_t)blockIdx.z * zA;  Al += (size_t)blockIdx.z * zA;
    Bh += (size_t)blockIdx.z * zB;  Bl += (size_t)blockIdx.z * zB;

    // staging: chunk q covers 16 rows; lane l -> row qq*16+(l>>2),
    // global k-slot = (l&3) ^ ((l>>3)&3)  (the source-side swizzle)
    const int srow = lane >> 2;
    const int kgel = ((lane & 3) ^ ((lane >> 3) & 3)) * 8;
    const __bf16* sp[NP];
    int dpo[NP];
#pragma unroll
    for (int p = 0; p < NP; ++p) {
        int q = p * 4 + w;
        int tile = (q < nA) ? 0 : (q < 2 * nA) ? 1 : (q < 2 * nA + nB) ? 2 : 3;
        int qq = q - ((tile == 0) ? 0 : (tile == 1) ? nA : (tile == 2) ? 2 * nA : 2 * nA + nB);
        const __bf16* base = (tile == 0) ? Ah : (tile == 1) ? Al : (tile == 2) ? Bh : Bl;
        long ld = (tile < 2) ? lda : ldb;
        int  rb = (tile < 2) ? bm : bn;
        sp[p] = base + (size_t)(rb + qq * 16 + srow) * ld + kgel;
        int tbase = (tile == 0) ? 0 : (tile == 1) ? BM * 32 : (tile == 2) ? BM * 64 : (BM * 64 + BN * 32);
        dpo[p] = tbase * 2 + qq * 1024;   // bytes; lane*16 appended by HW
    }

    f32x4 acc[MF][NF];
#pragma unroll
    for (int i = 0; i < MF; ++i)
#pragma unroll
        for (int j = 0; j < NF; ++j)
#pragma unroll
            for (int e = 0; e < 4; ++e) acc[i][j][e] = 0.f;

    auto stage = [&](int kt, int bsel) {
        char* lb = (char*)smem + bsel * (BUFE * 2);
#pragma unroll
        for (int p = 0; p < NP; ++p) gll16(sp[p] + (size_t)kt * 32, lb + dpo[p]);
    };

    stage(0, 0);

    // read-side swizzled slot offset (elems), lane-constant
    const int slotOff = (lgrp ^ ((lrow >> 1) & 3)) * 8;

    for (int kt = 0; kt < Ksteps; ++kt) {
        const int cur = kt & 1;
        // barrier 1: all waves finished READING buf cur^1 (their ds_reads were
        // lgkm-consumed by MFMAs before reaching here) -> safe to overwrite it
        __builtin_amdgcn_s_barrier();
        __builtin_amdgcn_sched_barrier(0);
        if (kt + 1 < Ksteps) {
            stage(kt + 1, cur ^ 1);
            // wait own tile-kt loads: exactly NP newer (tile kt+1) stay in flight
            __builtin_amdgcn_s_waitcnt(0xF70 | NP);
        } else {
            __builtin_amdgcn_s_waitcnt(0xF70);
        }
        // barrier 2: every wave's tile-kt chunks are resident in LDS
        __builtin_amdgcn_s_barrier();
        __builtin_amdgcn_sched_barrier(0);

        const __bf16* sb = smem + cur * BUFE;
        bf16x8 aH[MF], aL[MF], bHf[NF], bLf[NF];
#pragma unroll
        for (int mf = 0; mf < MF; ++mf) {
            int row = wr * WM + mf * 16 + lrow;
            aH[mf] = *(const bf16x8*)(sb + (size_t)row * 32 + slotOff);
            aL[mf] = *(const bf16x8*)(sb + BM * 32 + (size_t)row * 32 + slotOff);
        }
#pragma unroll
        for (int nf = 0; nf < NF; ++nf) {
            int col = wc * WN + nf * 16 + lrow;
            bHf[nf] = *(const bf16x8*)(sb + BM * 64 + (size_t)col * 32 + slotOff);
            bLf[nf] = *(const bf16x8*)(sb + BM * 64 + BN * 32 + (size_t)col * 32 + slotOff);
        }
#pragma unroll
        for (int mf = 0; mf < MF; ++mf)
#pragma unroll
            for (int nf = 0; nf < NF; ++nf) {
                acc[mf][nf] = __builtin_amdgcn_mfma_f32_16x16x32_bf16(aH[mf], bHf[nf], acc[mf][nf], 0, 0, 0);
                acc[mf][nf] = __builtin_amdgcn_mfma_f32_16x16x32_bf16(aH[mf], bLf[nf], acc[mf][nf], 0, 0, 0);
                acc[mf][nf] = __builtin_amdgcn_mfma_f32_16x16x32_bf16(aL[mf], bHf[nf], acc[mf][nf], 0, 0, 0);
            }
    }

    const size_t cz = (size_t)blockIdx.z * zC;
    const long cadj = (bn >= nsplit) ? splitAdd : 0;
#pragma unroll
    for (int mf = 0; mf < MF; ++mf) {
        int gi0 = bm + wr * WM + mf * 16 + lgrp * 4;
#pragma unroll
        for (int nf = 0; nf < NF; ++nf) {
            int gj = bn + wc * WN + nf * 16 + lrow;
#pragma unroll
            for (int r = 0; r < 4; ++r) {
                int gi = gi0 + r;
                if (gi < M) {
                    float v = acc[mf][nf][r];
                    if (EPI == 0) {
                        size_t cix = cz + (size_t)gi * ldc + gj + cadj;
                        __bf16 h = (__bf16)v;
                        Ch[cix] = h;
                        Cl[cix] = (__bf16)(v - (float)h);
                    } else if (EPI == 1) {
                        v += bias[gj];
                        v = 1.f / (1.f + expf(-v));
                        Cf[cz + (size_t)gi * ldc + gj] = v;
                    } else {
                        v += bias[gj];
                        v = tanhf(v);
                        float rg = zrp[(size_t)gi * 2 * ldc + ldc + gj];
                        size_t hix = (size_t)gi * ldc + gj;
                        hout[hix] = rg * hout[hix] + (1.f - rg) * v;
                    }
                }
            }
        }
    }
}

// ---------------------------------------------------------------------------
// LDS-tiled transpose between RM slots [(n*16+b)][KP] and T slots
// [s][i*16+b][node]. dir 0: RM->T, dir 1: T->RM. Skip i<iMin.
// ---------------------------------------------------------------------------
__global__ __launch_bounds__(256) void trans_kern(
    __bf16* __restrict__ TH, __bf16* __restrict__ TL,
    __bf16* __restrict__ RH, __bf16* __restrict__ RL,
    int c, int KP, int kk0, int kkEnd, int iMin, int dir)
{
    __shared__ __bf16 tile[32][66];
    const int b = blockIdx.z, nt = blockIdx.y * 64;
    const int kkb = kk0 + blockIdx.x * 32;
    const int t = threadIdx.x;
    const int c16 = 16 * c;

    for (int cp = 0; cp < 2; ++cp) {
        __bf16* Tp = cp ? TL : TH;
        __bf16* Rp = cp ? RL : RH;
        if (dir == 0) {
#pragma unroll
            for (int rep = 0; rep < 8; ++rep) {
                int kk = kkb + (t & 31);
                int nl = rep * 8 + (t >> 5);
                __bf16 v = (__bf16)0.f;
                if (kk < kkEnd) v = Rp[(size_t)((nt + nl) * 16 + b) * KP + kk];
                tile[t & 31][nl] = v;
            }
            __syncthreads();
#pragma unroll
            for (int rep = 0; rep < 8; ++rep) {
                int kkl = rep * 4 + (t >> 6);
                int kk = kkb + kkl;
                int n = nt + (t & 63);
                if (kk < kkEnd) {
                    int s = (kk >= c) + (kk >= 2 * c) + (kk >= 3 * c) + (kk >= 4 * c);
                    int i = kk - s * c;
                    if (i >= iMin)
                        Tp[((size_t)s * c16 + i * 16 + b) * 1024 + n] = tile[kkl][t & 63];
                }
            }
        } else {
#pragma unroll
            for (int rep = 0; rep < 8; ++rep) {
                int kkl = rep * 4 + (t >> 6);
                int kk = kkb + kkl;
                int n = nt + (t & 63);
                __bf16 v = (__bf16)0.f;
                if (kk < kkEnd) {
                    int s = (kk >= c) + (kk >= 2 * c) + (kk >= 3 * c) + (kk >= 4 * c);
                    int i = kk - s * c;
                    if (i >= iMin)
                        v = Tp[((size_t)s * c16 + i * 16 + b) * 1024 + n];
                }
                tile[kkl][t & 63] = v;
            }
            __syncthreads();
#pragma unroll
            for (int rep = 0; rep < 8; ++rep) {
                int kk = kkb + (t & 31);
                int nl = rep * 8 + (t >> 5);
                if (kk < kkEnd) {
                    int s = (kk >= c) + (kk >= 2 * c) + (kk >= 3 * c) + (kk >= 4 * c);
                    int i = kk - s * c;
                    if (i >= iMin)
                        Rp[(size_t)((nt + nl) * 16 + b) * KP + kk] = tile[t & 31][nl];
                }
            }
        }
        __syncthreads();
    }
}

// ---------------------------------------------------------------------------
// Build concat input into RM slot 0, split to bf16 hi/lo.
// ---------------------------------------------------------------------------
template<int MODE>
__global__ __launch_bounds__(256) void xcat_kern(
    __bf16* __restrict__ dH, __bf16* __restrict__ dL,
    const float* __restrict__ s1, const float* __restrict__ s2,
    const float* __restrict__ h, const float* __restrict__ zr,
    int t, int ccStart, int width, int KP)
{
    constexpr int C = (MODE < 2) ? 65 : (MODE < 4) ? 128 : (MODE < 6) ? 130 : 256;
    int idx = blockIdx.x * 256 + threadIdx.x;
    if (idx >= NB * width) return;
    int r = idx / width, ww = idx - r * width;
    int hspan = C - ccStart;
    int cc = (ww < hspan) ? (ccStart + ww) : (5 * C + (ww - hspan));
    int n = r >> 4, b = r & 15;
    float v = 0.f;
    if (cc < C) {
        if (MODE == 0 || MODE == 1) {
            if (cc == 0) v = s1[((size_t)b * TT + t) * NNODE + n];
            else { float hv = h[(size_t)r * 64 + cc - 1];
                   v = (MODE == 1) ? zr[(size_t)r * 128 + cc - 1] * hv : hv; }
        } else if (MODE == 2 || MODE == 3) {
            if (cc < 64) v = s1[(size_t)r * 64 + cc];
            else { float hv = h[(size_t)r * 64 + cc - 64];
                   v = (MODE == 3) ? zr[(size_t)r * 128 + cc - 64] * hv : hv; }
        } else if (MODE == 4 || MODE == 5) {
            if (cc == 0) v = s1[r];
            else if (cc == 1) v = s2[((size_t)b * TT + t) * NNODE + n];
            else { float hv = h[(size_t)r * 128 + cc - 2];
                   v = (MODE == 5) ? zr[(size_t)r * 256 + cc - 2] * hv : hv; }
        } else {
            if (cc < 128) v = s1[(size_t)r * 128 + cc];
            else { float hv = h[(size_t)r * 128 + cc - 128];
                   v = (MODE == 7) ? zr[(size_t)r * 256 + cc - 128] * hv : hv; }
        }
    }
    __bf16 hi = (__bf16)v;
    size_t o = (size_t)r * KP + cc;
    dH[o] = hi;
    dL[o] = (__bf16)(v - (float)hi);
}

// ---------------------------------------------------------------------------
// small kernels
// ---------------------------------------------------------------------------
__global__ __launch_bounds__(256) void compute_ne(
    const float* __restrict__ We1, const float* __restrict__ We2,
    const float* __restrict__ Mem, float* __restrict__ ne1, float* __restrict__ ne2)
{
    int idx = blockIdx.x * 256 + threadIdx.x;
    if (idx >= 2 * 65536) return;
    int which = idx >> 16;
    int i = idx & 65535;
    int n = i >> 6, d = i & 63;
    const float* We = which ? We2 : We1;
    float acc = 0.f;
#pragma unroll
    for (int k = 0; k < 20; ++k) acc += We[n * 20 + k] * Mem[k * 64 + d];
    (which ? ne2 : ne1)[i] = acc;
}

__global__ __launch_bounds__(256) void build_g(
    const float* __restrict__ ne1, const float* __restrict__ ne2, float* __restrict__ g)
{
    int row = blockIdx.x;
    int n = row & 1023;
    const float* qa = (row < 1024) ? ne1 : ne2;
    const float* kb = (row < 1024) ? ne2 : ne1;
    __shared__ float q[64];
    __shared__ float sc[1024];
    __shared__ float red[256];
    int tid = threadIdx.x;
    if (tid < 64) q[tid] = qa[n * 64 + tid];
    __syncthreads();
    for (int m = tid; m < 1024; m += 256) {
        float acc = 0.f;
        const float* kr = kb + m * 64;
#pragma unroll 8
        for (int d = 0; d < 64; ++d) acc += q[d] * kr[d];
        sc[m] = fmaxf(acc, 0.f);
    }
    __syncthreads();
    float mx = -1e30f;
    for (int m = tid; m < 1024; m += 256) mx = fmaxf(mx, sc[m]);
    red[tid] = mx;
    __syncthreads();
    for (int s2 = 128; s2 > 0; s2 >>= 1) {
        if (tid < s2) red[tid] = fmaxf(red[tid], red[tid + s2]);
        __syncthreads();
    }
    mx = red[0];
    __syncthreads();
    float sum = 0.f;
    for (int m = tid; m < 1024; m += 256) {
        float e = expf(sc[m] - mx);
        sc[m] = e;
        sum += e;
    }
    red[tid] = sum;
    __syncthreads();
    for (int s2 = 128; s2 > 0; s2 >>= 1) {
        if (tid < s2) red[tid] += red[tid + s2];
        __syncthreads();
    }
    float inv = 1.f / red[0];
    for (int m = tid; m < 1024; m += 256) g[(size_t)row * 1024 + m] = sc[m] * inv;
}

__global__ __launch_bounds__(256) void g_split(
    const float* __restrict__ g, __bf16* __restrict__ gh, __bf16* __restrict__ gl)
{
    int i = blockIdx.x * 256 + threadIdx.x;
    if (i >= 2048 * 1024) return;
    float v = g[i];
    __bf16 h = (__bf16)v;
    gh[i] = h;
    gl[i] = (__bf16)(v - (float)h);
}

__global__ __launch_bounds__(256) void build_weffT(
    const float* __restrict__ W, __bf16* __restrict__ dh, __bf16* __restrict__ dl,
    int c, int cout, int KP)
{
    int idx = blockIdx.x * 256 + threadIdx.x;
    if (idx >= cout * KP) return;
    int o = idx / KP, kk = idx - o * KP;
    float v = 0.f;
    if (kk < 5 * c) {
        int s = (kk >= c) + (kk >= 2 * c) + (kk >= 3 * c) + (kk >= 4 * c);
        int i = kk - s * c;
        if      (s == 0) v = W[(size_t)(0 * c + i) * cout + o] + W[(size_t)(3 * c + i) * cout + o]
                           - W[(size_t)(2 * c + i) * cout + o] - W[(size_t)(5 * c + i) * cout + o];
        else if (s == 1) v = W[(size_t)(1 * c + i) * cout + o];
        else if (s == 2) v = W[(size_t)(4 * c + i) * cout + o];
        else if (s == 3) v = 2.f * W[(size_t)(2 * c + i) * cout + o];
        else             v = 2.f * W[(size_t)(5 * c + i) * cout + o];
    }
    __bf16 h = (__bf16)v;
    dh[idx] = h;
    dl[idx] = (__bf16)(v - (float)h);
}

__global__ __launch_bounds__(64) void attention(
    const float* __restrict__ h, const float* __restrict__ Wq,
    const float* __restrict__ Mem, float* __restrict__ htc)
{
    int r = blockIdx.x;
    int j = threadIdx.x;
    __shared__ float hr[64], q[64], sc[20];
    hr[j] = h[(size_t)r * 64 + j];
    __syncthreads();
    float acc = 0.f;
#pragma unroll 8
    for (int i = 0; i < 64; ++i) acc += hr[i] * Wq[i * 64 + j];
    q[j] = acc;
    __syncthreads();
    if (j < 20) {
        float a = 0.f;
#pragma unroll 8
        for (int d = 0; d < 64; ++d) a += q[d] * Mem[j * 64 + d];
        sc[j] = a;
    }
    __syncthreads();
    if (j == 0) {
        float mx = sc[0];
        for (int m = 1; m < 20; ++m) mx = fmaxf(mx, sc[m]);
        float s = 0.f;
        for (int m = 0; m < 20; ++m) { sc[m] = expf(sc[m] - mx); s += sc[m]; }
        float inv = 1.f / s;
        for (int m = 0; m < 20; ++m) sc[m] *= inv;
    }
    __syncthreads();
    float v = 0.f;
#pragma unroll
    for (int m = 0; m < 20; ++m) v += sc[m] * Mem[m * 64 + j];
    htc[(size_t)r * 128 + j] = hr[j];
    htc[(size_t)r * 128 + 64 + j] = v;
}

__global__ __launch_bounds__(256) void proj_out(
    const float* __restrict__ h1, const float* __restrict__ pw, const float* __restrict__ pb,
    float* __restrict__ go, float* __restrict__ out, int t)
{
    int r = blockIdx.x * 256 + threadIdx.x;
    if (r >= NB) return;
    float acc = pb[0];
    const float* hr = h1 + (size_t)r * 128;
#pragma unroll 8
    for (int i = 0; i < 128; ++i) acc += hr[i] * pw[i];
    go[r] = acc;
    int n = r >> 4, b = r & 15;
    out[((size_t)b * TT + t) * NNODE + n] = acc;
}

// ---------------------------------------------------------------------------
// host
// ---------------------------------------------------------------------------
extern "C" void kernel_launch(void* const* d_in, const int* in_sizes, int n_in,
                              void* d_out, int out_size, void* d_ws, size_t ws_size,
                              hipStream_t stream)
{
    const float* x      = (const float*)d_in[0];
    const float* y_cov  = (const float*)d_in[1];
    const float* Memory = (const float*)d_in[2];
    const float* Wq     = (const float*)d_in[3];
    const float* We1    = (const float*)d_in[4];
    const float* We2    = (const float*)d_in[5];
    const float* e0gw = (const float*)d_in[6];  const float* e0gb = (const float*)d_in[7];
    const float* e0uw = (const float*)d_in[8];  const float* e0ub = (const float*)d_in[9];
    const float* e1gw = (const float*)d_in[10]; const float* e1gb = (const float*)d_in[11];
    const float* e1uw = (const float*)d_in[12]; const float* e1ub = (const float*)d_in[13];
    const float* d0gw = (const float*)d_in[14]; const float* d0gb = (const float*)d_in[15];
    const float* d0uw = (const float*)d_in[16]; const float* d0ub = (const float*)d_in[17];
    const float* d1gw = (const float*)d_in[18]; const float* d1gb = (const float*)d_in[19];
    const float* d1uw = (const float*)d_in[20]; const float* d1ub = (const float*)d_in[21];
    const float* proj_w = (const float*)d_in[22];
    const float* proj_b = (const float*)d_in[23];
    float* out = (float*)d_out;
    (void)in_sizes; (void)n_in; (void)out_size; (void)ws_size;

    char* wsb = (char*)d_ws;
    size_t off = 0;
    auto alloc = [&](size_t bytes) -> void* {
        void* p = wsb + off;
        off += (bytes + 255) & ~(size_t)255;
        return p;
    };

    float*  gf  = (float*) alloc(2048L * 1024 * 4);
    __bf16* gsH = (__bf16*)alloc(2048L * 1024 * 2);
    __bf16* gsL = (__bf16*)alloc(2048L * 1024 * 2);
    float*  ne1 = (float*) alloc(65536L * 4);
    float*  ne2 = (float*) alloc(65536L * 4);
    auto allocWT = [&](int cout, int KP, __bf16** h, __bf16** l) {
        *h = (__bf16*)alloc((size_t)cout * KP * 2);
        *l = (__bf16*)alloc((size_t)cout * KP * 2);
    };
    __bf16 *wE0gH, *wE0gL, *wE0uH, *wE0uL, *wE1gH, *wE1gL, *wE1uH, *wE1uL;
    __bf16 *wD0gH, *wD0gL, *wD0uH, *wD0uL, *wD1gH, *wD1gL, *wD1uH, *wD1uL;
    allocWT(128, 352,  &wE0gH, &wE0gL);  allocWT(64, 352,  &wE0uH, &wE0uL);
    allocWT(128, 640,  &wE1gH, &wE1gL);  allocWT(64, 640,  &wE1uH, &wE1uL);
    allocWT(256, 672,  &wD0gH, &wD0gL);  allocWT(128, 672, &wD0uH, &wD0uL);
    allocWT(256, 1280, &wD1gH, &wD1gL);  allocWT(128, 1280, &wD1uH, &wD1uL);
    __bf16* RMh = (__bf16*)alloc((size_t)NB * 1280 * 2);
    __bf16* RMl = (__bf16*)alloc((size_t)NB * 1280 * 2);
    __bf16* Th  = (__bf16*)alloc((size_t)(5 * 4096 + 128) * 1024 * 2);
    __bf16* Tl  = (__bf16*)alloc((size_t)(5 * 4096 + 128) * 1024 * 2);
    float* zr  = (float*)alloc((size_t)NB * 256 * 4);
    float* h0e = (float*)alloc((size_t)NB * 64 * 4);
    float* h1e = (float*)alloc((size_t)NB * 64 * 4);
    float* dh0 = (float*)alloc((size_t)NB * 128 * 4);
    float* dh1 = (float*)alloc((size_t)NB * 128 * 4);
    float* gob = (float*)alloc((size_t)NB * 4);

    // ---- setup ----
    compute_ne<<<cdiv(2 * 65536, 256), 256, 0, stream>>>(We1, We2, Memory, ne1, ne2);
    build_g<<<2048, 256, 0, stream>>>(ne1, ne2, gf);
    g_split<<<cdiv(2048 * 1024, 256), 256, 0, stream>>>(gf, gsH, gsL);
    build_weffT<<<cdiv(128 * 352, 256), 256, 0, stream>>>(e0gw, wE0gH, wE0gL, 65, 128, 352);
    build_weffT<<<cdiv(64 * 352, 256), 256, 0, stream>>>(e0uw, wE0uH, wE0uL, 65, 64, 352);
    build_weffT<<<cdiv(128 * 640, 256), 256, 0, stream>>>(e1gw, wE1gH, wE1gL, 128, 128, 640);
    build_weffT<<<cdiv(64 * 640, 256), 256, 0, stream>>>(e1uw, wE1uH, wE1uL, 128, 64, 640);
    build_weffT<<<cdiv(256 * 672, 256), 256, 0, stream>>>(d0gw, wD0gH, wD0gL, 130, 256, 672);
    build_weffT<<<cdiv(128 * 672, 256), 256, 0, stream>>>(d0uw, wD0uH, wD0uL, 130, 128, 672);
    build_weffT<<<cdiv(256 * 1280, 256), 256, 0, stream>>>(d1gw, wD1gH, wD1gL, 256, 256, 1280);
    build_weffT<<<cdiv(128 * 1280, 256), 256, 0, stream>>>(d1uw, wD1uH, wD1uL, 256, 128, 1280);
    hipMemsetAsync(h0e, 0, (size_t)NB * 64 * 4, stream);
    hipMemsetAsync(h1e, 0, (size_t)NB * 64 * 4, stream);

    // hops (trans0 -> hop1 -> hop2) then trans-back, weight GEMM w/ fused epi
    auto agcn_core = [&](int c, int cin2, int KP, const __bf16* wth, const __bf16* wtl,
                         const float* bias, int cout, int epi, float* zrOrOut, float* hptr) {
        int Mfull = 16 * c, Moff = 16 * cin2, Mv = Mfull - Moff;
        dim3 t0(cdiv(c - cin2, 32), 16, 16);
        trans_kern<<<t0, 256, 0, stream>>>(Th, Tl, RMh, RMl, c, KP, cin2, c, 0, 0);
        const __bf16* A1h = Th + (size_t)Moff * 1024;
        const __bf16* A1l = Tl + (size_t)Moff * 1024;
        __bf16* C1h = Th + (size_t)(Mfull + Moff) * 1024;
        __bf16* C1l = Tl + (size_t)(Mfull + Moff) * 1024;
        __bf16* C2h = Th + (size_t)(3 * Mfull + Moff) * 1024;
        __bf16* C2l = Tl + (size_t)(3 * Mfull + Moff) * 1024;
        if (Mv < 2048) {
            dim3 g1(16, cdiv(Mv, 64), 1);
            mm_kern<64, 128, 0><<<g1, 256, 0, stream>>>(
                A1h, A1l, 1024, 0, gsH, gsL, 0, 1024, Mv, 32,
                C1h, C1l, nullptr, 1024, 0, 1024, (long)Mfull * 1024 - 1024,
                nullptr, nullptr, nullptr);
            dim3 g2(8, cdiv(Mv, 64), 2);
            mm_kern<64, 128, 0><<<g2, 256, 0, stream>>>(
                C1h, C1l, 1024, (long)Mfull * 1024, gsH, gsL, (long)1024 * 1024, 1024, Mv, 32,
                C2h, C2l, nullptr, 1024, (long)Mfull * 1024, 1 << 30, 0,
                nullptr, nullptr, nullptr);
        } else {
            dim3 g1(16, cdiv(Mv, 128), 1);
            mm_kern<128, 128, 0><<<g1, 256, 0, stream>>>(
                A1h, A1l, 1024, 0, gsH, gsL, 0, 1024, Mv, 32,
                C1h, C1l, nullptr, 1024, 0, 1024, (long)Mfull * 1024 - 1024,
                nullptr, nullptr, nullptr);
            dim3 g2(8, cdiv(Mv, 128), 2);
            mm_kern<128, 128, 0><<<g2, 256, 0, stream>>>(
                C1h, C1l, 1024, (long)Mfull * 1024, gsH, gsL, (long)1024 * 1024, 1024, Mv, 32,
                C2h, C2l, nullptr, 1024, (long)Mfull * 1024, 1 << 30, 0,
                nullptr, nullptr, nullptr);
        }
        dim3 t1(cdiv(4 * c, 32), 16, 16);
        trans_kern<<<t1, 256, 0, stream>>>(Th, Tl, RMh, RMl, c, KP, c, 5 * c, cin2, 1);
        if (epi == 1) {
            if (cout == 256) {
                dim3 gw(2, 128, 1);
                mm_kern<128, 128, 1><<<gw, 256, 0, stream>>>(
                    RMh, RMl, KP, 0, wth, wtl, 0, KP, NB, KP / 32,
                    nullptr, nullptr, zrOrOut, cout, 0, 1 << 30, 0, bias, nullptr, nullptr);
            } else {
                dim3 gw(2, 128, 1);
                mm_kern<128, 64, 1><<<gw, 256, 0, stream>>>(
                    RMh, RMl, KP, 0, wth, wtl, 0, KP, NB, KP / 32,
                    nullptr, nullptr, zrOrOut, cout, 0, 1 << 30, 0, bias, nullptr, nullptr);
            }
        } else {   // epi 3: tanh + fused GRU update into hptr
            if (cout == 64) {
                dim3 gw(1, 256, 1);
                mm_kern<64, 64, 3><<<gw, 256, 0, stream>>>(
                    RMh, RMl, KP, 0, wth, wtl, 0, KP, NB, KP / 32,
                    nullptr, nullptr, nullptr, cout, 0, 1 << 30, 0, bias, zrOrOut, hptr);
            } else {
                dim3 gw(2, 128, 1);
                mm_kern<128, 64, 3><<<gw, 256, 0, stream>>>(
                    RMh, RMl, KP, 0, wth, wtl, 0, KP, NB, KP / 32,
                    nullptr, nullptr, nullptr, cout, 0, 1 << 30, 0, bias, zrOrOut, hptr);
            }
        }
    };

    // ---- encoder ----
    for (int t = 0; t < TT; ++t) {
        xcat_kern<0><<<cdiv(NB * 92, 256), 256, 0, stream>>>(RMh, RMl, x, nullptr, h0e, nullptr, t, 0, 92, 352);
        agcn_core(65, 0, 352, wE0gH, wE0gL, e0gb, 128, 1, zr, nullptr);
        xcat_kern<1><<<cdiv(NB * 64, 256), 256, 0, stream>>>(RMh, RMl, x, nullptr, h0e, zr, t, 1, 64, 352);
        agcn_core(65, 1, 352, wE0uH, wE0uL, e0ub, 64, 3, zr, h0e);
        xcat_kern<2><<<cdiv(NB * 128, 256), 256, 0, stream>>>(RMh, RMl, h0e, nullptr, h1e, nullptr, t, 0, 128, 640);
        agcn_core(128, 0, 640, wE1gH, wE1gL, e1gb, 128, 1, zr, nullptr);
        xcat_kern<3><<<cdiv(NB * 64, 256), 256, 0, stream>>>(RMh, RMl, h0e, nullptr, h1e, zr, t, 64, 64, 640);
        agcn_core(128, 64, 640, wE1uH, wE1uL, e1ub, 64, 3, zr, h1e);
    }

    // ---- memory attention ----
    attention<<<NB, 64, 0, stream>>>(h1e, Wq, Memory, dh0);
    hipMemcpyAsync(dh1, dh0, (size_t)NB * 128 * 4, hipMemcpyDeviceToDevice, stream);
    hipMemsetAsync(gob, 0, (size_t)NB * 4, stream);

    // ---- decoder ----
    for (int t = 0; t < TT; ++t) {
        xcat_kern<4><<<cdiv(NB * 152, 256), 256, 0, stream>>>(RMh, RMl, gob, y_cov, dh0, nullptr, t, 0, 152, 672);
        agcn_core(130, 0, 672, wD0gH, wD0gL, d0gb, 256, 1, zr, nullptr);
        xcat_kern<5><<<cdiv(NB * 128, 256), 256, 0, stream>>>(RMh, RMl, gob, y_cov, dh0, zr, t, 2, 128, 672);
        agcn_core(130, 2, 672, wD0uH, wD0uL, d0ub, 128, 3, zr, dh0);
        xcat_kern<6><<<cdiv(NB * 256, 256), 256, 0, stream>>>(RMh, RMl, dh0, nullptr, dh1, nullptr, t, 0, 256, 1280);
        agcn_core(256, 0, 1280, wD1gH, wD1gL, d1gb, 256, 1, zr, nullptr);
        xcat_kern<7><<<cdiv(NB * 128, 256), 256, 0, stream>>>(RMh, RMl, dh0, nullptr, dh1, zr, t, 128, 128, 1280);
        agcn_core(256, 128, 1280, wD1uH, wD1uL, d1ub, 128, 3, zr, dh1);
        proj_out<<<cdiv(NB, 256), 256, 0, stream>>>(dh1, proj_w, proj_b, gob, out, t);
    }
}

// Round 6
// 10702.315 us; speedup vs baseline: 4.5787x; 1.1809x over previous
//
#include <hip/hip_runtime.h>
#include <math.h>

#define NNODE 1024
#define BATCH 16
#define NB    16384
#define TT    12

typedef __bf16 bf16x8 __attribute__((ext_vector_type(8)));
typedef float  f32x4  __attribute__((ext_vector_type(4)));

static inline int cdiv(int a, int b) { return (a + b - 1) / b; }

// async global->LDS, 16B per lane, wave-uniform LDS base + lane*16
__device__ inline void gll16(const void* g, void* l) {
    __builtin_amdgcn_global_load_lds(
        (const __attribute__((address_space(1))) void*)g,
        (__attribute__((address_space(3))) void*)l, 16, 0, 0);
}

// ---------------------------------------------------------------------------
// Split-bf16 GEMM, counted-vmcnt double-buffered pipeline, coalesced staging,
// XCD-chunked + 2-col band block swizzle.
// D[i][j] = sum_k A[i][k]*B[j][k]  (both k-contig).
// PA: # A planes (1 = hi only, 2 = hi+lo). PB: # B planes.
// Passes: Ah*Bh always; Ah*Bl if PB==2; Al*Bh if PA==2 && kt < K3.
//   (K3 restricts the A-lo pass to the K-range where A-lo is nonzero.)
// EPI 0: store bf16 hi (Ch) with nsplit/splitAdd col relocation
// EPI 1: +bias, sigmoid -> Cf
// EPI 3: +bias, tanh, fused GRU: hout = r*hout + (1-r)*hc  (r from zrp)
// ---------------------------------------------------------------------------
template<int BM, int BN, int PA, int PB, int EPI>
__global__ __launch_bounds__(256) void mm_kern(
    const __bf16* __restrict__ Ah, const __bf16* __restrict__ Al, long lda, long zA,
    const __bf16* __restrict__ Bh, const __bf16* __restrict__ Bl, long zB, long ldb,
    int M, int Ksteps, int K3,
    __bf16* __restrict__ Ch, float* __restrict__ Cf,
    long ldc, long zC, int nsplit, long splitAdd,
    const float* __restrict__ bias, const float* __restrict__ zrp,
    float* __restrict__ hout)
{
    constexpr int WM = BM / 2, WN = BN / 2;
    constexpr int MF = WM / 16, NF = WN / 16;
    constexpr int nA = BM / 16, nB = BN / 16;       // 1KB chunks per plane
    constexpr int NPS = (2 * nA + 2 * nB) / 4;      // chunk slots per wave (max)
    constexpr int cAl = nA / 4, cBl = nB / 16 == 0 ? 0 : nB / 4;
    constexpr int NPfull = nA / 4 + nB / 4 + (PA == 2 ? cAl : 0) + (PB == 2 ? cBl : 0);
    constexpr int NPnoAl = NPfull - (PA == 2 ? cAl : 0);
    // plane bases (elems): Ah=0 | Al (if PA2) | Bh | Bl (if PB2)
    constexpr int bAl = BM * 32;
    constexpr int bBh = (PA == 2 ? 2 : 1) * BM * 32;
    constexpr int bBl = bBh + BN * 32;
    constexpr int BUFE = ((PA == 2 ? 2 : 1) * BM + (PB == 2 ? 2 : 1) * BN) * 32;
    __shared__ __bf16 smem[2 * BUFE];

    // ---- block swizzle: bijective XCD chunking + 2-col band ----
    const int nwgx = gridDim.x, nwgy = gridDim.y;
    const int nwg = nwgx * nwgy;
    const int lin = blockIdx.y * nwgx + blockIdx.x;
    const int q8 = nwg >> 3, r8 = nwg & 7;
    const int xcd = lin & 7, cidx = lin >> 3;
    const int lin2 = (xcd < r8) ? (xcd * (q8 + 1) + cidx)
                                : (r8 * (q8 + 1) + (xcd - r8) * q8 + cidx);
    const int G = ((nwgx & 1) == 0) ? 2 : 1;
    const int band = G * nwgy;
    const int gb = lin2 / band, rm = lin2 - gb * band;
    const int bxs = gb * G + (rm & (G - 1));
    const int bys = rm / G;

    const int bm = bys * BM, bn = bxs * BN;
    const int tid = threadIdx.x, w = tid >> 6, lane = tid & 63;
    const int wr = w >> 1, wc = w & 1;
    const int lgrp = lane >> 4, lrow = lane & 15;

    Ah += (size_t)blockIdx.z * zA;  Al += (size_t)blockIdx.z * zA;
    Bh += (size_t)blockIdx.z * zB;  Bl += (size_t)blockIdx.z * zB;

    const int srow = lane >> 2;
    const int kgel = ((lane & 3) ^ ((lane >> 3) & 3)) * 8;
    const __bf16* sp[NPS];
    int dpo[NPS];
    int ttyp[NPS];
#pragma unroll
    for (int p = 0; p < NPS; ++p) {
        int q = p * 4 + w;
        int tile = (q < nA) ? 0 : (q < 2 * nA) ? 1 : (q < 2 * nA + nB) ? 2 : 3;
        int qq = q - ((tile == 0) ? 0 : (tile == 1) ? nA : (tile == 2) ? 2 * nA : 2 * nA + nB);
        const __bf16* base = (tile == 0) ? Ah : (tile == 1) ? Al : (tile == 2) ? Bh : Bl;
        long ld = (tile < 2) ? lda : ldb;
        int  rb = (tile < 2) ? bm : bn;
        sp[p] = base + (size_t)(rb + qq * 16 + srow) * ld + kgel;
        int tbase = (tile == 0) ? 0 : (tile == 1) ? bAl : (tile == 2) ? bBh : bBl;
        dpo[p] = tbase * 2 + qq * 1024;
        ttyp[p] = tile;
    }

    f32x4 acc[MF][NF];
#pragma unroll
    for (int i = 0; i < MF; ++i)
#pragma unroll
        for (int j = 0; j < NF; ++j)
#pragma unroll
            for (int e = 0; e < 4; ++e) acc[i][j][e] = 0.f;

    auto stage = [&](int kt, int bsel) {
        char* lb = (char*)smem + bsel * (BUFE * 2);
#pragma unroll
        for (int p = 0; p < NPS; ++p) {
            int tile = ttyp[p];
            bool go = (tile == 0) || (tile == 2)
                   || (tile == 1 && PA == 2 && kt < K3)
                   || (tile == 3 && PB == 2);
            if (go) gll16(sp[p] + (size_t)kt * 32, lb + dpo[p]);
        }
    };

    stage(0, 0);

    const int slotOff = (lgrp ^ ((lrow >> 1) & 3)) * 8;

    for (int kt = 0; kt < Ksteps; ++kt) {
        const int cur = kt & 1;
        __builtin_amdgcn_s_barrier();
        __builtin_amdgcn_sched_barrier(0);
        if (kt + 1 < Ksteps) {
            stage(kt + 1, cur ^ 1);
            if (PA == 2 && (kt + 1) < K3)
                __builtin_amdgcn_s_waitcnt(0xF70 | NPfull);
            else
                __builtin_amdgcn_s_waitcnt(0xF70 | NPnoAl);
        } else {
            __builtin_amdgcn_s_waitcnt(0xF70);
        }
        __builtin_amdgcn_s_barrier();
        __builtin_amdgcn_sched_barrier(0);

        const __bf16* sb = smem + cur * BUFE;
        bf16x8 aH[MF], bHf[NF];
#pragma unroll
        for (int mf = 0; mf < MF; ++mf) {
            int row = wr * WM + mf * 16 + lrow;
            aH[mf] = *(const bf16x8*)(sb + (size_t)row * 32 + slotOff);
        }
#pragma unroll
        for (int nf = 0; nf < NF; ++nf) {
            int col = wc * WN + nf * 16 + lrow;
            bHf[nf] = *(const bf16x8*)(sb + bBh + (size_t)col * 32 + slotOff);
        }
#pragma unroll
        for (int mf = 0; mf < MF; ++mf)
#pragma unroll
            for (int nf = 0; nf < NF; ++nf)
                acc[mf][nf] = __builtin_amdgcn_mfma_f32_16x16x32_bf16(aH[mf], bHf[nf], acc[mf][nf], 0, 0, 0);

        if (PB == 2) {
            bf16x8 bLf[NF];
#pragma unroll
            for (int nf = 0; nf < NF; ++nf) {
                int col = wc * WN + nf * 16 + lrow;
                bLf[nf] = *(const bf16x8*)(sb + bBl + (size_t)col * 32 + slotOff);
            }
#pragma unroll
            for (int mf = 0; mf < MF; ++mf)
#pragma unroll
                for (int nf = 0; nf < NF; ++nf)
                    acc[mf][nf] = __builtin_amdgcn_mfma_f32_16x16x32_bf16(aH[mf], bLf[nf], acc[mf][nf], 0, 0, 0);
        }
        if (PA == 2 && kt < K3) {
            bf16x8 aL[MF];
#pragma unroll
            for (int mf = 0; mf < MF; ++mf) {
                int row = wr * WM + mf * 16 + lrow;
                aL[mf] = *(const bf16x8*)(sb + bAl + (size_t)row * 32 + slotOff);
            }
#pragma unroll
            for (int mf = 0; mf < MF; ++mf)
#pragma unroll
                for (int nf = 0; nf < NF; ++nf)
                    acc[mf][nf] = __builtin_amdgcn_mfma_f32_16x16x32_bf16(aL[mf], bHf[nf], acc[mf][nf], 0, 0, 0);
        }
    }

    const size_t cz = (size_t)blockIdx.z * zC;
    const long cadj = (bn >= nsplit) ? splitAdd : 0;
#pragma unroll
    for (int mf = 0; mf < MF; ++mf) {
        int gi0 = bm + wr * WM + mf * 16 + lgrp * 4;
#pragma unroll
        for (int nf = 0; nf < NF; ++nf) {
            int gj = bn + wc * WN + nf * 16 + lrow;
#pragma unroll
            for (int r = 0; r < 4; ++r) {
                int gi = gi0 + r;
                if (gi < M) {
                    float v = acc[mf][nf][r];
                    if (EPI == 0) {
                        Ch[cz + (size_t)gi * ldc + gj + cadj] = (__bf16)v;
                    } else if (EPI == 1) {
                        v += bias[gj];
                        v = 1.f / (1.f + expf(-v));
                        Cf[cz + (size_t)gi * ldc + gj] = v;
                    } else {
                        v += bias[gj];
                        v = tanhf(v);
                        float rg = zrp[(size_t)gi * 2 * ldc + ldc + gj];
                        size_t hix = (size_t)gi * ldc + gj;
                        hout[hix] = rg * hout[hix] + (1.f - rg) * v;
                    }
                }
            }
        }
    }
}

// ---------------------------------------------------------------------------
// LDS-tiled transpose between RM slots [(n*16+b)][KP] and T slots
// [s][i*16+b][node]. dir 0: RM->T, dir 1: T->RM. Skip i<iMin.
// nplanes: 2 = hi+lo, 1 = hi only.
// ---------------------------------------------------------------------------
__global__ __launch_bounds__(256) void trans_kern(
    __bf16* __restrict__ TH, __bf16* __restrict__ TL,
    __bf16* __restrict__ RH, __bf16* __restrict__ RL,
    int c, int KP, int kk0, int kkEnd, int iMin, int dir, int nplanes)
{
    __shared__ __bf16 tile[32][66];
    const int b = blockIdx.z, nt = blockIdx.y * 64;
    const int kkb = kk0 + blockIdx.x * 32;
    const int t = threadIdx.x;
    const int c16 = 16 * c;

    for (int cp = 0; cp < nplanes; ++cp) {
        __bf16* Tp = cp ? TL : TH;
        __bf16* Rp = cp ? RL : RH;
        if (dir == 0) {
#pragma unroll
            for (int rep = 0; rep < 8; ++rep) {
                int kk = kkb + (t & 31);
                int nl = rep * 8 + (t >> 5);
                __bf16 v = (__bf16)0.f;
                if (kk < kkEnd) v = Rp[(size_t)((nt + nl) * 16 + b) * KP + kk];
                tile[t & 31][nl] = v;
            }
            __syncthreads();
#pragma unroll
            for (int rep = 0; rep < 8; ++rep) {
                int kkl = rep * 4 + (t >> 6);
                int kk = kkb + kkl;
                int n = nt + (t & 63);
                if (kk < kkEnd) {
                    int s = (kk >= c) + (kk >= 2 * c) + (kk >= 3 * c) + (kk >= 4 * c);
                    int i = kk - s * c;
                    if (i >= iMin)
                        Tp[((size_t)s * c16 + i * 16 + b) * 1024 + n] = tile[kkl][t & 63];
                }
            }
        } else {
#pragma unroll
            for (int rep = 0; rep < 8; ++rep) {
                int kkl = rep * 4 + (t >> 6);
                int kk = kkb + kkl;
                int n = nt + (t & 63);
                __bf16 v = (__bf16)0.f;
                if (kk < kkEnd) {
                    int s = (kk >= c) + (kk >= 2 * c) + (kk >= 3 * c) + (kk >= 4 * c);
                    int i = kk - s * c;
                    if (i >= iMin)
                        v = Tp[((size_t)s * c16 + i * 16 + b) * 1024 + n];
                }
                tile[kkl][t & 63] = v;
            }
            __syncthreads();
#pragma unroll
            for (int rep = 0; rep < 8; ++rep) {
                int kk = kkb + (t & 31);
                int nl = rep * 8 + (t >> 5);
                if (kk < kkEnd) {
                    int s = (kk >= c) + (kk >= 2 * c) + (kk >= 3 * c) + (kk >= 4 * c);
                    int i = kk - s * c;
                    if (i >= iMin)
                        Rp[(size_t)((nt + nl) * 16 + b) * KP + kk] = tile[t & 31][nl];
                }
            }
        }
        __syncthreads();
    }
}

// ---------------------------------------------------------------------------
// Build concat input into RM slot 0, split to bf16 hi/lo.
// Gate path (ccStart==0): cc = ww < ca ? ww : 5C + (ww-ca); zeros both planes
// in [C, ca) (straddle region for the K3-restricted A-lo pass) and pad.
// ---------------------------------------------------------------------------
template<int MODE>
__global__ __launch_bounds__(256) void xcat_kern(
    __bf16* __restrict__ dH, __bf16* __restrict__ dL,
    const float* __restrict__ s1, const float* __restrict__ s2,
    const float* __restrict__ h, const float* __restrict__ zr,
    int t, int ccStart, int width, int KP, int ca)
{
    constexpr int C = (MODE < 2) ? 65 : (MODE < 4) ? 128 : (MODE < 6) ? 130 : 256;
    int idx = blockIdx.x * 256 + threadIdx.x;
    if (idx >= NB * width) return;
    int r = idx / width, ww = idx - r * width;
    int cc = (ccStart == 0) ? ((ww < ca) ? ww : 5 * C + (ww - ca))
                            : (ccStart + ww);
    int n = r >> 4, b = r & 15;
    float v = 0.f;
    if (cc < C) {
        if (MODE == 0 || MODE == 1) {
            if (cc == 0) v = s1[((size_t)b * TT + t) * NNODE + n];
            else { float hv = h[(size_t)r * 64 + cc - 1];
                   v = (MODE == 1) ? zr[(size_t)r * 128 + cc - 1] * hv : hv; }
        } else if (MODE == 2 || MODE == 3) {
            if (cc < 64) v = s1[(size_t)r * 64 + cc];
            else { float hv = h[(size_t)r * 64 + cc - 64];
                   v = (MODE == 3) ? zr[(size_t)r * 128 + cc - 64] * hv : hv; }
        } else if (MODE == 4 || MODE == 5) {
            if (cc == 0) v = s1[r];
            else if (cc == 1) v = s2[((size_t)b * TT + t) * NNODE + n];
            else { float hv = h[(size_t)r * 128 + cc - 2];
                   v = (MODE == 5) ? zr[(size_t)r * 256 + cc - 2] * hv : hv; }
        } else {
            if (cc < 128) v = s1[(size_t)r * 128 + cc];
            else { float hv = h[(size_t)r * 128 + cc - 128];
                   v = (MODE == 7) ? zr[(size_t)r * 256 + cc - 128] * hv : hv; }
        }
    }
    __bf16 hi = (__bf16)v;
    size_t o = (size_t)r * KP + cc;
    dH[o] = hi;
    dL[o] = (__bf16)(v - (float)hi);
}

// ---------------------------------------------------------------------------
// small kernels
// ---------------------------------------------------------------------------
__global__ __launch_bounds__(256) void compute_ne(
    const float* __restrict__ We1, const float* __restrict__ We2,
    const float* __restrict__ Mem, float* __restrict__ ne1, float* __restrict__ ne2)
{
    int idx = blockIdx.x * 256 + threadIdx.x;
    if (idx >= 2 * 65536) return;
    int which = idx >> 16;
    int i = idx & 65535;
    int n = i >> 6, d = i & 63;
    const float* We = which ? We2 : We1;
    float acc = 0.f;
#pragma unroll
    for (int k = 0; k < 20; ++k) acc += We[n * 20 + k] * Mem[k * 64 + d];
    (which ? ne2 : ne1)[i] = acc;
}

__global__ __launch_bounds__(256) void build_g(
    const float* __restrict__ ne1, const float* __restrict__ ne2, float* __restrict__ g)
{
    int row = blockIdx.x;
    int n = row & 1023;
    const float* qa = (row < 1024) ? ne1 : ne2;
    const float* kb = (row < 1024) ? ne2 : ne1;
    __shared__ float q[64];
    __shared__ float sc[1024];
    __shared__ float red[256];
    int tid = threadIdx.x;
    if (tid < 64) q[tid] = qa[n * 64 + tid];
    __syncthreads();
    for (int m = tid; m < 1024; m += 256) {
        float acc = 0.f;
        const float* kr = kb + m * 64;
#pragma unroll 8
        for (int d = 0; d < 64; ++d) acc += q[d] * kr[d];
        sc[m] = fmaxf(acc, 0.f);
    }
    __syncthreads();
    float mx = -1e30f;
    for (int m = tid; m < 1024; m += 256) mx = fmaxf(mx, sc[m]);
    red[tid] = mx;
    __syncthreads();
    for (int s2 = 128; s2 > 0; s2 >>= 1) {
        if (tid < s2) red[tid] = fmaxf(red[tid], red[tid + s2]);
        __syncthreads();
    }
    mx = red[0];
    __syncthreads();
    float sum = 0.f;
    for (int m = tid; m < 1024; m += 256) {
        float e = expf(sc[m] - mx);
        sc[m] = e;
        sum += e;
    }
    red[tid] = sum;
    __syncthreads();
    for (int s2 = 128; s2 > 0; s2 >>= 1) {
        if (tid < s2) red[tid] += red[tid + s2];
        __syncthreads();
    }
    float inv = 1.f / red[0];
    for (int m = tid; m < 1024; m += 256) g[(size_t)row * 1024 + m] = sc[m] * inv;
}

__global__ __launch_bounds__(256) void g_hi(
    const float* __restrict__ g, __bf16* __restrict__ gh)
{
    int i = blockIdx.x * 256 + threadIdx.x;
    if (i >= 2048 * 1024) return;
    gh[i] = (__bf16)g[i];
}

__global__ __launch_bounds__(256) void build_weffT(
    const float* __restrict__ W, __bf16* __restrict__ dh, __bf16* __restrict__ dl,
    int c, int cout, int KP)
{
    int idx = blockIdx.x * 256 + threadIdx.x;
    if (idx >= cout * KP) return;
    int o = idx / KP, kk = idx - o * KP;
    float v = 0.f;
    if (kk < 5 * c) {
        int s = (kk >= c) + (kk >= 2 * c) + (kk >= 3 * c) + (kk >= 4 * c);
        int i = kk - s * c;
        if      (s == 0) v = W[(size_t)(0 * c + i) * cout + o] + W[(size_t)(3 * c + i) * cout + o]
                           - W[(size_t)(2 * c + i) * cout + o] - W[(size_t)(5 * c + i) * cout + o];
        else if (s == 1) v = W[(size_t)(1 * c + i) * cout + o];
        else if (s == 2) v = W[(size_t)(4 * c + i) * cout + o];
        else if (s == 3) v = 2.f * W[(size_t)(2 * c + i) * cout + o];
        else             v = 2.f * W[(size_t)(5 * c + i) * cout + o];
    }
    __bf16 h = (__bf16)v;
    dh[idx] = h;
    dl[idx] = (__bf16)(v - (float)h);
}

__global__ __launch_bounds__(64) void attention(
    const float* __restrict__ h, const float* __restrict__ Wq,
    const float* __restrict__ Mem, float* __restrict__ htc)
{
    int r = blockIdx.x;
    int j = threadIdx.x;
    __shared__ float hr[64], q[64], sc[20];
    hr[j] = h[(size_t)r * 64 + j];
    __syncthreads();
    float acc = 0.f;
#pragma unroll 8
    for (int i = 0; i < 64; ++i) acc += hr[i] * Wq[i * 64 + j];
    q[j] = acc;
    __syncthreads();
    if (j < 20) {
        float a = 0.f;
#pragma unroll 8
        for (int d = 0; d < 64; ++d) a += q[d] * Mem[j * 64 + d];
        sc[j] = a;
    }
    __syncthreads();
    if (j == 0) {
        float mx = sc[0];
        for (int m = 1; m < 20; ++m) mx = fmaxf(mx, sc[m]);
        float s = 0.f;
        for (int m = 0; m < 20; ++m) { sc[m] = expf(sc[m] - mx); s += sc[m]; }
        float inv = 1.f / s;
        for (int m = 0; m < 20; ++m) sc[m] *= inv;
    }
    __syncthreads();
    float v = 0.f;
#pragma unroll
    for (int m = 0; m < 20; ++m) v += sc[m] * Mem[m * 64 + j];
    htc[(size_t)r * 128 + j] = hr[j];
    htc[(size_t)r * 128 + 64 + j] = v;
}

__global__ __launch_bounds__(256) void proj_out(
    const float* __restrict__ h1, const float* __restrict__ pw, const float* __restrict__ pb,
    float* __restrict__ go, float* __restrict__ out, int t)
{
    int r = blockIdx.x * 256 + threadIdx.x;
    if (r >= NB) return;
    float acc = pb[0];
    const float* hr = h1 + (size_t)r * 128;
#pragma unroll 8
    for (int i = 0; i < 128; ++i) acc += hr[i] * pw[i];
    go[r] = acc;
    int n = r >> 4, b = r & 15;
    out[((size_t)b * TT + t) * NNODE + n] = acc;
}

// ---------------------------------------------------------------------------
// host
// ---------------------------------------------------------------------------
extern "C" void kernel_launch(void* const* d_in, const int* in_sizes, int n_in,
                              void* d_out, int out_size, void* d_ws, size_t ws_size,
                              hipStream_t stream)
{
    const float* x      = (const float*)d_in[0];
    const float* y_cov  = (const float*)d_in[1];
    const float* Memory = (const float*)d_in[2];
    const float* Wq     = (const float*)d_in[3];
    const float* We1    = (const float*)d_in[4];
    const float* We2    = (const float*)d_in[5];
    const float* e0gw = (const float*)d_in[6];  const float* e0gb = (const float*)d_in[7];
    const float* e0uw = (const float*)d_in[8];  const float* e0ub = (const float*)d_in[9];
    const float* e1gw = (const float*)d_in[10]; const float* e1gb = (const float*)d_in[11];
    const float* e1uw = (const float*)d_in[12]; const float* e1ub = (const float*)d_in[13];
    const float* d0gw = (const float*)d_in[14]; const float* d0gb = (const float*)d_in[15];
    const float* d0uw = (const float*)d_in[16]; const float* d0ub = (const float*)d_in[17];
    const float* d1gw = (const float*)d_in[18]; const float* d1gb = (const float*)d_in[19];
    const float* d1uw = (const float*)d_in[20]; const float* d1ub = (const float*)d_in[21];
    const float* proj_w = (const float*)d_in[22];
    const float* proj_b = (const float*)d_in[23];
    float* out = (float*)d_out;
    (void)in_sizes; (void)n_in; (void)out_size; (void)ws_size;

    char* wsb = (char*)d_ws;
    size_t off = 0;
    auto alloc = [&](size_t bytes) -> void* {
        void* p = wsb + off;
        off += (bytes + 255) & ~(size_t)255;
        return p;
    };

    float*  gf  = (float*) alloc(2048L * 1024 * 4);
    __bf16* gsH = (__bf16*)alloc(2048L * 1024 * 2);
    float*  ne1 = (float*) alloc(65536L * 4);
    float*  ne2 = (float*) alloc(65536L * 4);
    auto allocWT = [&](int cout, int KP, __bf16** h, __bf16** l) {
        *h = (__bf16*)alloc((size_t)cout * KP * 2);
        *l = (__bf16*)alloc((size_t)cout * KP * 2);
    };
    __bf16 *wE0gH, *wE0gL, *wE0uH, *wE0uL, *wE1gH, *wE1gL, *wE1uH, *wE1uL;
    __bf16 *wD0gH, *wD0gL, *wD0uH, *wD0uL, *wD1gH, *wD1gL, *wD1uH, *wD1uL;
    allocWT(128, 352,  &wE0gH, &wE0gL);  allocWT(64, 352,  &wE0uH, &wE0uL);
    allocWT(128, 640,  &wE1gH, &wE1gL);  allocWT(64, 640,  &wE1uH, &wE1uL);
    allocWT(256, 672,  &wD0gH, &wD0gL);  allocWT(128, 672, &wD0uH, &wD0uL);
    allocWT(256, 1280, &wD1gH, &wD1gL);  allocWT(128, 1280, &wD1uH, &wD1uL);
    __bf16* RMh = (__bf16*)alloc((size_t)NB * 1280 * 2);
    __bf16* RMl = (__bf16*)alloc((size_t)NB * 1280 * 2);
    __bf16* Th  = (__bf16*)alloc((size_t)(5 * 4096 + 128) * 1024 * 2);
    __bf16* Tl  = (__bf16*)alloc((size_t)(5 * 4096 + 128) * 1024 * 2);
    float* zr  = (float*)alloc((size_t)NB * 256 * 4);
    float* h0e = (float*)alloc((size_t)NB * 64 * 4);
    float* h1e = (float*)alloc((size_t)NB * 64 * 4);
    float* dh0 = (float*)alloc((size_t)NB * 128 * 4);
    float* dh1 = (float*)alloc((size_t)NB * 128 * 4);
    float* gob = (float*)alloc((size_t)NB * 4);

    // ---- setup ----
    compute_ne<<<cdiv(2 * 65536, 256), 256, 0, stream>>>(We1, We2, Memory, ne1, ne2);
    build_g<<<2048, 256, 0, stream>>>(ne1, ne2, gf);
    g_hi<<<cdiv(2048 * 1024, 256), 256, 0, stream>>>(gf, gsH);
    build_weffT<<<cdiv(128 * 352, 256), 256, 0, stream>>>(e0gw, wE0gH, wE0gL, 65, 128, 352);
    build_weffT<<<cdiv(64 * 352, 256), 256, 0, stream>>>(e0uw, wE0uH, wE0uL, 65, 64, 352);
    build_weffT<<<cdiv(128 * 640, 256), 256, 0, stream>>>(e1gw, wE1gH, wE1gL, 128, 128, 640);
    build_weffT<<<cdiv(64 * 640, 256), 256, 0, stream>>>(e1uw, wE1uH, wE1uL, 128, 64, 640);
    build_weffT<<<cdiv(256 * 672, 256), 256, 0, stream>>>(d0gw, wD0gH, wD0gL, 130, 256, 672);
    build_weffT<<<cdiv(128 * 672, 256), 256, 0, stream>>>(d0uw, wD0uH, wD0uL, 130, 128, 672);
    build_weffT<<<cdiv(256 * 1280, 256), 256, 0, stream>>>(d1gw, wD1gH, wD1gL, 256, 256, 1280);
    build_weffT<<<cdiv(128 * 1280, 256), 256, 0, stream>>>(d1uw, wD1uH, wD1uL, 256, 128, 1280);
    hipMemsetAsync(h0e, 0, (size_t)NB * 64 * 4, stream);
    hipMemsetAsync(h1e, 0, (size_t)NB * 64 * 4, stream);

    auto agcn_core = [&](int c, int cin2, int KP, const __bf16* wth, const __bf16* wtl,
                         const float* bias, int cout, int epi, float* zrOrOut, float* hptr,
                         int K3w) {
        int Mfull = 16 * c, Moff = 16 * cin2, Mv = Mfull - Moff;
        dim3 t0(cdiv(c - cin2, 32), 16, 16);
        trans_kern<<<t0, 256, 0, stream>>>(Th, Tl, RMh, RMl, c, KP, cin2, c, 0, 0, 2);
        const __bf16* A1h = Th + (size_t)Moff * 1024;
        const __bf16* A1l = Tl + (size_t)Moff * 1024;
        __bf16* C1h = Th + (size_t)(Mfull + Moff) * 1024;
        __bf16* C2h = Th + (size_t)(3 * Mfull + Moff) * 1024;
        if (Mv < 2048) {
            dim3 g1(16, cdiv(Mv, 64), 1);
            mm_kern<64, 128, 2, 1, 0><<<g1, 256, 0, stream>>>(
                A1h, A1l, 1024, 0, gsH, gsH, 0, 1024, Mv, 32, 32,
                C1h, nullptr, 1024, 0, 1024, (long)Mfull * 1024 - 1024,
                nullptr, nullptr, nullptr);
            dim3 g2(8, cdiv(Mv, 64), 2);
            mm_kern<64, 128, 1, 1, 0><<<g2, 256, 0, stream>>>(
                C1h, C1h, 1024, (long)Mfull * 1024, gsH, gsH, (long)1024 * 1024, 1024, Mv, 32, 0,
                C2h, nullptr, 1024, (long)Mfull * 1024, 1 << 30, 0,
                nullptr, nullptr, nullptr);
        } else {
            dim3 g1(16, cdiv(Mv, 128), 1);
            mm_kern<128, 128, 2, 1, 0><<<g1, 256, 0, stream>>>(
                A1h, A1l, 1024, 0, gsH, gsH, 0, 1024, Mv, 32, 32,
                C1h, nullptr, 1024, 0, 1024, (long)Mfull * 1024 - 1024,
                nullptr, nullptr, nullptr);
            dim3 g2(8, cdiv(Mv, 128), 2);
            mm_kern<128, 128, 1, 1, 0><<<g2, 256, 0, stream>>>(
                C1h, C1h, 1024, (long)Mfull * 1024, gsH, gsH, (long)1024 * 1024, 1024, Mv, 32, 0,
                C2h, nullptr, 1024, (long)Mfull * 1024, 1 << 30, 0,
                nullptr, nullptr, nullptr);
        }
        dim3 t1(cdiv(4 * c, 32), 16, 16);
        trans_kern<<<t1, 256, 0, stream>>>(Th, Tl, RMh, RMl, c, KP, c, 5 * c, cin2, 1, 1);
        if (epi == 1) {
            if (cout == 256) {
                dim3 gw(2, 128, 1);
                mm_kern<128, 128, 2, 2, 1><<<gw, 256, 0, stream>>>(
                    RMh, RMl, KP, 0, wth, wtl, 0, KP, NB, KP / 32, K3w,
                    nullptr, zrOrOut, cout, 0, 1 << 30, 0, bias, nullptr, nullptr);
            } else {
                dim3 gw(2, 128, 1);
                mm_kern<128, 64, 2, 2, 1><<<gw, 256, 0, stream>>>(
                    RMh, RMl, KP, 0, wth, wtl, 0, KP, NB, KP / 32, K3w,
                    nullptr, zrOrOut, cout, 0, 1 << 30, 0, bias, nullptr, nullptr);
            }
        } else {
            if (cout == 64) {
                dim3 gw(1, 256, 1);
                mm_kern<64, 64, 2, 2, 3><<<gw, 256, 0, stream>>>(
                    RMh, RMl, KP, 0, wth, wtl, 0, KP, NB, KP / 32, K3w,
                    nullptr, nullptr, cout, 0, 1 << 30, 0, bias, zrOrOut, hptr);
            } else {
                dim3 gw(2, 128, 1);
                mm_kern<128, 64, 2, 2, 3><<<gw, 256, 0, stream>>>(
                    RMh, RMl, KP, 0, wth, wtl, 0, KP, NB, KP / 32, K3w,
                    nullptr, nullptr, cout, 0, 1 << 30, 0, bias, zrOrOut, hptr);
            }
        }
    };

    // ---- encoder ----
    for (int t = 0; t < TT; ++t) {
        xcat_kern<0><<<cdiv(NB * 123, 256), 256, 0, stream>>>(RMh, RMl, x, nullptr, h0e, nullptr, t, 0, 123, 352, 96);
        agcn_core(65, 0, 352, wE0gH, wE0gL, e0gb, 128, 1, zr, nullptr, 3);
        xcat_kern<1><<<cdiv(NB * 64, 256), 256, 0, stream>>>(RMh, RMl, x, nullptr, h0e, zr, t, 1, 64, 352, 96);
        agcn_core(65, 1, 352, wE0uH, wE0uL, e0ub, 64, 3, zr, h0e, 3);
        xcat_kern<2><<<cdiv(NB * 128, 256), 256, 0, stream>>>(RMh, RMl, h0e, nullptr, h1e, nullptr, t, 0, 128, 640, 128);
        agcn_core(128, 0, 640, wE1gH, wE1gL, e1gb, 128, 1, zr, nullptr, 4);
        xcat_kern<3><<<cdiv(NB * 64, 256), 256, 0, stream>>>(RMh, RMl, h0e, nullptr, h1e, zr, t, 64, 64, 640, 128);
        agcn_core(128, 64, 640, wE1uH, wE1uL, e1ub, 64, 3, zr, h1e, 4);
    }

    // ---- memory attention ----
    attention<<<NB, 64, 0, stream>>>(h1e, Wq, Memory, dh0);
    hipMemcpyAsync(dh1, dh0, (size_t)NB * 128 * 4, hipMemcpyDeviceToDevice, stream);
    hipMemsetAsync(gob, 0, (size_t)NB * 4, stream);

    // ---- decoder ----
    for (int t = 0; t < TT; ++t) {
        xcat_kern<4><<<cdiv(NB * 182, 256), 256, 0, stream>>>(RMh, RMl, gob, y_cov, dh0, nullptr, t, 0, 182, 672, 160);
        agcn_core(130, 0, 672, wD0gH, wD0gL, d0gb, 256, 1, zr, nullptr, 5);
        xcat_kern<5><<<cdiv(NB * 128, 256), 256, 0, stream>>>(RMh, RMl, gob, y_cov, dh0, zr, t, 2, 128, 672, 160);
        agcn_core(130, 2, 672, wD0uH, wD0uL, d0ub, 128, 3, zr, dh0, 5);
        xcat_kern<6><<<cdiv(NB * 256, 256), 256, 0, stream>>>(RMh, RMl, dh0, nullptr, dh1, nullptr, t, 0, 256, 1280, 256);
        agcn_core(256, 0, 1280, wD1gH, wD1gL, d1gb, 256, 1, zr, nullptr, 8);
        xcat_kern<7><<<cdiv(NB * 128, 256), 256, 0, stream>>>(RMh, RMl, dh0, nullptr, dh1, zr, t, 128, 128, 1280, 256);
        agcn_core(256, 128, 1280, wD1uH, wD1uL, d1ub, 128, 3, zr, dh1, 8);
        proj_out<<<cdiv(NB, 256), 256, 0, stream>>>(dh1, proj_w, proj_b, gob, out, t);
    }
}

// Round 7
// 9875.489 us; speedup vs baseline: 4.9620x; 1.0837x over previous
//
#include <hip/hip_runtime.h>
#include <math.h>

#define NNODE 1024
#define BATCH 16
#define NB    16384
#define TT    12

typedef __bf16 bf16x8 __attribute__((ext_vector_type(8)));
typedef float  f32x4  __attribute__((ext_vector_type(4)));

static inline int cdiv(int a, int b) { return (a + b - 1) / b; }

// async global->LDS, 16B per lane, wave-uniform LDS base + lane*16
__device__ inline void gll16(const void* g, void* l) {
    __builtin_amdgcn_global_load_lds(
        (const __attribute__((address_space(1))) void*)g,
        (__attribute__((address_space(3))) void*)l, 16, 0, 0);
}

// ---------------------------------------------------------------------------
// Split-bf16 GEMM, counted-vmcnt double-buffered pipeline, coalesced staging,
// XCD-chunked + 2-col band block swizzle.
// D[i][j] = sum_k A[i][k]*B[j][k]  (both k-contig).
// PA/PB: plane counts. Passes: Ah*Bh always; Ah*Bl if PB==2;
//        Al*Bh if PA==2 && kt<K3 && bn<aloCols (block-uniform col gate).
// EPI 0: plain bf16 store Ch[cz + gi*ldc + gj]
// EPI 1: +bias, sigmoid -> Cf
// EPI 2: RM-transposed store (hop): tile rows are T-rows (i*16+b) at global
//        row Moff+bm; cols j -> slot 1+(bn>>10), node n=(bn+jl)&1023.
//        RM[(n*16+b)*ldc + (1+bn/1024)*cpad + i] = val  (hi only, via LDS)
// EPI 3: +bias, tanh, fused GRU: hout = r*hout + (1-r)*hc  (r from zrp)
// ---------------------------------------------------------------------------
template<int BM, int BN, int PA, int PB, int EPI>
__global__ __launch_bounds__(256) void mm_kern(
    const __bf16* __restrict__ Ah, const __bf16* __restrict__ Al, long lda, long zA,
    const __bf16* __restrict__ Bh, const __bf16* __restrict__ Bl, long zB, long ldb,
    int M, int Ksteps, int K3, int aloCols,
    __bf16* __restrict__ Ch, float* __restrict__ Cf,
    long ldc, long zC, int cpadParam, long MoffParam,
    const float* __restrict__ bias, const float* __restrict__ zrp,
    float* __restrict__ hout)
{
    constexpr int WM = BM / 2, WN = BN / 2;
    constexpr int MF = WM / 16, NF = WN / 16;
    constexpr int nA = BM / 16, nB = BN / 16;       // 1KB chunks per plane
    constexpr int NPS = (2 * nA + 2 * nB) / 4;      // chunk slots per wave (max)
    constexpr int cAl = nA / 4;
    constexpr int NPfull = nA / 4 + nB / 4 + (PA == 2 ? cAl : 0) + (PB == 2 ? nB / 4 : 0);
    constexpr int NPnoAl = NPfull - (PA == 2 ? cAl : 0);
    constexpr int bAl = BM * 32;
    constexpr int bBh = (PA == 2 ? 2 : 1) * BM * 32;
    constexpr int bBl = bBh + BN * 32;
    constexpr int BUFE = ((PA == 2 ? 2 : 1) * BM + (PB == 2 ? 2 : 1) * BN) * 32;
    __shared__ __bf16 smem[2 * BUFE];

    // ---- block swizzle: bijective XCD chunking + 2-col band ----
    const int nwgx = gridDim.x, nwgy = gridDim.y;
    const int nwg = nwgx * nwgy;
    const int lin = blockIdx.y * nwgx + blockIdx.x;
    const int q8 = nwg >> 3, r8 = nwg & 7;
    const int xcd = lin & 7, cidx = lin >> 3;
    const int lin2 = (xcd < r8) ? (xcd * (q8 + 1) + cidx)
                                : (r8 * (q8 + 1) + (xcd - r8) * q8 + cidx);
    const int G = ((nwgx & 1) == 0) ? 2 : 1;
    const int band = G * nwgy;
    const int gb = lin2 / band, rm = lin2 - gb * band;
    const int bxs = gb * G + (rm & (G - 1));
    const int bys = rm / G;

    const int bm = bys * BM, bn = bxs * BN;
    const int tid = threadIdx.x, w = tid >> 6, lane = tid & 63;
    const int wr = w >> 1, wc = w & 1;
    const int lgrp = lane >> 4, lrow = lane & 15;
    const bool aloNeed = (PA == 2) && (bn < aloCols);

    Ah += (size_t)blockIdx.z * zA;  Al += (size_t)blockIdx.z * zA;
    Bh += (size_t)blockIdx.z * zB;  Bl += (size_t)blockIdx.z * zB;

    const int srow = lane >> 2;
    const int kgel = ((lane & 3) ^ ((lane >> 3) & 3)) * 8;
    const __bf16* sp[NPS];
    int dpo[NPS];
    int ttyp[NPS];
#pragma unroll
    for (int p = 0; p < NPS; ++p) {
        int q = p * 4 + w;
        int tile = (q < nA) ? 0 : (q < 2 * nA) ? 1 : (q < 2 * nA + nB) ? 2 : 3;
        int qq = q - ((tile == 0) ? 0 : (tile == 1) ? nA : (tile == 2) ? 2 * nA : 2 * nA + nB);
        const __bf16* base = (tile == 0) ? Ah : (tile == 1) ? Al : (tile == 2) ? Bh : Bl;
        long ld = (tile < 2) ? lda : ldb;
        int  rb = (tile < 2) ? bm : bn;
        sp[p] = base + (size_t)(rb + qq * 16 + srow) * ld + kgel;
        int tbase = (tile == 0) ? 0 : (tile == 1) ? bAl : (tile == 2) ? bBh : bBl;
        dpo[p] = tbase * 2 + qq * 1024;
        ttyp[p] = tile;
    }

    f32x4 acc[MF][NF];
#pragma unroll
    for (int i = 0; i < MF; ++i)
#pragma unroll
        for (int j = 0; j < NF; ++j)
#pragma unroll
            for (int e = 0; e < 4; ++e) acc[i][j][e] = 0.f;

    auto stage = [&](int kt, int bsel) {
        char* lb = (char*)smem + bsel * (BUFE * 2);
#pragma unroll
        for (int p = 0; p < NPS; ++p) {
            int tile = ttyp[p];
            bool go = (tile == 0) || (tile == 2)
                   || (tile == 1 && aloNeed && kt < K3)
                   || (tile == 3 && PB == 2);
            if (go) gll16(sp[p] + (size_t)kt * 32, lb + dpo[p]);
        }
    };

    stage(0, 0);

    const int slotOff = (lgrp ^ ((lrow >> 1) & 3)) * 8;

    for (int kt = 0; kt < Ksteps; ++kt) {
        const int cur = kt & 1;
        __builtin_amdgcn_s_barrier();
        __builtin_amdgcn_sched_barrier(0);
        if (kt + 1 < Ksteps) {
            stage(kt + 1, cur ^ 1);
            if (aloNeed && (kt + 1) < K3)
                __builtin_amdgcn_s_waitcnt(0xF70 | NPfull);
            else
                __builtin_amdgcn_s_waitcnt(0xF70 | NPnoAl);
        } else {
            __builtin_amdgcn_s_waitcnt(0xF70);
        }
        __builtin_amdgcn_s_barrier();
        __builtin_amdgcn_sched_barrier(0);

        const __bf16* sb = smem + cur * BUFE;
        bf16x8 aH[MF], bHf[NF];
#pragma unroll
        for (int mf = 0; mf < MF; ++mf) {
            int row = wr * WM + mf * 16 + lrow;
            aH[mf] = *(const bf16x8*)(sb + (size_t)row * 32 + slotOff);
        }
#pragma unroll
        for (int nf = 0; nf < NF; ++nf) {
            int col = wc * WN + nf * 16 + lrow;
            bHf[nf] = *(const bf16x8*)(sb + bBh + (size_t)col * 32 + slotOff);
        }
        __builtin_amdgcn_s_setprio(1);
#pragma unroll
        for (int mf = 0; mf < MF; ++mf)
#pragma unroll
            for (int nf = 0; nf < NF; ++nf)
                acc[mf][nf] = __builtin_amdgcn_mfma_f32_16x16x32_bf16(aH[mf], bHf[nf], acc[mf][nf], 0, 0, 0);

        if (PB == 2) {
            bf16x8 bLf[NF];
#pragma unroll
            for (int nf = 0; nf < NF; ++nf) {
                int col = wc * WN + nf * 16 + lrow;
                bLf[nf] = *(const bf16x8*)(sb + bBl + (size_t)col * 32 + slotOff);
            }
#pragma unroll
            for (int mf = 0; mf < MF; ++mf)
#pragma unroll
                for (int nf = 0; nf < NF; ++nf)
                    acc[mf][nf] = __builtin_amdgcn_mfma_f32_16x16x32_bf16(aH[mf], bLf[nf], acc[mf][nf], 0, 0, 0);
        }
        if (PA == 2 && aloNeed && kt < K3) {
            bf16x8 aL[MF];
#pragma unroll
            for (int mf = 0; mf < MF; ++mf) {
                int row = wr * WM + mf * 16 + lrow;
                aL[mf] = *(const bf16x8*)(sb + bAl + (size_t)row * 32 + slotOff);
            }
#pragma unroll
            for (int mf = 0; mf < MF; ++mf)
#pragma unroll
                for (int nf = 0; nf < NF; ++nf)
                    acc[mf][nf] = __builtin_amdgcn_mfma_f32_16x16x32_bf16(aL[mf], bHf[nf], acc[mf][nf], 0, 0, 0);
        }
        __builtin_amdgcn_s_setprio(0);
    }

    if (EPI == 2) {
        // ---- LDS-transposed RM store (hi only) ----
        constexpr int NI = BM / 16;            // i's per block
        __syncthreads();                       // K-loop LDS reuse safe
        __bf16* LT = smem;                     // BM*BN elems <= 2*BUFE
#pragma unroll
        for (int mf = 0; mf < MF; ++mf) {
            int il = wr * MF + mf;
#pragma unroll
            for (int nf = 0; nf < NF; ++nf) {
                int nl = wc * WN + nf * 16 + lrow;
#pragma unroll
                for (int r = 0; r < 4; ++r) {
                    int b = lgrp * 4 + r;
                    LT[nl * BM + ((b ^ (nl & 15)) * NI) + il] = (__bf16)acc[mf][nf][r];
                }
            }
        }
        __syncthreads();
        const int ibase = (int)((MoffParam + bm) >> 4);
        const long scol = (long)(1 + (bn >> 10)) * cpadParam + ibase;
        const bool fullM = (bm + BM <= M);
        const bool al16 = ((scol & 7) == 0) && (NI == 8);
#pragma unroll
        for (int q = 0; q < (BN * 16) / 256; ++q) {
            int rr = q * 256 + tid;
            int nl = rr >> 4, b = rr & 15;
            int el = nl * BM + ((b ^ (nl & 15)) * NI);
            int n = (bn & 1023) + nl;
            size_t addr = ((size_t)n * 16 + b) * ldc + scol;
            if (fullM && al16) {
                *(uint4*)(Ch + addr) = *(const uint4*)(LT + el);
            } else {
#pragma unroll
                for (int il = 0; il < NI; ++il)
                    if (bm + il * 16 + b < M) Ch[addr + il] = LT[el + il];
            }
        }
        return;
    }

    const size_t cz = (size_t)blockIdx.z * zC;
#pragma unroll
    for (int mf = 0; mf < MF; ++mf) {
        int gi0 = bm + wr * WM + mf * 16 + lgrp * 4;
#pragma unroll
        for (int nf = 0; nf < NF; ++nf) {
            int gj = bn + wc * WN + nf * 16 + lrow;
#pragma unroll
            for (int r = 0; r < 4; ++r) {
                int gi = gi0 + r;
                if (gi < M) {
                    float v = acc[mf][nf][r];
                    if (EPI == 0) {
                        Ch[cz + (size_t)gi * ldc + gj] = (__bf16)v;
                    } else if (EPI == 1) {
                        v += bias[gj];
                        v = 1.f / (1.f + expf(-v));
                        Cf[cz + (size_t)gi * ldc + gj] = v;
                    } else if (EPI == 3) {
                        v += bias[gj];
                        v = tanhf(v);
                        float rg = zrp[(size_t)gi * 2 * ldc + ldc + gj];
                        size_t hix = (size_t)gi * ldc + gj;
                        hout[hix] = rg * hout[hix] + (1.f - rg) * v;
                    }
                }
            }
        }
    }
}

// ---------------------------------------------------------------------------
// LDS-tiled transpose RM slot0 -> T slot0: T[i*16+b][node] from RM[(n*16+b)][kk]
// (dir-0 only now). kk in [kk0, kkEnd).
// ---------------------------------------------------------------------------
__global__ __launch_bounds__(256) void trans_kern(
    __bf16* __restrict__ TH, __bf16* __restrict__ TL,
    const __bf16* __restrict__ RH, const __bf16* __restrict__ RL,
    int c, int KP, int kk0, int kkEnd)
{
    __shared__ __bf16 tile[32][66];
    const int b = blockIdx.z, nt = blockIdx.y * 64;
    const int kkb = kk0 + blockIdx.x * 32;
    const int t = threadIdx.x;

    for (int cp = 0; cp < 2; ++cp) {
        __bf16* Tp = cp ? TL : TH;
        const __bf16* Rp = cp ? RL : RH;
#pragma unroll
        for (int rep = 0; rep < 8; ++rep) {
            int kk = kkb + (t & 31);
            int nl = rep * 8 + (t >> 5);
            __bf16 v = (__bf16)0.f;
            if (kk < kkEnd) v = Rp[(size_t)((nt + nl) * 16 + b) * KP + kk];
            tile[t & 31][nl] = v;
        }
        __syncthreads();
#pragma unroll
        for (int rep = 0; rep < 8; ++rep) {
            int kkl = rep * 4 + (t >> 6);
            int kk = kkb + kkl;
            int n = nt + (t & 63);
            if (kk < kkEnd)
                Tp[((size_t)kk * 16 + b) * 1024 + n] = tile[kkl][t & 63];
        }
        __syncthreads();
    }
}

// ---------------------------------------------------------------------------
// Build concat input into RM slot0 region, split to bf16 hi/lo.
// Gate (ccStart==0): cols [0, width) linear; cc>=C -> zeros (pad + straddle).
// Update: cols [ccStart, ccStart+width).
// ---------------------------------------------------------------------------
template<int MODE>
__global__ __launch_bounds__(256) void xcat_kern(
    __bf16* __restrict__ dH, __bf16* __restrict__ dL,
    const float* __restrict__ s1, const float* __restrict__ s2,
    const float* __restrict__ h, const float* __restrict__ zr,
    int t, int ccStart, int width, int KP)
{
    constexpr int C = (MODE < 2) ? 65 : (MODE < 4) ? 128 : (MODE < 6) ? 130 : 256;
    int idx = blockIdx.x * 256 + threadIdx.x;
    if (idx >= NB * width) return;
    int r = idx / width, ww = idx - r * width;
    int cc = ccStart + ww;
    int n = r >> 4, b = r & 15;
    float v = 0.f;
    if (cc < C) {
        if (MODE == 0 || MODE == 1) {
            if (cc == 0) v = s1[((size_t)b * TT + t) * NNODE + n];
            else { float hv = h[(size_t)r * 64 + cc - 1];
                   v = (MODE == 1) ? zr[(size_t)r * 128 + cc - 1] * hv : hv; }
        } else if (MODE == 2 || MODE == 3) {
            if (cc < 64) v = s1[(size_t)r * 64 + cc];
            else { float hv = h[(size_t)r * 64 + cc - 64];
                   v = (MODE == 3) ? zr[(size_t)r * 128 + cc - 64] * hv : hv; }
        } else if (MODE == 4 || MODE == 5) {
            if (cc == 0) v = s1[r];
            else if (cc == 1) v = s2[((size_t)b * TT + t) * NNODE + n];
            else { float hv = h[(size_t)r * 128 + cc - 2];
                   v = (MODE == 5) ? zr[(size_t)r * 256 + cc - 2] * hv : hv; }
        } else {
            if (cc < 128) v = s1[(size_t)r * 128 + cc];
            else { float hv = h[(size_t)r * 128 + cc - 128];
                   v = (MODE == 7) ? zr[(size_t)r * 256 + cc - 128] * hv : hv; }
        }
    }
    __bf16 hi = (__bf16)v;
    size_t o = (size_t)r * KP + cc;
    dH[o] = hi;
    dL[o] = (__bf16)(v - (float)hi);
}

// ---------------------------------------------------------------------------
// small kernels
// ---------------------------------------------------------------------------
__global__ __launch_bounds__(256) void compute_ne(
    const float* __restrict__ We1, const float* __restrict__ We2,
    const float* __restrict__ Mem, float* __restrict__ ne1, float* __restrict__ ne2)
{
    int idx = blockIdx.x * 256 + threadIdx.x;
    if (idx >= 2 * 65536) return;
    int which = idx >> 16;
    int i = idx & 65535;
    int n = i >> 6, d = i & 63;
    const float* We = which ? We2 : We1;
    float acc = 0.f;
#pragma unroll
    for (int k = 0; k < 20; ++k) acc += We[n * 20 + k] * Mem[k * 64 + d];
    (which ? ne2 : ne1)[i] = acc;
}

__global__ __launch_bounds__(256) void build_g(
    const float* __restrict__ ne1, const float* __restrict__ ne2, float* __restrict__ g)
{
    int row = blockIdx.x;
    int n = row & 1023;
    const float* qa = (row < 1024) ? ne1 : ne2;
    const float* kb = (row < 1024) ? ne2 : ne1;
    __shared__ float q[64];
    __shared__ float sc[1024];
    __shared__ float red[256];
    int tid = threadIdx.x;
    if (tid < 64) q[tid] = qa[n * 64 + tid];
    __syncthreads();
    for (int m = tid; m < 1024; m += 256) {
        float acc = 0.f;
        const float* kr = kb + m * 64;
#pragma unroll 8
        for (int d = 0; d < 64; ++d) acc += q[d] * kr[d];
        sc[m] = fmaxf(acc, 0.f);
    }
    __syncthreads();
    float mx = -1e30f;
    for (int m = tid; m < 1024; m += 256) mx = fmaxf(mx, sc[m]);
    red[tid] = mx;
    __syncthreads();
    for (int s2 = 128; s2 > 0; s2 >>= 1) {
        if (tid < s2) red[tid] = fmaxf(red[tid], red[tid + s2]);
        __syncthreads();
    }
    mx = red[0];
    __syncthreads();
    float sum = 0.f;
    for (int m = tid; m < 1024; m += 256) {
        float e = expf(sc[m] - mx);
        sc[m] = e;
        sum += e;
    }
    red[tid] = sum;
    __syncthreads();
    for (int s2 = 128; s2 > 0; s2 >>= 1) {
        if (tid < s2) red[tid] += red[tid + s2];
        __syncthreads();
    }
    float inv = 1.f / red[0];
    for (int m = tid; m < 1024; m += 256) g[(size_t)row * 1024 + m] = sc[m] * inv;
}

// gf (2048x1024 f32) -> gquad rows 0..2047 (hi) + gsL (lo)
__global__ __launch_bounds__(256) void g_split(
    const float* __restrict__ g, __bf16* __restrict__ gh, __bf16* __restrict__ gl)
{
    int i = blockIdx.x * 256 + threadIdx.x;
    if (i >= 2048 * 1024) return;
    float v = g[i];
    __bf16 h = (__bf16)v;
    gh[i] = h;
    gl[i] = (__bf16)(v - (float)h);
}

// gT[z][k][m] = gf[z][m][k], split hi/lo  (for G2 = g @ g)
__global__ __launch_bounds__(256) void gT_kern(
    const float* __restrict__ gf, __bf16* __restrict__ gTh, __bf16* __restrict__ gTl)
{
    __shared__ float tile[32][33];
    int z = blockIdx.z;
    int m0 = blockIdx.y * 32, k0 = blockIdx.x * 32;
    int tx = threadIdx.x & 31, ty = threadIdx.x >> 5;
    for (int r = ty; r < 32; r += 8)
        tile[r][tx] = gf[(size_t)(z * 1024 + m0 + r) * 1024 + k0 + tx];
    __syncthreads();
    for (int r = ty; r < 32; r += 8) {
        float v = tile[tx][r];
        __bf16 h = (__bf16)v;
        size_t o = (size_t)(z * 1024 + k0 + r) * 1024 + m0 + tx;
        gTh[o] = h;
        gTl[o] = (__bf16)(v - (float)h);
    }
}

// effective weight, transposed [cout][KP], padded slots (cpad), order
// [X, Y1, Z1, Y2, Z2] -> [W0+W3-W2-W5, W1, W4, 2W2, 2W5]
__global__ __launch_bounds__(256) void build_weffT(
    const float* __restrict__ W, __bf16* __restrict__ dh, __bf16* __restrict__ dl,
    int c, int cpad, int cout, int KP)
{
    int idx = blockIdx.x * 256 + threadIdx.x;
    if (idx >= cout * KP) return;
    int o = idx / KP, kk = idx - o * KP;
    float v = 0.f;
    if (kk < 5 * cpad) {
        int s = kk / cpad;
        int i = kk - s * cpad;
        if (i < c) {
            if      (s == 0) v = W[(size_t)(0 * c + i) * cout + o] + W[(size_t)(3 * c + i) * cout + o]
                               - W[(size_t)(2 * c + i) * cout + o] - W[(size_t)(5 * c + i) * cout + o];
            else if (s == 1) v = W[(size_t)(1 * c + i) * cout + o];
            else if (s == 2) v = W[(size_t)(4 * c + i) * cout + o];
            else if (s == 3) v = 2.f * W[(size_t)(2 * c + i) * cout + o];
            else             v = 2.f * W[(size_t)(5 * c + i) * cout + o];
        }
    }
    __bf16 h = (__bf16)v;
    dh[idx] = h;
    dl[idx] = (__bf16)(v - (float)h);
}

__global__ __launch_bounds__(64) void attention(
    const float* __restrict__ h, const float* __restrict__ Wq,
    const float* __restrict__ Mem, float* __restrict__ htc)
{
    int r = blockIdx.x;
    int j = threadIdx.x;
    __shared__ float hr[64], q[64], sc[20];
    hr[j] = h[(size_t)r * 64 + j];
    __syncthreads();
    float acc = 0.f;
#pragma unroll 8
    for (int i = 0; i < 64; ++i) acc += hr[i] * Wq[i * 64 + j];
    q[j] = acc;
    __syncthreads();
    if (j < 20) {
        float a = 0.f;
#pragma unroll 8
        for (int d = 0; d < 64; ++d) a += q[d] * Mem[j * 64 + d];
        sc[j] = a;
    }
    __syncthreads();
    if (j == 0) {
        float mx = sc[0];
        for (int m = 1; m < 20; ++m) mx = fmaxf(mx, sc[m]);
        float s = 0.f;
        for (int m = 0; m < 20; ++m) { sc[m] = expf(sc[m] - mx); s += sc[m]; }
        float inv = 1.f / s;
        for (int m = 0; m < 20; ++m) sc[m] *= inv;
    }
    __syncthreads();
    float v = 0.f;
#pragma unroll
    for (int m = 0; m < 20; ++m) v += sc[m] * Mem[m * 64 + j];
    htc[(size_t)r * 128 + j] = hr[j];
    htc[(size_t)r * 128 + 64 + j] = v;
}

__global__ __launch_bounds__(256) void proj_out(
    const float* __restrict__ h1, const float* __restrict__ pw, const float* __restrict__ pb,
    float* __restrict__ go, float* __restrict__ out, int t)
{
    int r = blockIdx.x * 256 + threadIdx.x;
    if (r >= NB) return;
    float acc = pb[0];
    const float* hr = h1 + (size_t)r * 128;
#pragma unroll 8
    for (int i = 0; i < 128; ++i) acc += hr[i] * pw[i];
    go[r] = acc;
    int n = r >> 4, b = r & 15;
    out[((size_t)b * TT + t) * NNODE + n] = acc;
}

// ---------------------------------------------------------------------------
// host
// ---------------------------------------------------------------------------
extern "C" void kernel_launch(void* const* d_in, const int* in_sizes, int n_in,
                              void* d_out, int out_size, void* d_ws, size_t ws_size,
                              hipStream_t stream)
{
    const float* x      = (const float*)d_in[0];
    const float* y_cov  = (const float*)d_in[1];
    const float* Memory = (const float*)d_in[2];
    const float* Wq     = (const float*)d_in[3];
    const float* We1    = (const float*)d_in[4];
    const float* We2    = (const float*)d_in[5];
    const float* e0gw = (const float*)d_in[6];  const float* e0gb = (const float*)d_in[7];
    const float* e0uw = (const float*)d_in[8];  const float* e0ub = (const float*)d_in[9];
    const float* e1gw = (const float*)d_in[10]; const float* e1gb = (const float*)d_in[11];
    const float* e1uw = (const float*)d_in[12]; const float* e1ub = (const float*)d_in[13];
    const float* d0gw = (const float*)d_in[14]; const float* d0gb = (const float*)d_in[15];
    const float* d0uw = (const float*)d_in[16]; const float* d0ub = (const float*)d_in[17];
    const float* d1gw = (const float*)d_in[18]; const float* d1gb = (const float*)d_in[19];
    const float* d1uw = (const float*)d_in[20]; const float* d1ub = (const float*)d_in[21];
    const float* proj_w = (const float*)d_in[22];
    const float* proj_b = (const float*)d_in[23];
    float* out = (float*)d_out;
    (void)in_sizes; (void)n_in; (void)out_size; (void)ws_size;

    char* wsb = (char*)d_ws;
    size_t off = 0;
    auto alloc = [&](size_t bytes) -> void* {
        void* p = wsb + off;
        off += (bytes + 255) & ~(size_t)255;
        return p;
    };

    float*  gf   = (float*) alloc(2048L * 1024 * 4);
    __bf16* gquad = (__bf16*)alloc(4096L * 1024 * 2);   // g1|g2|G2_1|G2_2 (hi)
    __bf16* gsL  = (__bf16*)alloc(2048L * 1024 * 2);
    __bf16* gTh  = (__bf16*)alloc(2048L * 1024 * 2);
    __bf16* gTl  = (__bf16*)alloc(2048L * 1024 * 2);
    float*  ne1  = (float*) alloc(65536L * 4);
    float*  ne2  = (float*) alloc(65536L * 4);
    auto allocWT = [&](int cout, int KP, __bf16** h, __bf16** l) {
        *h = (__bf16*)alloc((size_t)cout * KP * 2);
        *l = (__bf16*)alloc((size_t)cout * KP * 2);
    };
    __bf16 *wE0gH, *wE0gL, *wE0uH, *wE0uL, *wE1gH, *wE1gL, *wE1uH, *wE1uL;
    __bf16 *wD0gH, *wD0gL, *wD0uH, *wD0uL, *wD1gH, *wD1gL, *wD1uH, *wD1uL;
    allocWT(128, 384,  &wE0gH, &wE0gL);  allocWT(64, 384,  &wE0uH, &wE0uL);
    allocWT(128, 640,  &wE1gH, &wE1gL);  allocWT(64, 640,  &wE1uH, &wE1uL);
    allocWT(256, 704,  &wD0gH, &wD0gL);  allocWT(128, 704, &wD0uH, &wD0uL);
    allocWT(256, 1280, &wD1gH, &wD1gL);  allocWT(128, 1280, &wD1uH, &wD1uL);
    __bf16* RMh = (__bf16*)alloc((size_t)NB * 1280 * 2);
    __bf16* RMl = (__bf16*)alloc((size_t)NB * 1280 * 2);
    __bf16* Th  = (__bf16*)alloc((size_t)(4096 + 128) * 1024 * 2);
    __bf16* Tl  = (__bf16*)alloc((size_t)(4096 + 128) * 1024 * 2);
    float* zr  = (float*)alloc((size_t)NB * 256 * 4);
    float* h0e = (float*)alloc((size_t)NB * 64 * 4);
    float* h1e = (float*)alloc((size_t)NB * 64 * 4);
    float* dh0 = (float*)alloc((size_t)NB * 128 * 4);
    float* dh1 = (float*)alloc((size_t)NB * 128 * 4);
    float* gob = (float*)alloc((size_t)NB * 4);

    // ---- setup ----
    compute_ne<<<cdiv(2 * 65536, 256), 256, 0, stream>>>(We1, We2, Memory, ne1, ne2);
    build_g<<<2048, 256, 0, stream>>>(ne1, ne2, gf);
    g_split<<<cdiv(2048 * 1024, 256), 256, 0, stream>>>(gf, gquad, gsL);
    {
        dim3 gt(32, 32, 2);
        gT_kern<<<gt, 256, 0, stream>>>(gf, gTh, gTl);
        // G2_z = g_z @ g_z  (3-pass split), -> gquad rows 2048 + z*1024
        dim3 gg(8, 8, 2);
        mm_kern<128, 128, 2, 2, 0><<<gg, 256, 0, stream>>>(
            gquad, gsL, 1024, (long)1024 * 1024,
            gTh, gTl, (long)1024 * 1024, 1024,
            1024, 32, 32, 1 << 30,
            gquad + (size_t)2048 * 1024, nullptr, 1024, (long)1024 * 1024,
            0, 0, nullptr, nullptr, nullptr);
    }
    build_weffT<<<cdiv(128 * 384, 256), 256, 0, stream>>>(e0gw, wE0gH, wE0gL, 65, 72, 128, 384);
    build_weffT<<<cdiv(64 * 384, 256), 256, 0, stream>>>(e0uw, wE0uH, wE0uL, 65, 72, 64, 384);
    build_weffT<<<cdiv(128 * 640, 256), 256, 0, stream>>>(e1gw, wE1gH, wE1gL, 128, 128, 128, 640);
    build_weffT<<<cdiv(64 * 640, 256), 256, 0, stream>>>(e1uw, wE1uH, wE1uL, 128, 128, 64, 640);
    build_weffT<<<cdiv(256 * 704, 256), 256, 0, stream>>>(d0gw, wD0gH, wD0gL, 130, 136, 256, 704);
    build_weffT<<<cdiv(128 * 704, 256), 256, 0, stream>>>(d0uw, wD0uH, wD0uL, 130, 136, 128, 704);
    build_weffT<<<cdiv(256 * 1280, 256), 256, 0, stream>>>(d1gw, wD1gH, wD1gL, 256, 256, 256, 1280);
    build_weffT<<<cdiv(128 * 1280, 256), 256, 0, stream>>>(d1uw, wD1uH, wD1uL, 256, 256, 128, 1280);
    hipMemsetAsync(h0e, 0, (size_t)NB * 64 * 4 * 2, stream);   // h0e + h1e adjacent

    // cell: xcat -> trans0 -> merged hop (EPI2, RM direct) -> weight GEMM
    auto agcn_core = [&](int c, int cpad, int cin2, int KP,
                         const __bf16* wth, const __bf16* wtl,
                         const float* bias, int cout, int epi, float* zrOrOut, float* hptr,
                         int K3w) {
        int Moff = 16 * cin2, Mv = 16 * c - Moff;
        dim3 t0(cdiv(c - cin2, 32), 16, 16);
        trans_kern<<<t0, 256, 0, stream>>>(Th, Tl, RMh, RMl, c, KP, cin2, c);
        // merged hop: B = [g1 | g2 | G2_1 | G2_2], N=4096; A-lo only for bn<2048
        dim3 gh(32, cdiv(Mv, 128), 1);
        mm_kern<128, 128, 2, 1, 2><<<gh, 256, 0, stream>>>(
            Th + (size_t)Moff * 1024, Tl + (size_t)Moff * 1024, 1024, 0,
            gquad, gquad, 0, 1024,
            Mv, 32, 32, 2048,
            RMh, nullptr, KP, 0, cpad, Moff,
            nullptr, nullptr, nullptr);
        if (epi == 1) {
            dim3 gw((cout == 256) ? 2 : 2, 128, 1);
            if (cout == 256)
                mm_kern<128, 128, 2, 2, 1><<<gw, 256, 0, stream>>>(
                    RMh, RMl, KP, 0, wth, wtl, 0, KP, NB, KP / 32, K3w, 1 << 30,
                    nullptr, zrOrOut, cout, 0, 0, 0, bias, nullptr, nullptr);
            else
                mm_kern<128, 64, 2, 2, 1><<<gw, 256, 0, stream>>>(
                    RMh, RMl, KP, 0, wth, wtl, 0, KP, NB, KP / 32, K3w, 1 << 30,
                    nullptr, zrOrOut, cout, 0, 0, 0, bias, nullptr, nullptr);
        } else {
            if (cout == 64) {
                dim3 gw(1, 256, 1);
                mm_kern<64, 64, 2, 2, 3><<<gw, 256, 0, stream>>>(
                    RMh, RMl, KP, 0, wth, wtl, 0, KP, NB, KP / 32, K3w, 1 << 30,
                    nullptr, nullptr, cout, 0, 0, 0, bias, zrOrOut, hptr);
            } else {
                dim3 gw(2, 128, 1);
                mm_kern<128, 64, 2, 2, 3><<<gw, 256, 0, stream>>>(
                    RMh, RMl, KP, 0, wth, wtl, 0, KP, NB, KP / 32, K3w, 1 << 30,
                    nullptr, nullptr, cout, 0, 0, 0, bias, zrOrOut, hptr);
            }
        }
    };

    // ---- encoder ----
    for (int t = 0; t < TT; ++t) {
        xcat_kern<0><<<cdiv(NB * 96, 256), 256, 0, stream>>>(RMh, RMl, x, nullptr, h0e, nullptr, t, 0, 96, 384);
        agcn_core(65, 72, 0, 384, wE0gH, wE0gL, e0gb, 128, 1, zr, nullptr, 3);
        xcat_kern<1><<<cdiv(NB * 64, 256), 256, 0, stream>>>(RMh, RMl, x, nullptr, h0e, zr, t, 1, 64, 384);
        agcn_core(65, 72, 1, 384, wE0uH, wE0uL, e0ub, 64, 3, zr, h0e, 3);
        xcat_kern<2><<<cdiv(NB * 128, 256), 256, 0, stream>>>(RMh, RMl, h0e, nullptr, h1e, nullptr, t, 0, 128, 640);
        agcn_core(128, 128, 0, 640, wE1gH, wE1gL, e1gb, 128, 1, zr, nullptr, 4);
        xcat_kern<3><<<cdiv(NB * 64, 256), 256, 0, stream>>>(RMh, RMl, h0e, nullptr, h1e, zr, t, 64, 64, 640);
        agcn_core(128, 128, 64, 640, wE1uH, wE1uL, e1ub, 64, 3, zr, h1e, 4);
    }

    // ---- memory attention ----
    attention<<<NB, 64, 0, stream>>>(h1e, Wq, Memory, dh0);
    hipMemcpyAsync(dh1, dh0, (size_t)NB * 128 * 4, hipMemcpyDeviceToDevice, stream);
    hipMemsetAsync(gob, 0, (size_t)NB * 4, stream);

    // ---- decoder ----
    for (int t = 0; t < TT; ++t) {
        xcat_kern<4><<<cdiv(NB * 160, 256), 256, 0, stream>>>(RMh, RMl, gob, y_cov, dh0, nullptr, t, 0, 160, 704);
        agcn_core(130, 136, 0, 704, wD0gH, wD0gL, d0gb, 256, 1, zr, nullptr, 5);
        xcat_kern<5><<<cdiv(NB * 128, 256), 256, 0, stream>>>(RMh, RMl, gob, y_cov, dh0, zr, t, 2, 128, 704);
        agcn_core(130, 136, 2, 704, wD0uH, wD0uL, d0ub, 128, 3, zr, dh0, 5);
        xcat_kern<6><<<cdiv(NB * 256, 256), 256, 0, stream>>>(RMh, RMl, dh0, nullptr, dh1, nullptr, t, 0, 256, 1280);
        agcn_core(256, 256, 0, 1280, wD1gH, wD1gL, d1gb, 256, 1, zr, nullptr, 8);
        xcat_kern<7><<<cdiv(NB * 128, 256), 256, 0, stream>>>(RMh, RMl, dh0, nullptr, dh1, zr, t, 128, 128, 1280);
        agcn_core(256, 256, 128, 1280, wD1uH, wD1uL, d1ub, 128, 3, zr, dh1, 8);
        proj_out<<<cdiv(NB, 256), 256, 0, stream>>>(dh1, proj_w, proj_b, gob, out, t);
    }
}

// Round 8
// 7186.497 us; speedup vs baseline: 6.8187x; 1.3742x over previous
//
#include <hip/hip_runtime.h>
#include <math.h>

#define NNODE 1024
#define BATCH 16
#define NB    16384
#define TT    12

typedef __bf16 bf16x8 __attribute__((ext_vector_type(8)));
typedef float  f32x4  __attribute__((ext_vector_type(4)));

static inline int cdiv(int a, int b) { return (a + b - 1) / b; }

// async global->LDS, 16B per lane, wave-uniform LDS base + lane*16
__device__ inline void gll16(const void* g, void* l) {
    __builtin_amdgcn_global_load_lds(
        (const __attribute__((address_space(1))) void*)g,
        (__attribute__((address_space(3))) void*)l, 16, 0, 0);
}

// ---------------------------------------------------------------------------
// Split-bf16 GEMM, counted-vmcnt double-buffered pipeline, coalesced staging,
// XCD-chunked + 2-col band block swizzle.
// D[i][j] = sum_k A[i][k]*B[j][k]  (both k-contig).
// PA/PB: plane counts (1 = hi only). Passes: Ah*Bh always; Ah*Bl if PB==2;
//        Al*Bh if PA==2 && kt<K3 && bn<aloCols.
// EPI 0: plain bf16 store Ch
// EPI 1: +bias, sigmoid -> Cf
// EPI 2: RM-transposed hop store: RM[(n*16+b)*ldc + (1+bn/1024)*cpad + i] (hi)
// EPI 3: +bias, tanh, fused GRU: hout = r*hout + (1-r)*hc  (r from zrp)
// ---------------------------------------------------------------------------
template<int BM, int BN, int PA, int PB, int EPI>
__global__ __launch_bounds__(256) void mm_kern(
    const __bf16* __restrict__ Ah, const __bf16* __restrict__ Al, long lda, long zA,
    const __bf16* __restrict__ Bh, const __bf16* __restrict__ Bl, long zB, long ldb,
    int M, int Ksteps, int K3, int aloCols,
    __bf16* __restrict__ Ch, float* __restrict__ Cf,
    long ldc, long zC, int cpadParam, long MoffParam,
    const float* __restrict__ bias, const float* __restrict__ zrp,
    float* __restrict__ hout)
{
    constexpr int WM = BM / 2, WN = BN / 2;
    constexpr int MF = WM / 16, NF = WN / 16;
    constexpr int nA = BM / 16, nB = BN / 16;       // 1KB chunks per plane
    constexpr int nAl = (PA == 2) ? nA : 0;
    constexpr int nBl = (PB == 2) ? nB : 0;
    constexpr int TOT = nA + nAl + nB + nBl;
    constexpr int NPS = TOT / 4;                    // chunk slots per wave
    constexpr int cAlw = nAl / 4;
    constexpr int NPfull = NPS, NPnoAl = NPS - cAlw;
    constexpr int e0 = nA, e1 = nA + nAl, e2 = nA + nAl + nB;
    constexpr int bAl = BM * 32;
    constexpr int bBh = (PA == 2 ? 2 : 1) * BM * 32;
    constexpr int bBl = bBh + BN * 32;
    constexpr int BUFE = ((PA == 2 ? 2 : 1) * BM + (PB == 2 ? 2 : 1) * BN) * 32;
    __shared__ __bf16 smem[2 * BUFE];

    // ---- block swizzle: bijective XCD chunking + 2-col band ----
    const int nwgx = gridDim.x, nwgy = gridDim.y;
    const int nwg = nwgx * nwgy;
    const int lin = blockIdx.y * nwgx + blockIdx.x;
    const int q8 = nwg >> 3, r8 = nwg & 7;
    const int xcd = lin & 7, cidx = lin >> 3;
    const int lin2 = (xcd < r8) ? (xcd * (q8 + 1) + cidx)
                                : (r8 * (q8 + 1) + (xcd - r8) * q8 + cidx);
    const int G = ((nwgx & 1) == 0) ? 2 : 1;
    const int band = G * nwgy;
    const int gb = lin2 / band, rm = lin2 - gb * band;
    const int bxs = gb * G + (rm & (G - 1));
    const int bys = rm / G;

    const int bm = bys * BM, bn = bxs * BN;
    const int tid = threadIdx.x, w = tid >> 6, lane = tid & 63;
    const int wr = w >> 1, wc = w & 1;
    const int lgrp = lane >> 4, lrow = lane & 15;
    const bool aloNeed = (PA == 2) && (bn < aloCols);

    Ah += (size_t)blockIdx.z * zA;  Al += (size_t)blockIdx.z * zA;
    Bh += (size_t)blockIdx.z * zB;  Bl += (size_t)blockIdx.z * zB;

    const int srow = lane >> 2;
    const int kgel = ((lane & 3) ^ ((lane >> 3) & 3)) * 8;
    const __bf16* sp[NPS];
    int dpo[NPS];
    int ttyp[NPS];
#pragma unroll
    for (int p = 0; p < NPS; ++p) {
        int q = p * 4 + w;
        int tile = (q < e0) ? 0 : (q < e1) ? 1 : (q < e2) ? 2 : 3;
        int qq = q - ((tile == 0) ? 0 : (tile == 1) ? e0 : (tile == 2) ? e1 : e2);
        const __bf16* base = (tile == 0) ? Ah : (tile == 1) ? Al : (tile == 2) ? Bh : Bl;
        long ld = (tile < 2) ? lda : ldb;
        int  rb = (tile < 2) ? bm : bn;
        sp[p] = base + (size_t)(rb + qq * 16 + srow) * ld + kgel;
        int tbase = (tile == 0) ? 0 : (tile == 1) ? bAl : (tile == 2) ? bBh : bBl;
        dpo[p] = tbase * 2 + qq * 1024;
        ttyp[p] = tile;
    }

    f32x4 acc[MF][NF];
#pragma unroll
    for (int i = 0; i < MF; ++i)
#pragma unroll
        for (int j = 0; j < NF; ++j)
#pragma unroll
            for (int e = 0; e < 4; ++e) acc[i][j][e] = 0.f;

    auto stage = [&](int kt, int bsel) {
        char* lb = (char*)smem + bsel * (BUFE * 2);
#pragma unroll
        for (int p = 0; p < NPS; ++p) {
            int tile = ttyp[p];
            bool go = (tile == 0) || (tile == 2)
                   || (tile == 1 && aloNeed && kt < K3)
                   || (tile == 3 && PB == 2);
            if (go) gll16(sp[p] + (size_t)kt * 32, lb + dpo[p]);
        }
    };

    stage(0, 0);

    const int slotOff = (lgrp ^ ((lrow >> 1) & 3)) * 8;

    for (int kt = 0; kt < Ksteps; ++kt) {
        const int cur = kt & 1;
        __builtin_amdgcn_s_barrier();
        __builtin_amdgcn_sched_barrier(0);
        if (kt + 1 < Ksteps) {
            stage(kt + 1, cur ^ 1);
            if (aloNeed && (kt + 1) < K3)
                __builtin_amdgcn_s_waitcnt(0xF70 | NPfull);
            else
                __builtin_amdgcn_s_waitcnt(0xF70 | NPnoAl);
        } else {
            __builtin_amdgcn_s_waitcnt(0xF70);
        }
        __builtin_amdgcn_s_barrier();
        __builtin_amdgcn_sched_barrier(0);

        const __bf16* sb = smem + cur * BUFE;
        bf16x8 aH[MF], bHf[NF];
#pragma unroll
        for (int mf = 0; mf < MF; ++mf) {
            int row = wr * WM + mf * 16 + lrow;
            aH[mf] = *(const bf16x8*)(sb + (size_t)row * 32 + slotOff);
        }
#pragma unroll
        for (int nf = 0; nf < NF; ++nf) {
            int col = wc * WN + nf * 16 + lrow;
            bHf[nf] = *(const bf16x8*)(sb + bBh + (size_t)col * 32 + slotOff);
        }
        __builtin_amdgcn_s_setprio(1);
#pragma unroll
        for (int mf = 0; mf < MF; ++mf)
#pragma unroll
            for (int nf = 0; nf < NF; ++nf)
                acc[mf][nf] = __builtin_amdgcn_mfma_f32_16x16x32_bf16(aH[mf], bHf[nf], acc[mf][nf], 0, 0, 0);

        if (PB == 2) {
            bf16x8 bLf[NF];
#pragma unroll
            for (int nf = 0; nf < NF; ++nf) {
                int col = wc * WN + nf * 16 + lrow;
                bLf[nf] = *(const bf16x8*)(sb + bBl + (size_t)col * 32 + slotOff);
            }
#pragma unroll
            for (int mf = 0; mf < MF; ++mf)
#pragma unroll
                for (int nf = 0; nf < NF; ++nf)
                    acc[mf][nf] = __builtin_amdgcn_mfma_f32_16x16x32_bf16(aH[mf], bLf[nf], acc[mf][nf], 0, 0, 0);
        }
        if (PA == 2 && aloNeed && kt < K3) {
            bf16x8 aL[MF];
#pragma unroll
            for (int mf = 0; mf < MF; ++mf) {
                int row = wr * WM + mf * 16 + lrow;
                aL[mf] = *(const bf16x8*)(sb + bAl + (size_t)row * 32 + slotOff);
            }
#pragma unroll
            for (int mf = 0; mf < MF; ++mf)
#pragma unroll
                for (int nf = 0; nf < NF; ++nf)
                    acc[mf][nf] = __builtin_amdgcn_mfma_f32_16x16x32_bf16(aL[mf], bHf[nf], acc[mf][nf], 0, 0, 0);
        }
        __builtin_amdgcn_s_setprio(0);
    }

    if (EPI == 2) {
        // ---- LDS-transposed RM store (hi only) ----
        constexpr int NI = BM / 16;
        __syncthreads();
        __bf16* LT = smem;                  // BM*BN elems == 2*BUFE for 1,1 cfg
#pragma unroll
        for (int mf = 0; mf < MF; ++mf) {
            int il = wr * MF + mf;
#pragma unroll
            for (int nf = 0; nf < NF; ++nf) {
                int nl = wc * WN + nf * 16 + lrow;
#pragma unroll
                for (int r = 0; r < 4; ++r) {
                    int b = lgrp * 4 + r;
                    LT[nl * BM + ((b ^ (nl & 15)) * NI) + il] = (__bf16)acc[mf][nf][r];
                }
            }
        }
        __syncthreads();
        const int ibase = (int)((MoffParam + bm) >> 4);
        const long scol = (long)(1 + (bn >> 10)) * cpadParam + ibase;
        const bool fullM = (bm + BM <= M);
        const bool al16 = ((scol & 7) == 0) && (NI == 8);
#pragma unroll
        for (int q = 0; q < (BN * 16) / 256; ++q) {
            int rr = q * 256 + tid;
            int nl = rr >> 4, b = rr & 15;
            int el = nl * BM + ((b ^ (nl & 15)) * NI);
            int n = (bn & 1023) + nl;
            size_t addr = ((size_t)n * 16 + b) * ldc + scol;
            if (fullM && al16) {
                *(uint4*)(Ch + addr) = *(const uint4*)(LT + el);
            } else {
#pragma unroll
                for (int il = 0; il < NI; ++il)
                    if (bm + il * 16 + b < M) Ch[addr + il] = LT[el + il];
            }
        }
        return;
    }

    const size_t cz = (size_t)blockIdx.z * zC;
#pragma unroll
    for (int mf = 0; mf < MF; ++mf) {
        int gi0 = bm + wr * WM + mf * 16 + lgrp * 4;
#pragma unroll
        for (int nf = 0; nf < NF; ++nf) {
            int gj = bn + wc * WN + nf * 16 + lrow;
#pragma unroll
            for (int r = 0; r < 4; ++r) {
                int gi = gi0 + r;
                if (gi < M) {
                    float v = acc[mf][nf][r];
                    if (EPI == 0) {
                        Ch[cz + (size_t)gi * ldc + gj] = (__bf16)v;
                    } else if (EPI == 1) {
                        v += bias[gj];
                        v = 1.f / (1.f + expf(-v));
                        Cf[cz + (size_t)gi * ldc + gj] = v;
                    } else if (EPI == 3) {
                        v += bias[gj];
                        v = tanhf(v);
                        float rg = zrp[(size_t)gi * 2 * ldc + ldc + gj];
                        size_t hix = (size_t)gi * ldc + gj;
                        hout[hix] = rg * hout[hix] + (1.f - rg) * v;
                    }
                }
            }
        }
    }
}

// ---------------------------------------------------------------------------
// Fused concat-build + transpose: computes v(cc,n,b), writes RM hi/lo
// (coalesced, cc-contig) for cc in [cc0, zEnd) and T hi plane
// (coalesced, n-contig, via LDS) for cc in [cc0, C).
// Gate cells (cc0==0) also zero RMl straddle [C, zEnd).
// ---------------------------------------------------------------------------
template<int MODE>
__global__ __launch_bounds__(256) void xcatT_kern(
    __bf16* __restrict__ RMh, __bf16* __restrict__ RMl, __bf16* __restrict__ Th,
    const float* __restrict__ s1, const float* __restrict__ s2,
    const float* __restrict__ h, const float* __restrict__ zr,
    int t, int cc0, int zEnd, int KP)
{
    constexpr int C = (MODE < 2) ? 65 : (MODE < 4) ? 128 : (MODE < 6) ? 130 : 256;
    __shared__ __bf16 tile[32][66];
    const int b = blockIdx.z, nt = blockIdx.y * 64;
    const int kkb = cc0 + blockIdx.x * 32;
    const int tdx = threadIdx.x;

#pragma unroll
    for (int rep = 0; rep < 8; ++rep) {
        int cc = kkb + (tdx & 31);
        int nl = rep * 8 + (tdx >> 5);
        int n = nt + nl;
        int r = n * 16 + b;
        float v = 0.f;
        if (cc < C) {
            if (MODE == 0 || MODE == 1) {
                if (cc == 0) v = s1[((size_t)b * TT + t) * NNODE + n];
                else { float hv = h[(size_t)r * 64 + cc - 1];
                       v = (MODE == 1) ? zr[(size_t)r * 128 + cc - 1] * hv : hv; }
            } else if (MODE == 2 || MODE == 3) {
                if (cc < 64) v = s1[(size_t)r * 64 + cc];
                else { float hv = h[(size_t)r * 64 + cc - 64];
                       v = (MODE == 3) ? zr[(size_t)r * 128 + cc - 64] * hv : hv; }
            } else if (MODE == 4 || MODE == 5) {
                if (cc == 0) v = s1[r];
                else if (cc == 1) v = s2[((size_t)b * TT + t) * NNODE + n];
                else { float hv = h[(size_t)r * 128 + cc - 2];
                       v = (MODE == 5) ? zr[(size_t)r * 256 + cc - 2] * hv : hv; }
            } else {
                if (cc < 128) v = s1[(size_t)r * 128 + cc];
                else { float hv = h[(size_t)r * 128 + cc - 128];
                       v = (MODE == 7) ? zr[(size_t)r * 256 + cc - 128] * hv : hv; }
            }
        }
        __bf16 hi = (__bf16)v;
        if (cc < zEnd) {
            size_t o = (size_t)r * KP + cc;
            RMh[o] = hi;
            RMl[o] = (__bf16)(v - (float)hi);
        }
        tile[tdx & 31][nl] = hi;
    }
    __syncthreads();
#pragma unroll
    for (int rep = 0; rep < 8; ++rep) {
        int kkl = rep * 4 + (tdx >> 6);
        int kk = kkb + kkl;
        int n = nt + (tdx & 63);
        if (kk < C)
            Th[((size_t)kk * 16 + b) * 1024 + n] = tile[kkl][tdx & 63];
    }
}

// ---------------------------------------------------------------------------
// small kernels
// ---------------------------------------------------------------------------
__global__ __launch_bounds__(256) void compute_ne(
    const float* __restrict__ We1, const float* __restrict__ We2,
    const float* __restrict__ Mem, float* __restrict__ ne1, float* __restrict__ ne2)
{
    int idx = blockIdx.x * 256 + threadIdx.x;
    if (idx >= 2 * 65536) return;
    int which = idx >> 16;
    int i = idx & 65535;
    int n = i >> 6, d = i & 63;
    const float* We = which ? We2 : We1;
    float acc = 0.f;
#pragma unroll
    for (int k = 0; k < 20; ++k) acc += We[n * 20 + k] * Mem[k * 64 + d];
    (which ? ne2 : ne1)[i] = acc;
}

__global__ __launch_bounds__(256) void build_g(
    const float* __restrict__ ne1, const float* __restrict__ ne2, float* __restrict__ g)
{
    int row = blockIdx.x;
    int n = row & 1023;
    const float* qa = (row < 1024) ? ne1 : ne2;
    const float* kb = (row < 1024) ? ne2 : ne1;
    __shared__ float q[64];
    __shared__ float sc[1024];
    __shared__ float red[256];
    int tid = threadIdx.x;
    if (tid < 64) q[tid] = qa[n * 64 + tid];
    __syncthreads();
    for (int m = tid; m < 1024; m += 256) {
        float acc = 0.f;
        const float* kr = kb + m * 64;
#pragma unroll 8
        for (int d = 0; d < 64; ++d) acc += q[d] * kr[d];
        sc[m] = fmaxf(acc, 0.f);
    }
    __syncthreads();
    float mx = -1e30f;
    for (int m = tid; m < 1024; m += 256) mx = fmaxf(mx, sc[m]);
    red[tid] = mx;
    __syncthreads();
    for (int s2 = 128; s2 > 0; s2 >>= 1) {
        if (tid < s2) red[tid] = fmaxf(red[tid], red[tid + s2]);
        __syncthreads();
    }
    mx = red[0];
    __syncthreads();
    float sum = 0.f;
    for (int m = tid; m < 1024; m += 256) {
        float e = expf(sc[m] - mx);
        sc[m] = e;
        sum += e;
    }
    red[tid] = sum;
    __syncthreads();
    for (int s2 = 128; s2 > 0; s2 >>= 1) {
        if (tid < s2) red[tid] += red[tid + s2];
        __syncthreads();
    }
    float inv = 1.f / red[0];
    for (int m = tid; m < 1024; m += 256) g[(size_t)row * 1024 + m] = sc[m] * inv;
}

__global__ __launch_bounds__(256) void g_split(
    const float* __restrict__ g, __bf16* __restrict__ gh, __bf16* __restrict__ gl)
{
    int i = blockIdx.x * 256 + threadIdx.x;
    if (i >= 2048 * 1024) return;
    float v = g[i];
    __bf16 h = (__bf16)v;
    gh[i] = h;
    gl[i] = (__bf16)(v - (float)h);
}

__global__ __launch_bounds__(256) void gT_kern(
    const float* __restrict__ gf, __bf16* __restrict__ gTh, __bf16* __restrict__ gTl)
{
    __shared__ float tile[32][33];
    int z = blockIdx.z;
    int m0 = blockIdx.y * 32, k0 = blockIdx.x * 32;
    int tx = threadIdx.x & 31, ty = threadIdx.x >> 5;
    for (int r = ty; r < 32; r += 8)
        tile[r][tx] = gf[(size_t)(z * 1024 + m0 + r) * 1024 + k0 + tx];
    __syncthreads();
    for (int r = ty; r < 32; r += 8) {
        float v = tile[tx][r];
        __bf16 h = (__bf16)v;
        size_t o = (size_t)(z * 1024 + k0 + r) * 1024 + m0 + tx;
        gTh[o] = h;
        gTl[o] = (__bf16)(v - (float)h);
    }
}

__global__ __launch_bounds__(256) void build_weffT(
    const float* __restrict__ W, __bf16* __restrict__ dh, __bf16* __restrict__ dl,
    int c, int cpad, int cout, int KP)
{
    int idx = blockIdx.x * 256 + threadIdx.x;
    if (idx >= cout * KP) return;
    int o = idx / KP, kk = idx - o * KP;
    float v = 0.f;
    if (kk < 5 * cpad) {
        int s = kk / cpad;
        int i = kk - s * cpad;
        if (i < c) {
            if      (s == 0) v = W[(size_t)(0 * c + i) * cout + o] + W[(size_t)(3 * c + i) * cout + o]
                               - W[(size_t)(2 * c + i) * cout + o] - W[(size_t)(5 * c + i) * cout + o];
            else if (s == 1) v = W[(size_t)(1 * c + i) * cout + o];
            else if (s == 2) v = W[(size_t)(4 * c + i) * cout + o];
            else if (s == 3) v = 2.f * W[(size_t)(2 * c + i) * cout + o];
            else             v = 2.f * W[(size_t)(5 * c + i) * cout + o];
        }
    }
    __bf16 h = (__bf16)v;
    dh[idx] = h;
    dl[idx] = (__bf16)(v - (float)h);
}

__global__ __launch_bounds__(64) void attention(
    const float* __restrict__ h, const float* __restrict__ Wq,
    const float* __restrict__ Mem, float* __restrict__ htc)
{
    int r = blockIdx.x;
    int j = threadIdx.x;
    __shared__ float hr[64], q[64], sc[20];
    hr[j] = h[(size_t)r * 64 + j];
    __syncthreads();
    float acc = 0.f;
#pragma unroll 8
    for (int i = 0; i < 64; ++i) acc += hr[i] * Wq[i * 64 + j];
    q[j] = acc;
    __syncthreads();
    if (j < 20) {
        float a = 0.f;
#pragma unroll 8
        for (int d = 0; d < 64; ++d) a += q[d] * Mem[j * 64 + d];
        sc[j] = a;
    }
    __syncthreads();
    if (j == 0) {
        float mx = sc[0];
        for (int m = 1; m < 20; ++m) mx = fmaxf(mx, sc[m]);
        float s = 0.f;
        for (int m = 0; m < 20; ++m) { sc[m] = expf(sc[m] - mx); s += sc[m]; }
        float inv = 1.f / s;
        for (int m = 0; m < 20; ++m) sc[m] *= inv;
    }
    __syncthreads();
    float v = 0.f;
#pragma unroll
    for (int m = 0; m < 20; ++m) v += sc[m] * Mem[m * 64 + j];
    htc[(size_t)r * 128 + j] = hr[j];
    htc[(size_t)r * 128 + 64 + j] = v;
}

__global__ __launch_bounds__(256) void proj_out(
    const float* __restrict__ h1, const float* __restrict__ pw, const float* __restrict__ pb,
    float* __restrict__ go, float* __restrict__ out, int t)
{
    int r = blockIdx.x * 256 + threadIdx.x;
    if (r >= NB) return;
    float acc = pb[0];
    const float* hr = h1 + (size_t)r * 128;
#pragma unroll 8
    for (int i = 0; i < 128; ++i) acc += hr[i] * pw[i];
    go[r] = acc;
    int n = r >> 4, b = r & 15;
    out[((size_t)b * TT + t) * NNODE + n] = acc;
}

// ---------------------------------------------------------------------------
// host
// ---------------------------------------------------------------------------
extern "C" void kernel_launch(void* const* d_in, const int* in_sizes, int n_in,
                              void* d_out, int out_size, void* d_ws, size_t ws_size,
                              hipStream_t stream)
{
    const float* x      = (const float*)d_in[0];
    const float* y_cov  = (const float*)d_in[1];
    const float* Memory = (const float*)d_in[2];
    const float* Wq     = (const float*)d_in[3];
    const float* We1    = (const float*)d_in[4];
    const float* We2    = (const float*)d_in[5];
    const float* e0gw = (const float*)d_in[6];  const float* e0gb = (const float*)d_in[7];
    const float* e0uw = (const float*)d_in[8];  const float* e0ub = (const float*)d_in[9];
    const float* e1gw = (const float*)d_in[10]; const float* e1gb = (const float*)d_in[11];
    const float* e1uw = (const float*)d_in[12]; const float* e1ub = (const float*)d_in[13];
    const float* d0gw = (const float*)d_in[14]; const float* d0gb = (const float*)d_in[15];
    const float* d0uw = (const float*)d_in[16]; const float* d0ub = (const float*)d_in[17];
    const float* d1gw = (const float*)d_in[18]; const float* d1gb = (const float*)d_in[19];
    const float* d1uw = (const float*)d_in[20]; const float* d1ub = (const float*)d_in[21];
    const float* proj_w = (const float*)d_in[22];
    const float* proj_b = (const float*)d_in[23];
    float* out = (float*)d_out;
    (void)in_sizes; (void)n_in; (void)out_size; (void)ws_size;

    char* wsb = (char*)d_ws;
    size_t off = 0;
    auto alloc = [&](size_t bytes) -> void* {
        void* p = wsb + off;
        off += (bytes + 255) & ~(size_t)255;
        return p;
    };

    float*  gf    = (float*) alloc(2048L * 1024 * 4);
    __bf16* gquad = (__bf16*)alloc(4096L * 1024 * 2);   // g1|g2|G2_1|G2_2 (hi)
    __bf16* gsL   = (__bf16*)alloc(2048L * 1024 * 2);
    __bf16* gTh   = (__bf16*)alloc(2048L * 1024 * 2);
    __bf16* gTl   = (__bf16*)alloc(2048L * 1024 * 2);
    float*  ne1   = (float*) alloc(65536L * 4);
    float*  ne2   = (float*) alloc(65536L * 4);
    auto allocWT = [&](int cout, int KP, __bf16** h, __bf16** l) {
        *h = (__bf16*)alloc((size_t)cout * KP * 2);
        *l = (__bf16*)alloc((size_t)cout * KP * 2);
    };
    __bf16 *wE0gH, *wE0gL, *wE0uH, *wE0uL, *wE1gH, *wE1gL, *wE1uH, *wE1uL;
    __bf16 *wD0gH, *wD0gL, *wD0uH, *wD0uL, *wD1gH, *wD1gL, *wD1uH, *wD1uL;
    allocWT(128, 384,  &wE0gH, &wE0gL);  allocWT(64, 384,  &wE0uH, &wE0uL);
    allocWT(128, 640,  &wE1gH, &wE1gL);  allocWT(64, 640,  &wE1uH, &wE1uL);
    allocWT(256, 704,  &wD0gH, &wD0gL);  allocWT(128, 704, &wD0uH, &wD0uL);
    allocWT(256, 1280, &wD1gH, &wD1gL);  allocWT(128, 1280, &wD1uH, &wD1uL);
    __bf16* RMh = (__bf16*)alloc((size_t)NB * 1280 * 2);
    __bf16* RMl = (__bf16*)alloc((size_t)NB * 1280 * 2);
    __bf16* Th  = (__bf16*)alloc((size_t)4096 * 1024 * 2);
    float* zr  = (float*)alloc((size_t)NB * 256 * 4);
    float* h0e = (float*)alloc((size_t)NB * 64 * 4);
    float* h1e = (float*)alloc((size_t)NB * 64 * 4);
    float* dh0 = (float*)alloc((size_t)NB * 128 * 4);
    float* dh1 = (float*)alloc((size_t)NB * 128 * 4);
    float* gob = (float*)alloc((size_t)NB * 4);

    // ---- setup ----
    compute_ne<<<cdiv(2 * 65536, 256), 256, 0, stream>>>(We1, We2, Memory, ne1, ne2);
    build_g<<<2048, 256, 0, stream>>>(ne1, ne2, gf);
    g_split<<<cdiv(2048 * 1024, 256), 256, 0, stream>>>(gf, gquad, gsL);
    {
        dim3 gt(32, 32, 2);
        gT_kern<<<gt, 256, 0, stream>>>(gf, gTh, gTl);
        dim3 gg(8, 8, 2);
        mm_kern<128, 128, 2, 2, 0><<<gg, 256, 0, stream>>>(
            gquad, gsL, 1024, (long)1024 * 1024,
            gTh, gTl, (long)1024 * 1024, 1024,
            1024, 32, 32, 1 << 30,
            gquad + (size_t)2048 * 1024, nullptr, 1024, (long)1024 * 1024,
            0, 0, nullptr, nullptr, nullptr);
    }
    build_weffT<<<cdiv(128 * 384, 256), 256, 0, stream>>>(e0gw, wE0gH, wE0gL, 65, 72, 128, 384);
    build_weffT<<<cdiv(64 * 384, 256), 256, 0, stream>>>(e0uw, wE0uH, wE0uL, 65, 72, 64, 384);
    build_weffT<<<cdiv(128 * 640, 256), 256, 0, stream>>>(e1gw, wE1gH, wE1gL, 128, 128, 128, 640);
    build_weffT<<<cdiv(64 * 640, 256), 256, 0, stream>>>(e1uw, wE1uH, wE1uL, 128, 128, 64, 640);
    build_weffT<<<cdiv(256 * 704, 256), 256, 0, stream>>>(d0gw, wD0gH, wD0gL, 130, 136, 256, 704);
    build_weffT<<<cdiv(128 * 704, 256), 256, 0, stream>>>(d0uw, wD0uH, wD0uL, 130, 136, 128, 704);
    build_weffT<<<cdiv(256 * 1280, 256), 256, 0, stream>>>(d1gw, wD1gH, wD1gL, 256, 256, 256, 1280);
    build_weffT<<<cdiv(128 * 1280, 256), 256, 0, stream>>>(d1uw, wD1uH, wD1uL, 256, 256, 128, 1280);
    hipMemsetAsync(h0e, 0, (size_t)NB * 64 * 4 * 2, stream);   // h0e + h1e adjacent

    // cell core: hop (EPI2, RM direct) + weight GEMM
    auto agcn_core = [&](int c, int cpad, int cin2, int KP,
                         const __bf16* wth, const __bf16* wtl,
                         const float* bias, int cout, int epi, float* zrOrOut, float* hptr,
                         int K3w) {
        int Moff = 16 * cin2, Mv = 16 * c - Moff;
        dim3 gh(32, cdiv(Mv, 128), 1);
        mm_kern<128, 128, 1, 1, 2><<<gh, 256, 0, stream>>>(
            Th + (size_t)Moff * 1024, Th + (size_t)Moff * 1024, 1024, 0,
            gquad, gquad, 0, 1024,
            Mv, 32, 0, 0,
            RMh, nullptr, KP, 0, cpad, Moff,
            nullptr, nullptr, nullptr);
        if (epi == 1) {
            dim3 gw(2, 128, 1);
            if (cout == 256)
                mm_kern<128, 128, 2, 2, 1><<<gw, 256, 0, stream>>>(
                    RMh, RMl, KP, 0, wth, wtl, 0, KP, NB, KP / 32, K3w, 1 << 30,
                    nullptr, zrOrOut, cout, 0, 0, 0, bias, nullptr, nullptr);
            else
                mm_kern<128, 64, 2, 2, 1><<<gw, 256, 0, stream>>>(
                    RMh, RMl, KP, 0, wth, wtl, 0, KP, NB, KP / 32, K3w, 1 << 30,
                    nullptr, zrOrOut, cout, 0, 0, 0, bias, nullptr, nullptr);
        } else {
            if (cout == 64) {
                dim3 gw(1, 256, 1);
                mm_kern<64, 64, 2, 2, 3><<<gw, 256, 0, stream>>>(
                    RMh, RMl, KP, 0, wth, wtl, 0, KP, NB, KP / 32, K3w, 1 << 30,
                    nullptr, nullptr, cout, 0, 0, 0, bias, zrOrOut, hptr);
            } else {
                dim3 gw(2, 128, 1);
                mm_kern<128, 64, 2, 2, 3><<<gw, 256, 0, stream>>>(
                    RMh, RMl, KP, 0, wth, wtl, 0, KP, NB, KP / 32, K3w, 1 << 30,
                    nullptr, nullptr, cout, 0, 0, 0, bias, zrOrOut, hptr);
            }
        }
    };

    // ---- encoder ----
    for (int t = 0; t < TT; ++t) {
        xcatT_kern<0><<<dim3(3, 16, 16), 256, 0, stream>>>(RMh, RMl, Th, x, nullptr, h0e, nullptr, t, 0, 96, 384);
        agcn_core(65, 72, 0, 384, wE0gH, wE0gL, e0gb, 128, 1, zr, nullptr, 3);
        xcatT_kern<1><<<dim3(2, 16, 16), 256, 0, stream>>>(RMh, RMl, Th, x, nullptr, h0e, zr, t, 1, 65, 384);
        agcn_core(65, 72, 1, 384, wE0uH, wE0uL, e0ub, 64, 3, zr, h0e, 3);
        xcatT_kern<2><<<dim3(4, 16, 16), 256, 0, stream>>>(RMh, RMl, Th, h0e, nullptr, h1e, nullptr, t, 0, 128, 640);
        agcn_core(128, 128, 0, 640, wE1gH, wE1gL, e1gb, 128, 1, zr, nullptr, 4);
        xcatT_kern<3><<<dim3(2, 16, 16), 256, 0, stream>>>(RMh, RMl, Th, h0e, nullptr, h1e, zr, t, 64, 128, 640);
        agcn_core(128, 128, 64, 640, wE1uH, wE1uL, e1ub, 64, 3, zr, h1e, 4);
    }

    // ---- memory attention ----
    attention<<<NB, 64, 0, stream>>>(h1e, Wq, Memory, dh0);
    hipMemcpyAsync(dh1, dh0, (size_t)NB * 128 * 4, hipMemcpyDeviceToDevice, stream);
    hipMemsetAsync(gob, 0, (size_t)NB * 4, stream);

    // ---- decoder ----
    for (int t = 0; t < TT; ++t) {
        xcatT_kern<4><<<dim3(5, 16, 16), 256, 0, stream>>>(RMh, RMl, Th, gob, y_cov, dh0, nullptr, t, 0, 160, 704);
        agcn_core(130, 136, 0, 704, wD0gH, wD0gL, d0gb, 256, 1, zr, nullptr, 5);
        xcatT_kern<5><<<dim3(4, 16, 16), 256, 0, stream>>>(RMh, RMl, Th, gob, y_cov, dh0, zr, t, 2, 130, 704);
        agcn_core(130, 136, 2, 704, wD0uH, wD0uL, d0ub, 128, 3, zr, dh0, 5);
        xcatT_kern<6><<<dim3(8, 16, 16), 256, 0, stream>>>(RMh, RMl, Th, dh0, nullptr, dh1, nullptr, t, 0, 256, 1280);
        agcn_core(256, 256, 0, 1280, wD1gH, wD1gL, d1gb, 256, 1, zr, nullptr, 8);
        xcatT_kern<7><<<dim3(4, 16, 16), 256, 0, stream>>>(RMh, RMl, Th, dh0, nullptr, dh1, zr, t, 128, 256, 1280);
        agcn_core(256, 256, 128, 1280, wD1uH, wD1uL, d1ub, 128, 3, zr, dh1, 8);
        proj_out<<<cdiv(NB, 256), 256, 0, stream>>>(dh1, proj_w, proj_b, gob, out, t);
    }
}

// Round 9
// 6498.399 us; speedup vs baseline: 7.5407x; 1.1059x over previous
//
#include <hip/hip_runtime.h>
#include <math.h>

#define NNODE 1024
#define BATCH 16
#define NB    16384
#define TT    12

typedef __bf16 bf16x8 __attribute__((ext_vector_type(8)));
typedef float  f32x4  __attribute__((ext_vector_type(4)));

static inline int cdiv(int a, int b) { return (a + b - 1) / b; }

// proper s_waitcnt immediate: vmcnt N (6-bit split [3:0],[15:14]), lgkm=15, exp=7
__host__ __device__ constexpr int vmenc(int n) {
    return 0x0F70 | (n & 0xF) | ((n >> 4) << 14);
}

// async global->LDS, 16B per lane, wave-uniform LDS base + lane*16
__device__ inline void gll16(const void* g, void* l) {
    __builtin_amdgcn_global_load_lds(
        (const __attribute__((address_space(1))) void*)g,
        (__attribute__((address_space(3))) void*)l, 16, 0, 0);
}

// ---------------------------------------------------------------------------
// Split-bf16 GEMM, counted-vmcnt double-buffered pipeline, BK=64 K-steps,
// coalesced staging (8 rows x 128B per 1KB chunk), XCD-chunked block swizzle.
// D[i][j] = sum_k A[i][k]*B[j][k]  (both k-contig).
// PA/PB: plane counts (1 = hi only). Passes: Ah*Bh always; Ah*Bl if PB==2;
//        Al*Bh if PA==2 && kt<K3 && bn<aloCols.
// LDS swizzle: 16B slot s at row r stored at slot s^(r&(BK/8-1)); applied on
// the global source address (write) and the ds_read address (read).
// EPI 0: plain bf16 store Ch
// EPI 1: +bias, sigmoid -> Cf
// EPI 2: RM-transposed hop store: RM[(n*16+b)*ldc + (1+bn/1024)*cpad + i] (hi)
// EPI 3: +bias, tanh, fused GRU: hout = r*hout + (1-r)*hc  (r from zrp)
// ---------------------------------------------------------------------------
template<int BM, int BN, int BK, int PA, int PB, int EPI>
__global__ __launch_bounds__(256) void mm_kern(
    const __bf16* __restrict__ Ah, const __bf16* __restrict__ Al, long lda, long zA,
    const __bf16* __restrict__ Bh, const __bf16* __restrict__ Bl, long zB, long ldb,
    int M, int Ksteps, int K3, int aloCols,
    __bf16* __restrict__ Ch, float* __restrict__ Cf,
    long ldc, long zC, int cpadParam, long MoffParam,
    const float* __restrict__ bias, const float* __restrict__ zrp,
    float* __restrict__ hout)
{
    constexpr int WM = BM / 2, WN = BN / 2;
    constexpr int MF = WM / 16, NF = WN / 16;
    constexpr int NSLOT = BK / 8;                   // 16B slots per row
    constexpr int RPC = 512 / BK;                   // rows per 1KB chunk
    constexpr int nA = BM / RPC, nB = BN / RPC;     // chunks per plane
    constexpr int nAl = (PA == 2) ? nA : 0;
    constexpr int nBl = (PB == 2) ? nB : 0;
    constexpr int TOT = nA + nAl + nB + nBl;
    constexpr int NPS = TOT / 4;                    // chunks per wave
    constexpr int cAlw = nAl / 4;
    constexpr int NPfull = NPS, NPnoAl = NPS - cAlw;
    constexpr int e0 = nA, e1 = nA + nAl, e2 = nA + nAl + nB;
    constexpr int bAl = BM * BK;
    constexpr int bBh = (PA == 2 ? 2 : 1) * BM * BK;
    constexpr int bBl = bBh + BN * BK;
    constexpr int BUFE = ((PA == 2 ? 2 : 1) * BM + (PB == 2 ? 2 : 1) * BN) * BK;
    __shared__ __bf16 smem[2 * BUFE];

    // ---- block swizzle: bijective XCD chunking + 2-col band ----
    const int nwgx = gridDim.x, nwgy = gridDim.y;
    const int nwg = nwgx * nwgy;
    const int lin = blockIdx.y * nwgx + blockIdx.x;
    const int q8 = nwg >> 3, r8 = nwg & 7;
    const int xcd = lin & 7, cidx = lin >> 3;
    const int lin2 = (xcd < r8) ? (xcd * (q8 + 1) + cidx)
                                : (r8 * (q8 + 1) + (xcd - r8) * q8 + cidx);
    const int G = ((nwgx & 1) == 0) ? 2 : 1;
    const int band = G * nwgy;
    const int gb = lin2 / band, rm = lin2 - gb * band;
    const int bxs = gb * G + (rm & (G - 1));
    const int bys = rm / G;

    const int bm = bys * BM, bn = bxs * BN;
    const int tid = threadIdx.x, w = tid >> 6, lane = tid & 63;
    const int wr = w >> 1, wc = w & 1;
    const int lgrp = lane >> 4, lrow = lane & 15;
    const bool aloNeed = (PA == 2) && (bn < aloCols);

    Ah += (size_t)blockIdx.z * zA;  Al += (size_t)blockIdx.z * zA;
    Bh += (size_t)blockIdx.z * zB;  Bl += (size_t)blockIdx.z * zB;

    // staging: lane -> row-in-chunk = lane/NSLOT, slot = (lane%NSLOT)^(row%NSLOT)
    const int srow = lane / NSLOT;
    const int kgel = ((lane & (NSLOT - 1)) ^ (srow & (NSLOT - 1))) * 8;
    const __bf16* sp[NPS];
    int dpo[NPS];
    int ttyp[NPS];
#pragma unroll
    for (int p = 0; p < NPS; ++p) {
        int q = p * 4 + w;
        int tile = (q < e0) ? 0 : (q < e1) ? 1 : (q < e2) ? 2 : 3;
        int qq = q - ((tile == 0) ? 0 : (tile == 1) ? e0 : (tile == 2) ? e1 : e2);
        const __bf16* base = (tile == 0) ? Ah : (tile == 1) ? Al : (tile == 2) ? Bh : Bl;
        long ld = (tile < 2) ? lda : ldb;
        int  rb = (tile < 2) ? bm : bn;
        sp[p] = base + (size_t)(rb + qq * RPC + srow) * ld + kgel;
        int tbase = (tile == 0) ? 0 : (tile == 1) ? bAl : (tile == 2) ? bBh : bBl;
        dpo[p] = tbase * 2 + qq * 1024;
        ttyp[p] = tile;
    }

    f32x4 acc[MF][NF];
#pragma unroll
    for (int i = 0; i < MF; ++i)
#pragma unroll
        for (int j = 0; j < NF; ++j)
#pragma unroll
            for (int e = 0; e < 4; ++e) acc[i][j][e] = 0.f;

    auto stage = [&](int kt, int bsel) {
        char* lb = (char*)smem + bsel * (BUFE * 2);
#pragma unroll
        for (int p = 0; p < NPS; ++p) {
            int tile = ttyp[p];
            bool go = (tile == 0) || (tile == 2)
                   || (tile == 1 && aloNeed && kt < K3)
                   || (tile == 3 && PB == 2);
            if (go) gll16(sp[p] + (size_t)kt * BK, lb + dpo[p]);
        }
    };

    stage(0, 0);

    const int rsw = (lrow & (NSLOT - 1));   // read-side row-swizzle term

    for (int kt = 0; kt < Ksteps; ++kt) {
        const int cur = kt & 1;
        __builtin_amdgcn_s_barrier();
        __builtin_amdgcn_sched_barrier(0);
        if (kt + 1 < Ksteps) {
            stage(kt + 1, cur ^ 1);
            if (aloNeed && (kt + 1) < K3)
                __builtin_amdgcn_s_waitcnt(vmenc(NPfull));
            else
                __builtin_amdgcn_s_waitcnt(vmenc(NPnoAl));
        } else {
            __builtin_amdgcn_s_waitcnt(vmenc(0));
        }
        __builtin_amdgcn_s_barrier();
        __builtin_amdgcn_sched_barrier(0);

        const __bf16* sb = smem + cur * BUFE;
#pragma unroll
        for (int kh = 0; kh < BK / 32; ++kh) {
            const int so = ((kh * 4 + lgrp) ^ rsw) * 8;
            bf16x8 aH[MF], bHf[NF];
#pragma unroll
            for (int mf = 0; mf < MF; ++mf) {
                int row = wr * WM + mf * 16 + lrow;
                aH[mf] = *(const bf16x8*)(sb + (size_t)row * BK + so);
            }
#pragma unroll
            for (int nf = 0; nf < NF; ++nf) {
                int col = wc * WN + nf * 16 + lrow;
                bHf[nf] = *(const bf16x8*)(sb + bBh + (size_t)col * BK + so);
            }
            __builtin_amdgcn_s_setprio(1);
#pragma unroll
            for (int mf = 0; mf < MF; ++mf)
#pragma unroll
                for (int nf = 0; nf < NF; ++nf)
                    acc[mf][nf] = __builtin_amdgcn_mfma_f32_16x16x32_bf16(aH[mf], bHf[nf], acc[mf][nf], 0, 0, 0);

            if (PB == 2) {
                bf16x8 bLf[NF];
#pragma unroll
                for (int nf = 0; nf < NF; ++nf) {
                    int col = wc * WN + nf * 16 + lrow;
                    bLf[nf] = *(const bf16x8*)(sb + bBl + (size_t)col * BK + so);
                }
#pragma unroll
                for (int mf = 0; mf < MF; ++mf)
#pragma unroll
                    for (int nf = 0; nf < NF; ++nf)
                        acc[mf][nf] = __builtin_amdgcn_mfma_f32_16x16x32_bf16(aH[mf], bLf[nf], acc[mf][nf], 0, 0, 0);
            }
            if (PA == 2 && aloNeed && kt < K3) {
                bf16x8 aL[MF];
#pragma unroll
                for (int mf = 0; mf < MF; ++mf) {
                    int row = wr * WM + mf * 16 + lrow;
                    aL[mf] = *(const bf16x8*)(sb + bAl + (size_t)row * BK + so);
                }
#pragma unroll
                for (int mf = 0; mf < MF; ++mf)
#pragma unroll
                    for (int nf = 0; nf < NF; ++nf)
                        acc[mf][nf] = __builtin_amdgcn_mfma_f32_16x16x32_bf16(aL[mf], bHf[nf], acc[mf][nf], 0, 0, 0);
            }
            __builtin_amdgcn_s_setprio(0);
        }
    }

    if (EPI == 2) {
        // ---- LDS-transposed RM store (hi only) ----
        constexpr int NI = BM / 16;
        __syncthreads();
        __bf16* LT = smem;                  // BM*BN elems <= 2*BUFE
#pragma unroll
        for (int mf = 0; mf < MF; ++mf) {
            int il = wr * MF + mf;
#pragma unroll
            for (int nf = 0; nf < NF; ++nf) {
                int nl = wc * WN + nf * 16 + lrow;
#pragma unroll
                for (int r = 0; r < 4; ++r) {
                    int b = lgrp * 4 + r;
                    LT[nl * BM + ((b ^ (nl & 15)) * NI) + il] = (__bf16)acc[mf][nf][r];
                }
            }
        }
        __syncthreads();
        const int ibase = (int)((MoffParam + bm) >> 4);
        const long scol = (long)(1 + (bn >> 10)) * cpadParam + ibase;
        const bool fullM = (bm + BM <= M);
        const bool al16 = ((scol & 7) == 0) && (NI == 8);
#pragma unroll
        for (int q = 0; q < (BN * 16) / 256; ++q) {
            int rr = q * 256 + tid;
            int nl = rr >> 4, b = rr & 15;
            int el = nl * BM + ((b ^ (nl & 15)) * NI);
            int n = (bn & 1023) + nl;
            size_t addr = ((size_t)n * 16 + b) * ldc + scol;
            if (fullM && al16) {
                *(uint4*)(Ch + addr) = *(const uint4*)(LT + el);
            } else {
#pragma unroll
                for (int il = 0; il < NI; ++il)
                    if (bm + il * 16 + b < M) Ch[addr + il] = LT[el + il];
            }
        }
        return;
    }

    const size_t cz = (size_t)blockIdx.z * zC;
#pragma unroll
    for (int mf = 0; mf < MF; ++mf) {
        int gi0 = bm + wr * WM + mf * 16 + lgrp * 4;
#pragma unroll
        for (int nf = 0; nf < NF; ++nf) {
            int gj = bn + wc * WN + nf * 16 + lrow;
#pragma unroll
            for (int r = 0; r < 4; ++r) {
                int gi = gi0 + r;
                if (gi < M) {
                    float v = acc[mf][nf][r];
                    if (EPI == 0) {
                        Ch[cz + (size_t)gi * ldc + gj] = (__bf16)v;
                    } else if (EPI == 1) {
                        v += bias[gj];
                        v = 1.f / (1.f + expf(-v));
                        Cf[cz + (size_t)gi * ldc + gj] = v;
                    } else if (EPI == 3) {
                        v += bias[gj];
                        v = tanhf(v);
                        float rg = zrp[(size_t)gi * 2 * ldc + ldc + gj];
                        size_t hix = (size_t)gi * ldc + gj;
                        hout[hix] = rg * hout[hix] + (1.f - rg) * v;
                    }
                }
            }
        }
    }
}

// ---------------------------------------------------------------------------
// Fused concat-build + transpose: computes v(cc,n,b), writes RM hi/lo
// (coalesced, cc-contig) for cc in [cc0, zEnd) and T hi plane
// (coalesced, n-contig, via LDS) for cc in [cc0, C).
// Gate cells (cc0==0) also zero RM straddle [C, zEnd) (both planes).
// ---------------------------------------------------------------------------
template<int MODE>
__global__ __launch_bounds__(256) void xcatT_kern(
    __bf16* __restrict__ RMh, __bf16* __restrict__ RMl, __bf16* __restrict__ Th,
    const float* __restrict__ s1, const float* __restrict__ s2,
    const float* __restrict__ h, const float* __restrict__ zr,
    int t, int cc0, int zEnd, int KP)
{
    constexpr int C = (MODE < 2) ? 65 : (MODE < 4) ? 128 : (MODE < 6) ? 130 : 256;
    __shared__ __bf16 tile[32][66];
    const int b = blockIdx.z, nt = blockIdx.y * 64;
    const int kkb = cc0 + blockIdx.x * 32;
    const int tdx = threadIdx.x;

#pragma unroll
    for (int rep = 0; rep < 8; ++rep) {
        int cc = kkb + (tdx & 31);
        int nl = rep * 8 + (tdx >> 5);
        int n = nt + nl;
        int r = n * 16 + b;
        float v = 0.f;
        if (cc < C) {
            if (MODE == 0 || MODE == 1) {
                if (cc == 0) v = s1[((size_t)b * TT + t) * NNODE + n];
                else { float hv = h[(size_t)r * 64 + cc - 1];
                       v = (MODE == 1) ? zr[(size_t)r * 128 + cc - 1] * hv : hv; }
            } else if (MODE == 2 || MODE == 3) {
                if (cc < 64) v = s1[(size_t)r * 64 + cc];
                else { float hv = h[(size_t)r * 64 + cc - 64];
                       v = (MODE == 3) ? zr[(size_t)r * 128 + cc - 64] * hv : hv; }
            } else if (MODE == 4 || MODE == 5) {
                if (cc == 0) v = s1[r];
                else if (cc == 1) v = s2[((size_t)b * TT + t) * NNODE + n];
                else { float hv = h[(size_t)r * 128 + cc - 2];
                       v = (MODE == 5) ? zr[(size_t)r * 256 + cc - 2] * hv : hv; }
            } else {
                if (cc < 128) v = s1[(size_t)r * 128 + cc];
                else { float hv = h[(size_t)r * 128 + cc - 128];
                       v = (MODE == 7) ? zr[(size_t)r * 256 + cc - 128] * hv : hv; }
            }
        }
        __bf16 hi = (__bf16)v;
        if (cc < zEnd) {
            size_t o = (size_t)r * KP + cc;
            RMh[o] = hi;
            RMl[o] = (__bf16)(v - (float)hi);
        }
        tile[tdx & 31][nl] = hi;
    }
    __syncthreads();
#pragma unroll
    for (int rep = 0; rep < 8; ++rep) {
        int kkl = rep * 4 + (tdx >> 6);
        int kk = kkb + kkl;
        int n = nt + (tdx & 63);
        if (kk < C)
            Th[((size_t)kk * 16 + b) * 1024 + n] = tile[kkl][tdx & 63];
    }
}

// ---------------------------------------------------------------------------
// small kernels
// ---------------------------------------------------------------------------
__global__ __launch_bounds__(256) void compute_ne(
    const float* __restrict__ We1, const float* __restrict__ We2,
    const float* __restrict__ Mem, float* __restrict__ ne1, float* __restrict__ ne2)
{
    int idx = blockIdx.x * 256 + threadIdx.x;
    if (idx >= 2 * 65536) return;
    int which = idx >> 16;
    int i = idx & 65535;
    int n = i >> 6, d = i & 63;
    const float* We = which ? We2 : We1;
    float acc = 0.f;
#pragma unroll
    for (int k = 0; k < 20; ++k) acc += We[n * 20 + k] * Mem[k * 64 + d];
    (which ? ne2 : ne1)[i] = acc;
}

__global__ __launch_bounds__(256) void build_g(
    const float* __restrict__ ne1, const float* __restrict__ ne2, float* __restrict__ g)
{
    int row = blockIdx.x;
    int n = row & 1023;
    const float* qa = (row < 1024) ? ne1 : ne2;
    const float* kb = (row < 1024) ? ne2 : ne1;
    __shared__ float q[64];
    __shared__ float sc[1024];
    __shared__ float red[256];
    int tid = threadIdx.x;
    if (tid < 64) q[tid] = qa[n * 64 + tid];
    __syncthreads();
    for (int m = tid; m < 1024; m += 256) {
        float acc = 0.f;
        const float* kr = kb + m * 64;
#pragma unroll 8
        for (int d = 0; d < 64; ++d) acc += q[d] * kr[d];
        sc[m] = fmaxf(acc, 0.f);
    }
    __syncthreads();
    float mx = -1e30f;
    for (int m = tid; m < 1024; m += 256) mx = fmaxf(mx, sc[m]);
    red[tid] = mx;
    __syncthreads();
    for (int s2 = 128; s2 > 0; s2 >>= 1) {
        if (tid < s2) red[tid] = fmaxf(red[tid], red[tid + s2]);
        __syncthreads();
    }
    mx = red[0];
    __syncthreads();
    float sum = 0.f;
    for (int m = tid; m < 1024; m += 256) {
        float e = expf(sc[m] - mx);
        sc[m] = e;
        sum += e;
    }
    red[tid] = sum;
    __syncthreads();
    for (int s2 = 128; s2 > 0; s2 >>= 1) {
        if (tid < s2) red[tid] += red[tid + s2];
        __syncthreads();
    }
    float inv = 1.f / red[0];
    for (int m = tid; m < 1024; m += 256) g[(size_t)row * 1024 + m] = sc[m] * inv;
}

__global__ __launch_bounds__(256) void g_split(
    const float* __restrict__ g, __bf16* __restrict__ gh, __bf16* __restrict__ gl)
{
    int i = blockIdx.x * 256 + threadIdx.x;
    if (i >= 2048 * 1024) return;
    float v = g[i];
    __bf16 h = (__bf16)v;
    gh[i] = h;
    gl[i] = (__bf16)(v - (float)h);
}

__global__ __launch_bounds__(256) void gT_kern(
    const float* __restrict__ gf, __bf16* __restrict__ gTh, __bf16* __restrict__ gTl)
{
    __shared__ float tile[32][33];
    int z = blockIdx.z;
    int m0 = blockIdx.y * 32, k0 = blockIdx.x * 32;
    int tx = threadIdx.x & 31, ty = threadIdx.x >> 5;
    for (int r = ty; r < 32; r += 8)
        tile[r][tx] = gf[(size_t)(z * 1024 + m0 + r) * 1024 + k0 + tx];
    __syncthreads();
    for (int r = ty; r < 32; r += 8) {
        float v = tile[tx][r];
        __bf16 h = (__bf16)v;
        size_t o = (size_t)(z * 1024 + k0 + r) * 1024 + m0 + tx;
        gTh[o] = h;
        gTl[o] = (__bf16)(v - (float)h);
    }
}

__global__ __launch_bounds__(256) void build_weffT(
    const float* __restrict__ W, __bf16* __restrict__ dh, __bf16* __restrict__ dl,
    int c, int cpad, int cout, int KP)
{
    int idx = blockIdx.x * 256 + threadIdx.x;
    if (idx >= cout * KP) return;
    int o = idx / KP, kk = idx - o * KP;
    float v = 0.f;
    if (kk < 5 * cpad) {
        int s = kk / cpad;
        int i = kk - s * cpad;
        if (i < c) {
            if      (s == 0) v = W[(size_t)(0 * c + i) * cout + o] + W[(size_t)(3 * c + i) * cout + o]
                               - W[(size_t)(2 * c + i) * cout + o] - W[(size_t)(5 * c + i) * cout + o];
            else if (s == 1) v = W[(size_t)(1 * c + i) * cout + o];
            else if (s == 2) v = W[(size_t)(4 * c + i) * cout + o];
            else if (s == 3) v = 2.f * W[(size_t)(2 * c + i) * cout + o];
            else             v = 2.f * W[(size_t)(5 * c + i) * cout + o];
        }
    }
    __bf16 h = (__bf16)v;
    dh[idx] = h;
    dl[idx] = (__bf16)(v - (float)h);
}

__global__ __launch_bounds__(64) void attention(
    const float* __restrict__ h, const float* __restrict__ Wq,
    const float* __restrict__ Mem, float* __restrict__ htc)
{
    int r = blockIdx.x;
    int j = threadIdx.x;
    __shared__ float hr[64], q[64], sc[20];
    hr[j] = h[(size_t)r * 64 + j];
    __syncthreads();
    float acc = 0.f;
#pragma unroll 8
    for (int i = 0; i < 64; ++i) acc += hr[i] * Wq[i * 64 + j];
    q[j] = acc;
    __syncthreads();
    if (j < 20) {
        float a = 0.f;
#pragma unroll 8
        for (int d = 0; d < 64; ++d) a += q[d] * Mem[j * 64 + d];
        sc[j] = a;
    }
    __syncthreads();
    if (j == 0) {
        float mx = sc[0];
        for (int m = 1; m < 20; ++m) mx = fmaxf(mx, sc[m]);
        float s = 0.f;
        for (int m = 0; m < 20; ++m) { sc[m] = expf(sc[m] - mx); s += sc[m]; }
        float inv = 1.f / s;
        for (int m = 0; m < 20; ++m) sc[m] *= inv;
    }
    __syncthreads();
    float v = 0.f;
#pragma unroll
    for (int m = 0; m < 20; ++m) v += sc[m] * Mem[m * 64 + j];
    htc[(size_t)r * 128 + j] = hr[j];
    htc[(size_t)r * 128 + 64 + j] = v;
}

__global__ __launch_bounds__(256) void proj_out(
    const float* __restrict__ h1, const float* __restrict__ pw, const float* __restrict__ pb,
    float* __restrict__ go, float* __restrict__ out, int t)
{
    int r = blockIdx.x * 256 + threadIdx.x;
    if (r >= NB) return;
    float acc = pb[0];
    const float* hr = h1 + (size_t)r * 128;
#pragma unroll 8
    for (int i = 0; i < 128; ++i) acc += hr[i] * pw[i];
    go[r] = acc;
    int n = r >> 4, b = r & 15;
    out[((size_t)b * TT + t) * NNODE + n] = acc;
}

// ---------------------------------------------------------------------------
// host
// ---------------------------------------------------------------------------
extern "C" void kernel_launch(void* const* d_in, const int* in_sizes, int n_in,
                              void* d_out, int out_size, void* d_ws, size_t ws_size,
                              hipStream_t stream)
{
    const float* x      = (const float*)d_in[0];
    const float* y_cov  = (const float*)d_in[1];
    const float* Memory = (const float*)d_in[2];
    const float* Wq     = (const float*)d_in[3];
    const float* We1    = (const float*)d_in[4];
    const float* We2    = (const float*)d_in[5];
    const float* e0gw = (const float*)d_in[6];  const float* e0gb = (const float*)d_in[7];
    const float* e0uw = (const float*)d_in[8];  const float* e0ub = (const float*)d_in[9];
    const float* e1gw = (const float*)d_in[10]; const float* e1gb = (const float*)d_in[11];
    const float* e1uw = (const float*)d_in[12]; const float* e1ub = (const float*)d_in[13];
    const float* d0gw = (const float*)d_in[14]; const float* d0gb = (const float*)d_in[15];
    const float* d0uw = (const float*)d_in[16]; const float* d0ub = (const float*)d_in[17];
    const float* d1gw = (const float*)d_in[18]; const float* d1gb = (const float*)d_in[19];
    const float* d1uw = (const float*)d_in[20]; const float* d1ub = (const float*)d_in[21];
    const float* proj_w = (const float*)d_in[22];
    const float* proj_b = (const float*)d_in[23];
    float* out = (float*)d_out;
    (void)in_sizes; (void)n_in; (void)out_size; (void)ws_size;

    char* wsb = (char*)d_ws;
    size_t off = 0;
    auto alloc = [&](size_t bytes) -> void* {
        void* p = wsb + off;
        off += (bytes + 255) & ~(size_t)255;
        return p;
    };

    float*  gf    = (float*) alloc(2048L * 1024 * 4);
    __bf16* gquad = (__bf16*)alloc(4096L * 1024 * 2);   // g1|g2|G2_1|G2_2 (hi)
    __bf16* gsL   = (__bf16*)alloc(2048L * 1024 * 2);
    __bf16* gTh   = (__bf16*)alloc(2048L * 1024 * 2);
    __bf16* gTl   = (__bf16*)alloc(2048L * 1024 * 2);
    float*  ne1   = (float*) alloc(65536L * 4);
    float*  ne2   = (float*) alloc(65536L * 4);
    auto allocWT = [&](int cout, int KP, __bf16** h, __bf16** l) {
        *h = (__bf16*)alloc((size_t)cout * KP * 2);
        *l = (__bf16*)alloc((size_t)cout * KP * 2);
    };
    __bf16 *wE0gH, *wE0gL, *wE0uH, *wE0uL, *wE1gH, *wE1gL, *wE1uH, *wE1uL;
    __bf16 *wD0gH, *wD0gL, *wD0uH, *wD0uL, *wD1gH, *wD1gL, *wD1uH, *wD1uL;
    allocWT(128, 384,  &wE0gH, &wE0gL);  allocWT(64, 384,  &wE0uH, &wE0uL);
    allocWT(128, 640,  &wE1gH, &wE1gL);  allocWT(64, 640,  &wE1uH, &wE1uL);
    allocWT(256, 704,  &wD0gH, &wD0gL);  allocWT(128, 704, &wD0uH, &wD0uL);
    allocWT(256, 1280, &wD1gH, &wD1gL);  allocWT(128, 1280, &wD1uH, &wD1uL);
    __bf16* RMh = (__bf16*)alloc((size_t)NB * 1280 * 2);
    __bf16* RMl = (__bf16*)alloc((size_t)NB * 1280 * 2);
    __bf16* Th  = (__bf16*)alloc((size_t)4096 * 1024 * 2);
    float* zr  = (float*)alloc((size_t)NB * 256 * 4);
    float* h0e = (float*)alloc((size_t)NB * 64 * 4);
    float* h1e = (float*)alloc((size_t)NB * 64 * 4);
    float* dh0 = (float*)alloc((size_t)NB * 128 * 4);
    float* dh1 = (float*)alloc((size_t)NB * 128 * 4);
    float* gob = (float*)alloc((size_t)NB * 4);

    // ---- setup ----
    compute_ne<<<cdiv(2 * 65536, 256), 256, 0, stream>>>(We1, We2, Memory, ne1, ne2);
    build_g<<<2048, 256, 0, stream>>>(ne1, ne2, gf);
    g_split<<<cdiv(2048 * 1024, 256), 256, 0, stream>>>(gf, gquad, gsL);
    {
        dim3 gt(32, 32, 2);
        gT_kern<<<gt, 256, 0, stream>>>(gf, gTh, gTl);
        // G2_z = g_z @ g_z  (3-pass split), -> gquad rows 2048 + z*1024
        dim3 gg(8, 8, 2);
        mm_kern<128, 128, 64, 2, 2, 0><<<gg, 256, 0, stream>>>(
            gquad, gsL, 1024, (long)1024 * 1024,
            gTh, gTl, (long)1024 * 1024, 1024,
            1024, 16, 16, 1 << 30,
            gquad + (size_t)2048 * 1024, nullptr, 1024, (long)1024 * 1024,
            0, 0, nullptr, nullptr, nullptr);
    }
    build_weffT<<<cdiv(128 * 384, 256), 256, 0, stream>>>(e0gw, wE0gH, wE0gL, 65, 72, 128, 384);
    build_weffT<<<cdiv(64 * 384, 256), 256, 0, stream>>>(e0uw, wE0uH, wE0uL, 65, 72, 64, 384);
    build_weffT<<<cdiv(128 * 640, 256), 256, 0, stream>>>(e1gw, wE1gH, wE1gL, 128, 128, 128, 640);
    build_weffT<<<cdiv(64 * 640, 256), 256, 0, stream>>>(e1uw, wE1uH, wE1uL, 128, 128, 64, 640);
    build_weffT<<<cdiv(256 * 704, 256), 256, 0, stream>>>(d0gw, wD0gH, wD0gL, 130, 136, 256, 704);
    build_weffT<<<cdiv(128 * 704, 256), 256, 0, stream>>>(d0uw, wD0uH, wD0uL, 130, 136, 128, 704);
    build_weffT<<<cdiv(256 * 1280, 256), 256, 0, stream>>>(d1gw, wD1gH, wD1gL, 256, 256, 256, 1280);
    build_weffT<<<cdiv(128 * 1280, 256), 256, 0, stream>>>(d1uw, wD1uH, wD1uL, 256, 256, 128, 1280);
    hipMemsetAsync(h0e, 0, (size_t)NB * 64 * 4 * 2, stream);   // h0e + h1e adjacent

    // cell core: hop (EPI2, RM direct) + weight GEMM. K3w in 64-col units.
    auto agcn_core = [&](int c, int cpad, int cin2, int KP,
                         const __bf16* wth, const __bf16* wtl,
                         const float* bias, int cout, int epi, float* zrOrOut, float* hptr,
                         int K3w) {
        int Moff = 16 * cin2, Mv = 16 * c - Moff;
        dim3 gh(32, cdiv(Mv, 128), 1);
        mm_kern<128, 128, 64, 1, 1, 2><<<gh, 256, 0, stream>>>(
            Th + (size_t)Moff * 1024, Th + (size_t)Moff * 1024, 1024, 0,
            gquad, gquad, 0, 1024,
            Mv, 16, 0, 0,
            RMh, nullptr, KP, 0, cpad, Moff,
            nullptr, nullptr, nullptr);
        if (epi == 1) {
            dim3 gw(2, 128, 1);
            if (cout == 256)
                mm_kern<128, 128, 64, 2, 2, 1><<<gw, 256, 0, stream>>>(
                    RMh, RMl, KP, 0, wth, wtl, 0, KP, NB, KP / 64, K3w, 1 << 30,
                    nullptr, zrOrOut, cout, 0, 0, 0, bias, nullptr, nullptr);
            else
                mm_kern<128, 64, 64, 2, 2, 1><<<gw, 256, 0, stream>>>(
                    RMh, RMl, KP, 0, wth, wtl, 0, KP, NB, KP / 64, K3w, 1 << 30,
                    nullptr, zrOrOut, cout, 0, 0, 0, bias, nullptr, nullptr);
        } else {
            if (cout == 64) {
                dim3 gw(1, 256, 1);
                mm_kern<64, 64, 64, 2, 2, 3><<<gw, 256, 0, stream>>>(
                    RMh, RMl, KP, 0, wth, wtl, 0, KP, NB, KP / 64, K3w, 1 << 30,
                    nullptr, nullptr, cout, 0, 0, 0, bias, zrOrOut, hptr);
            } else {
                dim3 gw(2, 128, 1);
                mm_kern<128, 64, 64, 2, 2, 3><<<gw, 256, 0, stream>>>(
                    RMh, RMl, KP, 0, wth, wtl, 0, KP, NB, KP / 64, K3w, 1 << 30,
                    nullptr, nullptr, cout, 0, 0, 0, bias, zrOrOut, hptr);
            }
        }
    };

    // ---- encoder ----
    for (int t = 0; t < TT; ++t) {
        // enc0: c=65, cpad=72, K3=2 -> gate zEnd = 128
        xcatT_kern<0><<<dim3(4, 16, 16), 256, 0, stream>>>(RMh, RMl, Th, x, nullptr, h0e, nullptr, t, 0, 128, 384);
        agcn_core(65, 72, 0, 384, wE0gH, wE0gL, e0gb, 128, 1, zr, nullptr, 2);
        xcatT_kern<1><<<dim3(2, 16, 16), 256, 0, stream>>>(RMh, RMl, Th, x, nullptr, h0e, zr, t, 1, 65, 384);
        agcn_core(65, 72, 1, 384, wE0uH, wE0uL, e0ub, 64, 3, zr, h0e, 2);
        // enc1: c=128, cpad=128, K3=2 -> zEnd = 128 = C
        xcatT_kern<2><<<dim3(4, 16, 16), 256, 0, stream>>>(RMh, RMl, Th, h0e, nullptr, h1e, nullptr, t, 0, 128, 640);
        agcn_core(128, 128, 0, 640, wE1gH, wE1gL, e1gb, 128, 1, zr, nullptr, 2);
        xcatT_kern<3><<<dim3(2, 16, 16), 256, 0, stream>>>(RMh, RMl, Th, h0e, nullptr, h1e, zr, t, 64, 128, 640);
        agcn_core(128, 128, 64, 640, wE1uH, wE1uL, e1ub, 64, 3, zr, h1e, 2);
    }

    // ---- memory attention ----
    attention<<<NB, 64, 0, stream>>>(h1e, Wq, Memory, dh0);
    hipMemcpyAsync(dh1, dh0, (size_t)NB * 128 * 4, hipMemcpyDeviceToDevice, stream);
    hipMemsetAsync(gob, 0, (size_t)NB * 4, stream);

    // ---- decoder ----
    for (int t = 0; t < TT; ++t) {
        // dec0: c=130, cpad=136, K3=3 -> gate zEnd = 192
        xcatT_kern<4><<<dim3(6, 16, 16), 256, 0, stream>>>(RMh, RMl, Th, gob, y_cov, dh0, nullptr, t, 0, 192, 704);
        agcn_core(130, 136, 0, 704, wD0gH, wD0gL, d0gb, 256, 1, zr, nullptr, 3);
        xcatT_kern<5><<<dim3(4, 16, 16), 256, 0, stream>>>(RMh, RMl, Th, gob, y_cov, dh0, zr, t, 2, 130, 704);
        agcn_core(130, 136, 2, 704, wD0uH, wD0uL, d0ub, 128, 3, zr, dh0, 3);
        // dec1: c=256, cpad=256, K3=4 -> zEnd = 256 = C
        xcatT_kern<6><<<dim3(8, 16, 16), 256, 0, stream>>>(RMh, RMl, Th, dh0, nullptr, dh1, nullptr, t, 0, 256, 1280);
        agcn_core(256, 256, 0, 1280, wD1gH, wD1gL, d1gb, 256, 1, zr, nullptr, 4);
        xcatT_kern<7><<<dim3(4, 16, 16), 256, 0, stream>>>(RMh, RMl, Th, dh0, nullptr, dh1, zr, t, 128, 256, 1280);
        agcn_core(256, 256, 128, 1280, wD1uH, wD1uL, d1ub, 128, 3, zr, dh1, 4);
        proj_out<<<cdiv(NB, 256), 256, 0, stream>>>(dh1, proj_w, proj_b, gob, out, t);
    }
}

// Round 10
// 5757.717 us; speedup vs baseline: 8.5108x; 1.1286x over previous
//
#include <hip/hip_runtime.h>
#include <math.h>

#define NNODE 1024
#define BATCH 16
#define NB    16384
#define TT    12

typedef __bf16 bf16x8 __attribute__((ext_vector_type(8)));
typedef float  f32x4  __attribute__((ext_vector_type(4)));

static inline int cdiv(int a, int b) { return (a + b - 1) / b; }

// proper s_waitcnt immediate: vmcnt N (6-bit split [3:0],[15:14]), lgkm=15, exp=7
__host__ __device__ constexpr int vmenc(int n) {
    return 0x0F70 | (n & 0xF) | ((n >> 4) << 14);
}

// async global->LDS, 16B per lane, wave-uniform LDS base + lane*16
__device__ inline void gll16(const void* g, void* l) {
    __builtin_amdgcn_global_load_lds(
        (const __attribute__((address_space(1))) void*)g,
        (__attribute__((address_space(3))) void*)l, 16, 0, 0);
}

// ---------------------------------------------------------------------------
// Split-bf16 GEMM, counted-vmcnt double-buffered pipeline, BK=64 K-steps,
// coalesced staging (8 rows x 128B per 1KB chunk), XCD-chunked block swizzle.
// D[i][j] = sum_k A[i][k]*B[j][k]  (both k-contig).
// PA/PB: plane counts (1 = hi only). Passes: Ah*Bh always; Ah*Bl if PB==2;
//        Al*Bh if PA==2 && kt<K3 && bn<aloCols.
// LDS swizzle: 16B slot s at row r stored at slot s^(r&(BK/8-1)); applied on
// the global source address (write) and the ds_read address (read).
// EPI 0: plain bf16 store Ch
// EPI 1: +bias, sigmoid -> Cf
// EPI 2: RM-transposed hop store: RM[(n*16+b)*ldc + (1+bn/1024)*cpad + i] (hi)
// EPI 3: +bias, tanh, fused GRU: hout = r*hout + (1-r)*hc  (r from zrp)
// ---------------------------------------------------------------------------
template<int BM, int BN, int BK, int PA, int PB, int EPI>
__global__ __launch_bounds__(256) void mm_kern(
    const __bf16* __restrict__ Ah, const __bf16* __restrict__ Al, long lda, long zA,
    const __bf16* __restrict__ Bh, const __bf16* __restrict__ Bl, long zB, long ldb,
    int M, int Ksteps, int K3, int aloCols,
    __bf16* __restrict__ Ch, float* __restrict__ Cf,
    long ldc, long zC, int cpadParam, long MoffParam,
    const float* __restrict__ bias, const float* __restrict__ zrp,
    float* __restrict__ hout)
{
    constexpr int WM = BM / 2, WN = BN / 2;
    constexpr int MF = WM / 16, NF = WN / 16;
    constexpr int NSLOT = BK / 8;                   // 16B slots per row
    constexpr int RPC = 512 / BK;                   // rows per 1KB chunk
    constexpr int nA = BM / RPC, nB = BN / RPC;     // chunks per plane
    constexpr int nAl = (PA == 2) ? nA : 0;
    constexpr int nBl = (PB == 2) ? nB : 0;
    constexpr int TOT = nA + nAl + nB + nBl;
    constexpr int NPS = TOT / 4;                    // chunks per wave
    constexpr int cAlw = nAl / 4;
    constexpr int NPfull = NPS, NPnoAl = NPS - cAlw;
    constexpr int e0 = nA, e1 = nA + nAl, e2 = nA + nAl + nB;
    constexpr int bAl = BM * BK;
    constexpr int bBh = (PA == 2 ? 2 : 1) * BM * BK;
    constexpr int bBl = bBh + BN * BK;
    constexpr int BUFE = ((PA == 2 ? 2 : 1) * BM + (PB == 2 ? 2 : 1) * BN) * BK;
    __shared__ __bf16 smem[2 * BUFE];

    // ---- block swizzle: bijective XCD chunking + 2-col band ----
    const int nwgx = gridDim.x, nwgy = gridDim.y;
    const int nwg = nwgx * nwgy;
    const int lin = blockIdx.y * nwgx + blockIdx.x;
    const int q8 = nwg >> 3, r8 = nwg & 7;
    const int xcd = lin & 7, cidx = lin >> 3;
    const int lin2 = (xcd < r8) ? (xcd * (q8 + 1) + cidx)
                                : (r8 * (q8 + 1) + (xcd - r8) * q8 + cidx);
    const int G = ((nwgx & 1) == 0) ? 2 : 1;
    const int band = G * nwgy;
    const int gb = lin2 / band, rm = lin2 - gb * band;
    const int bxs = gb * G + (rm & (G - 1));
    const int bys = rm / G;

    const int bm = bys * BM, bn = bxs * BN;
    const int tid = threadIdx.x, w = tid >> 6, lane = tid & 63;
    const int wr = w >> 1, wc = w & 1;
    const int lgrp = lane >> 4, lrow = lane & 15;
    const bool aloNeed = (PA == 2) && (bn < aloCols);

    Ah += (size_t)blockIdx.z * zA;  Al += (size_t)blockIdx.z * zA;
    Bh += (size_t)blockIdx.z * zB;  Bl += (size_t)blockIdx.z * zB;

    // staging: lane -> row-in-chunk = lane/NSLOT, slot = (lane%NSLOT)^(row%NSLOT)
    const int srow = lane / NSLOT;
    const int kgel = ((lane & (NSLOT - 1)) ^ (srow & (NSLOT - 1))) * 8;
    const __bf16* sp[NPS];
    int dpo[NPS];
    int ttyp[NPS];
#pragma unroll
    for (int p = 0; p < NPS; ++p) {
        int q = p * 4 + w;
        int tile = (q < e0) ? 0 : (q < e1) ? 1 : (q < e2) ? 2 : 3;
        int qq = q - ((tile == 0) ? 0 : (tile == 1) ? e0 : (tile == 2) ? e1 : e2);
        const __bf16* base = (tile == 0) ? Ah : (tile == 1) ? Al : (tile == 2) ? Bh : Bl;
        long ld = (tile < 2) ? lda : ldb;
        int  rb = (tile < 2) ? bm : bn;
        sp[p] = base + (size_t)(rb + qq * RPC + srow) * ld + kgel;
        int tbase = (tile == 0) ? 0 : (tile == 1) ? bAl : (tile == 2) ? bBh : bBl;
        dpo[p] = tbase * 2 + qq * 1024;
        ttyp[p] = tile;
    }

    f32x4 acc[MF][NF];
#pragma unroll
    for (int i = 0; i < MF; ++i)
#pragma unroll
        for (int j = 0; j < NF; ++j)
#pragma unroll
            for (int e = 0; e < 4; ++e) acc[i][j][e] = 0.f;

    auto stage = [&](int kt, int bsel) {
        char* lb = (char*)smem + bsel * (BUFE * 2);
#pragma unroll
        for (int p = 0; p < NPS; ++p) {
            int tile = ttyp[p];
            bool go = (tile == 0) || (tile == 2)
                   || (tile == 1 && aloNeed && kt < K3)
                   || (tile == 3 && PB == 2);
            if (go) gll16(sp[p] + (size_t)kt * BK, lb + dpo[p]);
        }
    };

    stage(0, 0);

    const int rsw = (lrow & (NSLOT - 1));   // read-side row-swizzle term

    for (int kt = 0; kt < Ksteps; ++kt) {
        const int cur = kt & 1;
        __builtin_amdgcn_s_barrier();
        __builtin_amdgcn_sched_barrier(0);
        if (kt + 1 < Ksteps) {
            stage(kt + 1, cur ^ 1);
            if (aloNeed && (kt + 1) < K3)
                __builtin_amdgcn_s_waitcnt(vmenc(NPfull));
            else
                __builtin_amdgcn_s_waitcnt(vmenc(NPnoAl));
        } else {
            __builtin_amdgcn_s_waitcnt(vmenc(0));
        }
        __builtin_amdgcn_s_barrier();
        __builtin_amdgcn_sched_barrier(0);

        const __bf16* sb = smem + cur * BUFE;
#pragma unroll
        for (int kh = 0; kh < BK / 32; ++kh) {
            const int so = ((kh * 4 + lgrp) ^ rsw) * 8;
            bf16x8 aH[MF], bHf[NF];
#pragma unroll
            for (int mf = 0; mf < MF; ++mf) {
                int row = wr * WM + mf * 16 + lrow;
                aH[mf] = *(const bf16x8*)(sb + (size_t)row * BK + so);
            }
#pragma unroll
            for (int nf = 0; nf < NF; ++nf) {
                int col = wc * WN + nf * 16 + lrow;
                bHf[nf] = *(const bf16x8*)(sb + bBh + (size_t)col * BK + so);
            }
            __builtin_amdgcn_s_setprio(1);
#pragma unroll
            for (int mf = 0; mf < MF; ++mf)
#pragma unroll
                for (int nf = 0; nf < NF; ++nf)
                    acc[mf][nf] = __builtin_amdgcn_mfma_f32_16x16x32_bf16(aH[mf], bHf[nf], acc[mf][nf], 0, 0, 0);

            if (PB == 2) {
                bf16x8 bLf[NF];
#pragma unroll
                for (int nf = 0; nf < NF; ++nf) {
                    int col = wc * WN + nf * 16 + lrow;
                    bLf[nf] = *(const bf16x8*)(sb + bBl + (size_t)col * BK + so);
                }
#pragma unroll
                for (int mf = 0; mf < MF; ++mf)
#pragma unroll
                    for (int nf = 0; nf < NF; ++nf)
                        acc[mf][nf] = __builtin_amdgcn_mfma_f32_16x16x32_bf16(aH[mf], bLf[nf], acc[mf][nf], 0, 0, 0);
            }
            if (PA == 2 && aloNeed && kt < K3) {
                bf16x8 aL[MF];
#pragma unroll
                for (int mf = 0; mf < MF; ++mf) {
                    int row = wr * WM + mf * 16 + lrow;
                    aL[mf] = *(const bf16x8*)(sb + bAl + (size_t)row * BK + so);
                }
#pragma unroll
                for (int mf = 0; mf < MF; ++mf)
#pragma unroll
                    for (int nf = 0; nf < NF; ++nf)
                        acc[mf][nf] = __builtin_amdgcn_mfma_f32_16x16x32_bf16(aL[mf], bHf[nf], acc[mf][nf], 0, 0, 0);
            }
            __builtin_amdgcn_s_setprio(0);
        }
    }

    if (EPI == 2) {
        // ---- LDS-transposed RM store (hi only) ----
        constexpr int NI = BM / 16;
        __syncthreads();
        __bf16* LT = smem;                  // BM*BN elems <= 2*BUFE
#pragma unroll
        for (int mf = 0; mf < MF; ++mf) {
            int il = wr * MF + mf;
#pragma unroll
            for (int nf = 0; nf < NF; ++nf) {
                int nl = wc * WN + nf * 16 + lrow;
#pragma unroll
                for (int r = 0; r < 4; ++r) {
                    int b = lgrp * 4 + r;
                    LT[nl * BM + ((b ^ (nl & 15)) * NI) + il] = (__bf16)acc[mf][nf][r];
                }
            }
        }
        __syncthreads();
        const int ibase = (int)((MoffParam + bm) >> 4);
        const long scol = (long)(1 + (bn >> 10)) * cpadParam + ibase;
        const bool fullM = (bm + BM <= M);
        const bool al16 = ((scol & 7) == 0) && (NI == 8);
#pragma unroll
        for (int q = 0; q < (BN * 16) / 256; ++q) {
            int rr = q * 256 + tid;
            int nl = rr >> 4, b = rr & 15;
            int el = nl * BM + ((b ^ (nl & 15)) * NI);
            int n = (bn & 1023) + nl;
            size_t addr = ((size_t)n * 16 + b) * ldc + scol;
            if (fullM && al16) {
                *(uint4*)(Ch + addr) = *(const uint4*)(LT + el);
            } else {
#pragma unroll
                for (int il = 0; il < NI; ++il)
                    if (bm + il * 16 + b < M) Ch[addr + il] = LT[el + il];
            }
        }
        return;
    }

    const size_t cz = (size_t)blockIdx.z * zC;
#pragma unroll
    for (int mf = 0; mf < MF; ++mf) {
        int gi0 = bm + wr * WM + mf * 16 + lgrp * 4;
#pragma unroll
        for (int nf = 0; nf < NF; ++nf) {
            int gj = bn + wc * WN + nf * 16 + lrow;
#pragma unroll
            for (int r = 0; r < 4; ++r) {
                int gi = gi0 + r;
                if (gi < M) {
                    float v = acc[mf][nf][r];
                    if (EPI == 0) {
                        Ch[cz + (size_t)gi * ldc + gj] = (__bf16)v;
                    } else if (EPI == 1) {
                        v += bias[gj];
                        v = 1.f / (1.f + expf(-v));
                        Cf[cz + (size_t)gi * ldc + gj] = v;
                    } else if (EPI == 3) {
                        v += bias[gj];
                        v = tanhf(v);
                        float rg = zrp[(size_t)gi * 2 * ldc + ldc + gj];
                        size_t hix = (size_t)gi * ldc + gj;
                        hout[hix] = rg * hout[hix] + (1.f - rg) * v;
                    }
                }
            }
        }
    }
}

// ---------------------------------------------------------------------------
// Fused concat-build + transpose: computes v(cc,n,b), writes RM hi plane
// (coalesced, cc-contig) and T hi plane (coalesced, n-contig, via LDS)
// for cc in [cc0, C).
// ---------------------------------------------------------------------------
template<int MODE>
__global__ __launch_bounds__(256) void xcatT_kern(
    __bf16* __restrict__ RMh, __bf16* __restrict__ Th,
    const float* __restrict__ s1, const float* __restrict__ s2,
    const float* __restrict__ h, const float* __restrict__ zr,
    int t, int cc0, int KP)
{
    constexpr int C = (MODE < 2) ? 65 : (MODE < 4) ? 128 : (MODE < 6) ? 130 : 256;
    __shared__ __bf16 tile[32][66];
    const int b = blockIdx.z, nt = blockIdx.y * 64;
    const int kkb = cc0 + blockIdx.x * 32;
    const int tdx = threadIdx.x;

#pragma unroll
    for (int rep = 0; rep < 8; ++rep) {
        int cc = kkb + (tdx & 31);
        int nl = rep * 8 + (tdx >> 5);
        int n = nt + nl;
        int r = n * 16 + b;
        float v = 0.f;
        if (cc < C) {
            if (MODE == 0 || MODE == 1) {
                if (cc == 0) v = s1[((size_t)b * TT + t) * NNODE + n];
                else { float hv = h[(size_t)r * 64 + cc - 1];
                       v = (MODE == 1) ? zr[(size_t)r * 128 + cc - 1] * hv : hv; }
            } else if (MODE == 2 || MODE == 3) {
                if (cc < 64) v = s1[(size_t)r * 64 + cc];
                else { float hv = h[(size_t)r * 64 + cc - 64];
                       v = (MODE == 3) ? zr[(size_t)r * 128 + cc - 64] * hv : hv; }
            } else if (MODE == 4 || MODE == 5) {
                if (cc == 0) v = s1[r];
                else if (cc == 1) v = s2[((size_t)b * TT + t) * NNODE + n];
                else { float hv = h[(size_t)r * 128 + cc - 2];
                       v = (MODE == 5) ? zr[(size_t)r * 256 + cc - 2] * hv : hv; }
            } else {
                if (cc < 128) v = s1[(size_t)r * 128 + cc];
                else { float hv = h[(size_t)r * 128 + cc - 128];
                       v = (MODE == 7) ? zr[(size_t)r * 256 + cc - 128] * hv : hv; }
            }
        }
        __bf16 hi = (__bf16)v;
        if (cc < C)
            RMh[(size_t)r * KP + cc] = hi;
        tile[tdx & 31][nl] = hi;
    }
    __syncthreads();
#pragma unroll
    for (int rep = 0; rep < 8; ++rep) {
        int kkl = rep * 4 + (tdx >> 6);
        int kk = kkb + kkl;
        int n = nt + (tdx & 63);
        if (kk < C)
            Th[((size_t)kk * 16 + b) * 1024 + n] = tile[kkl][tdx & 63];
    }
}

// ---------------------------------------------------------------------------
// small kernels
// ---------------------------------------------------------------------------
__global__ __launch_bounds__(256) void compute_ne(
    const float* __restrict__ We1, const float* __restrict__ We2,
    const float* __restrict__ Mem, float* __restrict__ ne1, float* __restrict__ ne2)
{
    int idx = blockIdx.x * 256 + threadIdx.x;
    if (idx >= 2 * 65536) return;
    int which = idx >> 16;
    int i = idx & 65535;
    int n = i >> 6, d = i & 63;
    const float* We = which ? We2 : We1;
    float acc = 0.f;
#pragma unroll
    for (int k = 0; k < 20; ++k) acc += We[n * 20 + k] * Mem[k * 64 + d];
    (which ? ne2 : ne1)[i] = acc;
}

__global__ __launch_bounds__(256) void build_g(
    const float* __restrict__ ne1, const float* __restrict__ ne2, float* __restrict__ g)
{
    int row = blockIdx.x;
    int n = row & 1023;
    const float* qa = (row < 1024) ? ne1 : ne2;
    const float* kb = (row < 1024) ? ne2 : ne1;
    __shared__ float q[64];
    __shared__ float sc[1024];
    __shared__ float red[256];
    int tid = threadIdx.x;
    if (tid < 64) q[tid] = qa[n * 64 + tid];
    __syncthreads();
    for (int m = tid; m < 1024; m += 256) {
        float acc = 0.f;
        const float* kr = kb + m * 64;
#pragma unroll 8
        for (int d = 0; d < 64; ++d) acc += q[d] * kr[d];
        sc[m] = fmaxf(acc, 0.f);
    }
    __syncthreads();
    float mx = -1e30f;
    for (int m = tid; m < 1024; m += 256) mx = fmaxf(mx, sc[m]);
    red[tid] = mx;
    __syncthreads();
    for (int s2 = 128; s2 > 0; s2 >>= 1) {
        if (tid < s2) red[tid] = fmaxf(red[tid], red[tid + s2]);
        __syncthreads();
    }
    mx = red[0];
    __syncthreads();
    float sum = 0.f;
    for (int m = tid; m < 1024; m += 256) {
        float e = expf(sc[m] - mx);
        sc[m] = e;
        sum += e;
    }
    red[tid] = sum;
    __syncthreads();
    for (int s2 = 128; s2 > 0; s2 >>= 1) {
        if (tid < s2) red[tid] += red[tid + s2];
        __syncthreads();
    }
    float inv = 1.f / red[0];
    for (int m = tid; m < 1024; m += 256) g[(size_t)row * 1024 + m] = sc[m] * inv;
}

__global__ __launch_bounds__(256) void g_split(
    const float* __restrict__ g, __bf16* __restrict__ gh, __bf16* __restrict__ gl)
{
    int i = blockIdx.x * 256 + threadIdx.x;
    if (i >= 2048 * 1024) return;
    float v = g[i];
    __bf16 h = (__bf16)v;
    gh[i] = h;
    gl[i] = (__bf16)(v - (float)h);
}

__global__ __launch_bounds__(256) void gT_kern(
    const float* __restrict__ gf, __bf16* __restrict__ gTh, __bf16* __restrict__ gTl)
{
    __shared__ float tile[32][33];
    int z = blockIdx.z;
    int m0 = blockIdx.y * 32, k0 = blockIdx.x * 32;
    int tx = threadIdx.x & 31, ty = threadIdx.x >> 5;
    for (int r = ty; r < 32; r += 8)
        tile[r][tx] = gf[(size_t)(z * 1024 + m0 + r) * 1024 + k0 + tx];
    __syncthreads();
    for (int r = ty; r < 32; r += 8) {
        float v = tile[tx][r];
        __bf16 h = (__bf16)v;
        size_t o = (size_t)(z * 1024 + k0 + r) * 1024 + m0 + tx;
        gTh[o] = h;
        gTl[o] = (__bf16)(v - (float)h);
    }
}

// effective weight, transposed [cout][KP], padded slots (cpad), hi plane only
__global__ __launch_bounds__(256) void build_weffT(
    const float* __restrict__ W, __bf16* __restrict__ dh,
    int c, int cpad, int cout, int KP)
{
    int idx = blockIdx.x * 256 + threadIdx.x;
    if (idx >= cout * KP) return;
    int o = idx / KP, kk = idx - o * KP;
    float v = 0.f;
    if (kk < 5 * cpad) {
        int s = kk / cpad;
        int i = kk - s * cpad;
        if (i < c) {
            if      (s == 0) v = W[(size_t)(0 * c + i) * cout + o] + W[(size_t)(3 * c + i) * cout + o]
                               - W[(size_t)(2 * c + i) * cout + o] - W[(size_t)(5 * c + i) * cout + o];
            else if (s == 1) v = W[(size_t)(1 * c + i) * cout + o];
            else if (s == 2) v = W[(size_t)(4 * c + i) * cout + o];
            else if (s == 3) v = 2.f * W[(size_t)(2 * c + i) * cout + o];
            else             v = 2.f * W[(size_t)(5 * c + i) * cout + o];
        }
    }
    dh[idx] = (__bf16)v;
}

__global__ __launch_bounds__(64) void attention(
    const float* __restrict__ h, const float* __restrict__ Wq,
    const float* __restrict__ Mem, float* __restrict__ htc)
{
    int r = blockIdx.x;
    int j = threadIdx.x;
    __shared__ float hr[64], q[64], sc[20];
    hr[j] = h[(size_t)r * 64 + j];
    __syncthreads();
    float acc = 0.f;
#pragma unroll 8
    for (int i = 0; i < 64; ++i) acc += hr[i] * Wq[i * 64 + j];
    q[j] = acc;
    __syncthreads();
    if (j < 20) {
        float a = 0.f;
#pragma unroll 8
        for (int d = 0; d < 64; ++d) a += q[d] * Mem[j * 64 + d];
        sc[j] = a;
    }
    __syncthreads();
    if (j == 0) {
        float mx = sc[0];
        for (int m = 1; m < 20; ++m) mx = fmaxf(mx, sc[m]);
        float s = 0.f;
        for (int m = 0; m < 20; ++m) { sc[m] = expf(sc[m] - mx); s += sc[m]; }
        float inv = 1.f / s;
        for (int m = 0; m < 20; ++m) sc[m] *= inv;
    }
    __syncthreads();
    float v = 0.f;
#pragma unroll
    for (int m = 0; m < 20; ++m) v += sc[m] * Mem[m * 64 + j];
    htc[(size_t)r * 128 + j] = hr[j];
    htc[(size_t)r * 128 + 64 + j] = v;
}

__global__ __launch_bounds__(256) void proj_out(
    const float* __restrict__ h1, const float* __restrict__ pw, const float* __restrict__ pb,
    float* __restrict__ go, float* __restrict__ out, int t)
{
    int r = blockIdx.x * 256 + threadIdx.x;
    if (r >= NB) return;
    float acc = pb[0];
    const float* hr = h1 + (size_t)r * 128;
#pragma unroll 8
    for (int i = 0; i < 128; ++i) acc += hr[i] * pw[i];
    go[r] = acc;
    int n = r >> 4, b = r & 15;
    out[((size_t)b * TT + t) * NNODE + n] = acc;
}

// ---------------------------------------------------------------------------
// host
// ---------------------------------------------------------------------------
extern "C" void kernel_launch(void* const* d_in, const int* in_sizes, int n_in,
                              void* d_out, int out_size, void* d_ws, size_t ws_size,
                              hipStream_t stream)
{
    const float* x      = (const float*)d_in[0];
    const float* y_cov  = (const float*)d_in[1];
    const float* Memory = (const float*)d_in[2];
    const float* Wq     = (const float*)d_in[3];
    const float* We1    = (const float*)d_in[4];
    const float* We2    = (const float*)d_in[5];
    const float* e0gw = (const float*)d_in[6];  const float* e0gb = (const float*)d_in[7];
    const float* e0uw = (const float*)d_in[8];  const float* e0ub = (const float*)d_in[9];
    const float* e1gw = (const float*)d_in[10]; const float* e1gb = (const float*)d_in[11];
    const float* e1uw = (const float*)d_in[12]; const float* e1ub = (const float*)d_in[13];
    const float* d0gw = (const float*)d_in[14]; const float* d0gb = (const float*)d_in[15];
    const float* d0uw = (const float*)d_in[16]; const float* d0ub = (const float*)d_in[17];
    const float* d1gw = (const float*)d_in[18]; const float* d1gb = (const float*)d_in[19];
    const float* d1uw = (const float*)d_in[20]; const float* d1ub = (const float*)d_in[21];
    const float* proj_w = (const float*)d_in[22];
    const float* proj_b = (const float*)d_in[23];
    float* out = (float*)d_out;
    (void)in_sizes; (void)n_in; (void)out_size; (void)ws_size;

    char* wsb = (char*)d_ws;
    size_t off = 0;
    auto alloc = [&](size_t bytes) -> void* {
        void* p = wsb + off;
        off += (bytes + 255) & ~(size_t)255;
        return p;
    };

    float*  gf    = (float*) alloc(2048L * 1024 * 4);
    __bf16* gquad = (__bf16*)alloc(4096L * 1024 * 2);   // g1|g2|G2_1|G2_2 (hi)
    __bf16* gsL   = (__bf16*)alloc(2048L * 1024 * 2);
    __bf16* gTh   = (__bf16*)alloc(2048L * 1024 * 2);
    __bf16* gTl   = (__bf16*)alloc(2048L * 1024 * 2);
    float*  ne1   = (float*) alloc(65536L * 4);
    float*  ne2   = (float*) alloc(65536L * 4);
    auto allocWT = [&](int cout, int KP) {
        return (__bf16*)alloc((size_t)cout * KP * 2);
    };
    __bf16* wE0g = allocWT(128, 384);   __bf16* wE0u = allocWT(64, 384);
    __bf16* wE1g = allocWT(128, 640);   __bf16* wE1u = allocWT(64, 640);
    __bf16* wD0g = allocWT(256, 704);   __bf16* wD0u = allocWT(128, 704);
    __bf16* wD1g = allocWT(256, 1280);  __bf16* wD1u = allocWT(128, 1280);
    __bf16* RMh = (__bf16*)alloc((size_t)NB * 1280 * 2);
    __bf16* Th  = (__bf16*)alloc((size_t)4096 * 1024 * 2);
    float* zr  = (float*)alloc((size_t)NB * 256 * 4);
    float* h0e = (float*)alloc((size_t)NB * 64 * 4);
    float* h1e = (float*)alloc((size_t)NB * 64 * 4);
    float* dh0 = (float*)alloc((size_t)NB * 128 * 4);
    float* dh1 = (float*)alloc((size_t)NB * 128 * 4);
    float* gob = (float*)alloc((size_t)NB * 4);

    // ---- setup ----
    compute_ne<<<cdiv(2 * 65536, 256), 256, 0, stream>>>(We1, We2, Memory, ne1, ne2);
    build_g<<<2048, 256, 0, stream>>>(ne1, ne2, gf);
    g_split<<<cdiv(2048 * 1024, 256), 256, 0, stream>>>(gf, gquad, gsL);
    {
        dim3 gt(32, 32, 2);
        gT_kern<<<gt, 256, 0, stream>>>(gf, gTh, gTl);
        // G2_z = g_z @ g_z  (3-pass split), -> gquad rows 2048 + z*1024
        dim3 gg(8, 8, 2);
        mm_kern<128, 128, 64, 2, 2, 0><<<gg, 256, 0, stream>>>(
            gquad, gsL, 1024, (long)1024 * 1024,
            gTh, gTl, (long)1024 * 1024, 1024,
            1024, 16, 16, 1 << 30,
            gquad + (size_t)2048 * 1024, nullptr, 1024, (long)1024 * 1024,
            0, 0, nullptr, nullptr, nullptr);
    }
    build_weffT<<<cdiv(128 * 384, 256), 256, 0, stream>>>(e0gw, wE0g, 65, 72, 128, 384);
    build_weffT<<<cdiv(64 * 384, 256), 256, 0, stream>>>(e0uw, wE0u, 65, 72, 64, 384);
    build_weffT<<<cdiv(128 * 640, 256), 256, 0, stream>>>(e1gw, wE1g, 128, 128, 128, 640);
    build_weffT<<<cdiv(64 * 640, 256), 256, 0, stream>>>(e1uw, wE1u, 128, 128, 64, 640);
    build_weffT<<<cdiv(256 * 704, 256), 256, 0, stream>>>(d0gw, wD0g, 130, 136, 256, 704);
    build_weffT<<<cdiv(128 * 704, 256), 256, 0, stream>>>(d0uw, wD0u, 130, 136, 128, 704);
    build_weffT<<<cdiv(256 * 1280, 256), 256, 0, stream>>>(d1gw, wD1g, 256, 256, 256, 1280);
    build_weffT<<<cdiv(128 * 1280, 256), 256, 0, stream>>>(d1uw, wD1u, 256, 256, 128, 1280);
    hipMemsetAsync(h0e, 0, (size_t)NB * 64 * 4 * 2, stream);   // h0e + h1e adjacent

    // cell core: hop (EPI2, RM direct) + pure-bf16 weight GEMM (PA=PB=1)
    auto agcn_core = [&](int c, int cpad, int cin2, int KP,
                         const __bf16* wt, const float* bias, int cout, int epi,
                         float* zrOrOut, float* hptr) {
        int Moff = 16 * cin2, Mv = 16 * c - Moff;
        dim3 gh(32, cdiv(Mv, 128), 1);
        mm_kern<128, 128, 64, 1, 1, 2><<<gh, 256, 0, stream>>>(
            Th + (size_t)Moff * 1024, Th + (size_t)Moff * 1024, 1024, 0,
            gquad, gquad, 0, 1024,
            Mv, 16, 0, 0,
            RMh, nullptr, KP, 0, cpad, Moff,
            nullptr, nullptr, nullptr);
        if (epi == 1) {
            dim3 gw(2, 128, 1);
            if (cout == 256)
                mm_kern<128, 128, 64, 1, 1, 1><<<gw, 256, 0, stream>>>(
                    RMh, RMh, KP, 0, wt, wt, 0, KP, NB, KP / 64, 0, 0,
                    nullptr, zrOrOut, cout, 0, 0, 0, bias, nullptr, nullptr);
            else
                mm_kern<128, 64, 64, 1, 1, 1><<<gw, 256, 0, stream>>>(
                    RMh, RMh, KP, 0, wt, wt, 0, KP, NB, KP / 64, 0, 0,
                    nullptr, zrOrOut, cout, 0, 0, 0, bias, nullptr, nullptr);
        } else {
            if (cout == 64) {
                dim3 gw(1, 256, 1);
                mm_kern<64, 64, 64, 1, 1, 3><<<gw, 256, 0, stream>>>(
                    RMh, RMh, KP, 0, wt, wt, 0, KP, NB, KP / 64, 0, 0,
                    nullptr, nullptr, cout, 0, 0, 0, bias, zrOrOut, hptr);
            } else {
                dim3 gw(2, 128, 1);
                mm_kern<128, 64, 64, 1, 1, 3><<<gw, 256, 0, stream>>>(
                    RMh, RMh, KP, 0, wt, wt, 0, KP, NB, KP / 64, 0, 0,
                    nullptr, nullptr, cout, 0, 0, 0, bias, zrOrOut, hptr);
            }
        }
    };

    // ---- encoder ----
    for (int t = 0; t < TT; ++t) {
        xcatT_kern<0><<<dim3(3, 16, 16), 256, 0, stream>>>(RMh, Th, x, nullptr, h0e, nullptr, t, 0, 384);
        agcn_core(65, 72, 0, 384, wE0g, e0gb, 128, 1, zr, nullptr);
        xcatT_kern<1><<<dim3(2, 16, 16), 256, 0, stream>>>(RMh, Th, x, nullptr, h0e, zr, t, 1, 384);
        agcn_core(65, 72, 1, 384, wE0u, e0ub, 64, 3, zr, h0e);
        xcatT_kern<2><<<dim3(4, 16, 16), 256, 0, stream>>>(RMh, Th, h0e, nullptr, h1e, nullptr, t, 0, 640);
        agcn_core(128, 128, 0, 640, wE1g, e1gb, 128, 1, zr, nullptr);
        xcatT_kern<3><<<dim3(2, 16, 16), 256, 0, stream>>>(RMh, Th, h0e, nullptr, h1e, zr, t, 64, 640);
        agcn_core(128, 128, 64, 640, wE1u, e1ub, 64, 3, zr, h1e);
    }

    // ---- memory attention ----
    attention<<<NB, 64, 0, stream>>>(h1e, Wq, Memory, dh0);
    hipMemcpyAsync(dh1, dh0, (size_t)NB * 128 * 4, hipMemcpyDeviceToDevice, stream);
    hipMemsetAsync(gob, 0, (size_t)NB * 4, stream);

    // ---- decoder ----
    for (int t = 0; t < TT; ++t) {
        xcatT_kern<4><<<dim3(5, 16, 16), 256, 0, stream>>>(RMh, Th, gob, y_cov, dh0, nullptr, t, 0, 704);
        agcn_core(130, 136, 0, 704, wD0g, d0gb, 256, 1, zr, nullptr);
        xcatT_kern<5><<<dim3(4, 16, 16), 256, 0, stream>>>(RMh, Th, gob, y_cov, dh0, zr, t, 2, 704);
        agcn_core(130, 136, 2, 704, wD0u, d0ub, 128, 3, zr, dh0);
        xcatT_kern<6><<<dim3(8, 16, 16), 256, 0, stream>>>(RMh, Th, dh0, nullptr, dh1, nullptr, t, 0, 1280);
        agcn_core(256, 256, 0, 1280, wD1g, d1gb, 256, 1, zr, nullptr);
        xcatT_kern<7><<<dim3(4, 16, 16), 256, 0, stream>>>(RMh, Th, dh0, nullptr, dh1, zr, t, 128, 1280);
        agcn_core(256, 256, 128, 1280, wD1u, d1ub, 128, 3, zr, dh1);
        proj_out<<<cdiv(NB, 256), 256, 0, stream>>>(dh1, proj_w, proj_b, gob, out, t);
    }
}

// Round 11
// 5287.019 us; speedup vs baseline: 9.2685x; 1.0890x over previous
//
#include <hip/hip_runtime.h>
#include <math.h>

#define NNODE 1024
#define BATCH 16
#define NB    16384
#define TT    12

typedef __bf16 bf16x8 __attribute__((ext_vector_type(8)));
typedef float  f32x4  __attribute__((ext_vector_type(4)));

static inline int cdiv(int a, int b) { return (a + b - 1) / b; }

// proper s_waitcnt immediate: vmcnt N (6-bit split [3:0],[15:14]), lgkm=15, exp=7
__host__ __device__ constexpr int vmenc(int n) {
    return 0x0F70 | (n & 0xF) | ((n >> 4) << 14);
}

// async global->LDS, 16B per lane, wave-uniform LDS base + lane*16
__device__ inline void gll16(const void* g, void* l) {
    __builtin_amdgcn_global_load_lds(
        (const __attribute__((address_space(1))) void*)g,
        (__attribute__((address_space(3))) void*)l, 16, 0, 0);
}

// ---------------------------------------------------------------------------
// Split-bf16 GEMM, counted-vmcnt double-buffered pipeline, BK=64 K-steps,
// coalesced staging (8 rows x 128B per 1KB chunk), XCD-chunked block swizzle.
// D[i][j] = sum_k A[i][k]*B[j][k]  (both k-contig).
// PA/PB: plane counts (1 = hi only). Passes: Ah*Bh always; Ah*Bl if PB==2;
//        Al*Bh if PA==2 && kt<K3 && bn<aloCols.
// LDS swizzle: 16B slot s at row r stored at slot s^(r&(BK/8-1)); applied on
// the global source address (write) and the ds_read address (read).
// EPI 0: plain bf16 store Ch
// EPI 1: +bias, sigmoid -> Cf
// EPI 2: RM-transposed hop store: RM[(n*16+b)*ldc + (1+bn/1024)*cpad + i] (hi)
// EPI 3: +bias, tanh, fused GRU: hout = r*hout + (1-r)*hc  (r from zrp)
// ---------------------------------------------------------------------------
template<int BM, int BN, int BK, int PA, int PB, int EPI>
__global__ __launch_bounds__(256) void mm_kern(
    const __bf16* __restrict__ Ah, const __bf16* __restrict__ Al, long lda, long zA,
    const __bf16* __restrict__ Bh, const __bf16* __restrict__ Bl, long zB, long ldb,
    int M, int Ksteps, int K3, int aloCols,
    __bf16* __restrict__ Ch, float* __restrict__ Cf,
    long ldc, long zC, int cpadParam, long MoffParam,
    const float* __restrict__ bias, const float* __restrict__ zrp,
    float* __restrict__ hout)
{
    constexpr int WM = BM / 2, WN = BN / 2;
    constexpr int MF = WM / 16, NF = WN / 16;
    constexpr int NSLOT = BK / 8;                   // 16B slots per row
    constexpr int RPC = 512 / BK;                   // rows per 1KB chunk
    constexpr int nA = BM / RPC, nB = BN / RPC;     // chunks per plane
    constexpr int nAl = (PA == 2) ? nA : 0;
    constexpr int nBl = (PB == 2) ? nB : 0;
    constexpr int TOT = nA + nAl + nB + nBl;
    constexpr int NPS = TOT / 4;                    // chunks per wave
    constexpr int cAlw = nAl / 4;
    constexpr int NPfull = NPS, NPnoAl = NPS - cAlw;
    constexpr int e0 = nA, e1 = nA + nAl, e2 = nA + nAl + nB;
    constexpr int bAl = BM * BK;
    constexpr int bBh = (PA == 2 ? 2 : 1) * BM * BK;
    constexpr int bBl = bBh + BN * BK;
    constexpr int BUFE = ((PA == 2 ? 2 : 1) * BM + (PB == 2 ? 2 : 1) * BN) * BK;
    __shared__ __bf16 smem[2 * BUFE];

    // ---- block swizzle: bijective XCD chunking + 2-col band ----
    const int nwgx = gridDim.x, nwgy = gridDim.y;
    const int nwg = nwgx * nwgy;
    const int lin = blockIdx.y * nwgx + blockIdx.x;
    const int q8 = nwg >> 3, r8 = nwg & 7;
    const int xcd = lin & 7, cidx = lin >> 3;
    const int lin2 = (xcd < r8) ? (xcd * (q8 + 1) + cidx)
                                : (r8 * (q8 + 1) + (xcd - r8) * q8 + cidx);
    const int G = ((nwgx & 1) == 0) ? 2 : 1;
    const int band = G * nwgy;
    const int gb = lin2 / band, rm = lin2 - gb * band;
    const int bxs = gb * G + (rm & (G - 1));
    const int bys = rm / G;

    const int bm = bys * BM, bn = bxs * BN;
    const int tid = threadIdx.x, w = tid >> 6, lane = tid & 63;
    const int wr = w >> 1, wc = w & 1;
    const int lgrp = lane >> 4, lrow = lane & 15;
    const bool aloNeed = (PA == 2) && (bn < aloCols);

    Ah += (size_t)blockIdx.z * zA;  Al += (size_t)blockIdx.z * zA;
    Bh += (size_t)blockIdx.z * zB;  Bl += (size_t)blockIdx.z * zB;

    // staging: lane -> row-in-chunk = lane/NSLOT, slot = (lane%NSLOT)^(row%NSLOT)
    const int srow = lane / NSLOT;
    const int kgel = ((lane & (NSLOT - 1)) ^ (srow & (NSLOT - 1))) * 8;
    const __bf16* sp[NPS];
    int dpo[NPS];
    int ttyp[NPS];
#pragma unroll
    for (int p = 0; p < NPS; ++p) {
        int q = p * 4 + w;
        int tile = (q < e0) ? 0 : (q < e1) ? 1 : (q < e2) ? 2 : 3;
        int qq = q - ((tile == 0) ? 0 : (tile == 1) ? e0 : (tile == 2) ? e1 : e2);
        const __bf16* base = (tile == 0) ? Ah : (tile == 1) ? Al : (tile == 2) ? Bh : Bl;
        long ld = (tile < 2) ? lda : ldb;
        int  rb = (tile < 2) ? bm : bn;
        sp[p] = base + (size_t)(rb + qq * RPC + srow) * ld + kgel;
        int tbase = (tile == 0) ? 0 : (tile == 1) ? bAl : (tile == 2) ? bBh : bBl;
        dpo[p] = tbase * 2 + qq * 1024;
        ttyp[p] = tile;
    }

    f32x4 acc[MF][NF];
#pragma unroll
    for (int i = 0; i < MF; ++i)
#pragma unroll
        for (int j = 0; j < NF; ++j)
#pragma unroll
            for (int e = 0; e < 4; ++e) acc[i][j][e] = 0.f;

    auto stage = [&](int kt, int bsel) {
        char* lb = (char*)smem + bsel * (BUFE * 2);
#pragma unroll
        for (int p = 0; p < NPS; ++p) {
            int tile = ttyp[p];
            bool go = (tile == 0) || (tile == 2)
                   || (tile == 1 && aloNeed && kt < K3)
                   || (tile == 3 && PB == 2);
            if (go) gll16(sp[p] + (size_t)kt * BK, lb + dpo[p]);
        }
    };

    stage(0, 0);

    const int rsw = (lrow & (NSLOT - 1));   // read-side row-swizzle term

    for (int kt = 0; kt < Ksteps; ++kt) {
        const int cur = kt & 1;
        __builtin_amdgcn_s_barrier();
        __builtin_amdgcn_sched_barrier(0);
        if (kt + 1 < Ksteps) {
            stage(kt + 1, cur ^ 1);
            if (aloNeed && (kt + 1) < K3)
                __builtin_amdgcn_s_waitcnt(vmenc(NPfull));
            else
                __builtin_amdgcn_s_waitcnt(vmenc(NPnoAl));
        } else {
            __builtin_amdgcn_s_waitcnt(vmenc(0));
        }
        __builtin_amdgcn_s_barrier();
        __builtin_amdgcn_sched_barrier(0);

        const __bf16* sb = smem + cur * BUFE;
#pragma unroll
        for (int kh = 0; kh < BK / 32; ++kh) {
            const int so = ((kh * 4 + lgrp) ^ rsw) * 8;
            bf16x8 aH[MF], bHf[NF];
#pragma unroll
            for (int mf = 0; mf < MF; ++mf) {
                int row = wr * WM + mf * 16 + lrow;
                aH[mf] = *(const bf16x8*)(sb + (size_t)row * BK + so);
            }
#pragma unroll
            for (int nf = 0; nf < NF; ++nf) {
                int col = wc * WN + nf * 16 + lrow;
                bHf[nf] = *(const bf16x8*)(sb + bBh + (size_t)col * BK + so);
            }
            __builtin_amdgcn_s_setprio(1);
#pragma unroll
            for (int mf = 0; mf < MF; ++mf)
#pragma unroll
                for (int nf = 0; nf < NF; ++nf)
                    acc[mf][nf] = __builtin_amdgcn_mfma_f32_16x16x32_bf16(aH[mf], bHf[nf], acc[mf][nf], 0, 0, 0);

            if (PB == 2) {
                bf16x8 bLf[NF];
#pragma unroll
                for (int nf = 0; nf < NF; ++nf) {
                    int col = wc * WN + nf * 16 + lrow;
                    bLf[nf] = *(const bf16x8*)(sb + bBl + (size_t)col * BK + so);
                }
#pragma unroll
                for (int mf = 0; mf < MF; ++mf)
#pragma unroll
                    for (int nf = 0; nf < NF; ++nf)
                        acc[mf][nf] = __builtin_amdgcn_mfma_f32_16x16x32_bf16(aH[mf], bLf[nf], acc[mf][nf], 0, 0, 0);
            }
            if (PA == 2 && aloNeed && kt < K3) {
                bf16x8 aL[MF];
#pragma unroll
                for (int mf = 0; mf < MF; ++mf) {
                    int row = wr * WM + mf * 16 + lrow;
                    aL[mf] = *(const bf16x8*)(sb + bAl + (size_t)row * BK + so);
                }
#pragma unroll
                for (int mf = 0; mf < MF; ++mf)
#pragma unroll
                    for (int nf = 0; nf < NF; ++nf)
                        acc[mf][nf] = __builtin_amdgcn_mfma_f32_16x16x32_bf16(aL[mf], bHf[nf], acc[mf][nf], 0, 0, 0);
            }
            __builtin_amdgcn_s_setprio(0);
        }
    }

    if (EPI == 2) {
        // ---- LDS-transposed RM store (hi only) ----
        constexpr int NI = BM / 16;
        __syncthreads();
        __bf16* LT = smem;                  // BM*BN elems <= 2*BUFE
#pragma unroll
        for (int mf = 0; mf < MF; ++mf) {
            int il = wr * MF + mf;
#pragma unroll
            for (int nf = 0; nf < NF; ++nf) {
                int nl = wc * WN + nf * 16 + lrow;
#pragma unroll
                for (int r = 0; r < 4; ++r) {
                    int b = lgrp * 4 + r;
                    LT[nl * BM + ((b ^ (nl & 15)) * NI) + il] = (__bf16)acc[mf][nf][r];
                }
            }
        }
        __syncthreads();
        const int ibase = (int)((MoffParam + bm) >> 4);
        const long scol = (long)(1 + (bn >> 10)) * cpadParam + ibase;
        const bool fullM = (bm + BM <= M);
        const bool al16 = ((scol & 7) == 0) && (NI == 8);
#pragma unroll
        for (int q = 0; q < (BN * 16) / 256; ++q) {
            int rr = q * 256 + tid;
            int nl = rr >> 4, b = rr & 15;
            int el = nl * BM + ((b ^ (nl & 15)) * NI);
            int n = (bn & 1023) + nl;
            size_t addr = ((size_t)n * 16 + b) * ldc + scol;
            if (fullM && al16) {
                *(uint4*)(Ch + addr) = *(const uint4*)(LT + el);
            } else {
#pragma unroll
                for (int il = 0; il < NI; ++il)
                    if (bm + il * 16 + b < M) Ch[addr + il] = LT[el + il];
            }
        }
        return;
    }

    const size_t cz = (size_t)blockIdx.z * zC;
#pragma unroll
    for (int mf = 0; mf < MF; ++mf) {
        int gi0 = bm + wr * WM + mf * 16 + lgrp * 4;
#pragma unroll
        for (int nf = 0; nf < NF; ++nf) {
            int gj = bn + wc * WN + nf * 16 + lrow;
#pragma unroll
            for (int r = 0; r < 4; ++r) {
                int gi = gi0 + r;
                if (gi < M) {
                    float v = acc[mf][nf][r];
                    if (EPI == 0) {
                        Ch[cz + (size_t)gi * ldc + gj] = (__bf16)v;
                    } else if (EPI == 1) {
                        v += bias[gj];
                        v = 1.f / (1.f + expf(-v));
                        Cf[cz + (size_t)gi * ldc + gj] = v;
                    } else if (EPI == 3) {
                        v += bias[gj];
                        v = tanhf(v);
                        float rg = zrp[(size_t)gi * 2 * ldc + ldc + gj];
                        size_t hix = (size_t)gi * ldc + gj;
                        hout[hix] = rg * hout[hix] + (1.f - rg) * v;
                    }
                }
            }
        }
    }
}

// ---------------------------------------------------------------------------
// Fused concat-build + transpose: computes v(cc,n,b), writes RM hi plane
// (coalesced, cc-contig) and T hi plane (coalesced, n-contig, via LDS)
// for cc in [cc0, C).
// ---------------------------------------------------------------------------
template<int MODE>
__global__ __launch_bounds__(256) void xcatT_kern(
    __bf16* __restrict__ RMh, __bf16* __restrict__ Th,
    const float* __restrict__ s1, const float* __restrict__ s2,
    const float* __restrict__ h, const float* __restrict__ zr,
    int t, int cc0, int KP)
{
    constexpr int C = (MODE < 2) ? 65 : (MODE < 4) ? 128 : (MODE < 6) ? 130 : 256;
    __shared__ __bf16 tile[32][66];
    const int b = blockIdx.z, nt = blockIdx.y * 64;
    const int kkb = cc0 + blockIdx.x * 32;
    const int tdx = threadIdx.x;

#pragma unroll
    for (int rep = 0; rep < 8; ++rep) {
        int cc = kkb + (tdx & 31);
        int nl = rep * 8 + (tdx >> 5);
        int n = nt + nl;
        int r = n * 16 + b;
        float v = 0.f;
        if (cc < C) {
            if (MODE == 0 || MODE == 1) {
                if (cc == 0) v = s1[((size_t)b * TT + t) * NNODE + n];
                else { float hv = h[(size_t)r * 64 + cc - 1];
                       v = (MODE == 1) ? zr[(size_t)r * 128 + cc - 1] * hv : hv; }
            } else if (MODE == 2 || MODE == 3) {
                if (cc < 64) v = s1[(size_t)r * 64 + cc];
                else { float hv = h[(size_t)r * 64 + cc - 64];
                       v = (MODE == 3) ? zr[(size_t)r * 128 + cc - 64] * hv : hv; }
            } else if (MODE == 4 || MODE == 5) {
                if (cc == 0) v = s1[r];
                else if (cc == 1) v = s2[((size_t)b * TT + t) * NNODE + n];
                else { float hv = h[(size_t)r * 128 + cc - 2];
                       v = (MODE == 5) ? zr[(size_t)r * 256 + cc - 2] * hv : hv; }
            } else {
                if (cc < 128) v = s1[(size_t)r * 128 + cc];
                else { float hv = h[(size_t)r * 128 + cc - 128];
                       v = (MODE == 7) ? zr[(size_t)r * 256 + cc - 128] * hv : hv; }
            }
        }
        __bf16 hi = (__bf16)v;
        if (cc < C)
            RMh[(size_t)r * KP + cc] = hi;
        tile[tdx & 31][nl] = hi;
    }
    __syncthreads();
#pragma unroll
    for (int rep = 0; rep < 8; ++rep) {
        int kkl = rep * 4 + (tdx >> 6);
        int kk = kkb + kkl;
        int n = nt + (tdx & 63);
        if (kk < C)
            Th[((size_t)kk * 16 + b) * 1024 + n] = tile[kkl][tdx & 63];
    }
}

// ---------------------------------------------------------------------------
// small kernels
// ---------------------------------------------------------------------------
__global__ __launch_bounds__(256) void compute_ne(
    const float* __restrict__ We1, const float* __restrict__ We2,
    const float* __restrict__ Mem, float* __restrict__ ne1, float* __restrict__ ne2)
{
    int idx = blockIdx.x * 256 + threadIdx.x;
    if (idx >= 2 * 65536) return;
    int which = idx >> 16;
    int i = idx & 65535;
    int n = i >> 6, d = i & 63;
    const float* We = which ? We2 : We1;
    float acc = 0.f;
#pragma unroll
    for (int k = 0; k < 20; ++k) acc += We[n * 20 + k] * Mem[k * 64 + d];
    (which ? ne2 : ne1)[i] = acc;
}

__global__ __launch_bounds__(256) void build_g(
    const float* __restrict__ ne1, const float* __restrict__ ne2, float* __restrict__ g)
{
    int row = blockIdx.x;
    int n = row & 1023;
    const float* qa = (row < 1024) ? ne1 : ne2;
    const float* kb = (row < 1024) ? ne2 : ne1;
    __shared__ float q[64];
    __shared__ float sc[1024];
    __shared__ float red[256];
    int tid = threadIdx.x;
    if (tid < 64) q[tid] = qa[n * 64 + tid];
    __syncthreads();
    for (int m = tid; m < 1024; m += 256) {
        float acc = 0.f;
        const float* kr = kb + m * 64;
#pragma unroll 8
        for (int d = 0; d < 64; ++d) acc += q[d] * kr[d];
        sc[m] = fmaxf(acc, 0.f);
    }
    __syncthreads();
    float mx = -1e30f;
    for (int m = tid; m < 1024; m += 256) mx = fmaxf(mx, sc[m]);
    red[tid] = mx;
    __syncthreads();
    for (int s2 = 128; s2 > 0; s2 >>= 1) {
        if (tid < s2) red[tid] = fmaxf(red[tid], red[tid + s2]);
        __syncthreads();
    }
    mx = red[0];
    __syncthreads();
    float sum = 0.f;
    for (int m = tid; m < 1024; m += 256) {
        float e = expf(sc[m] - mx);
        sc[m] = e;
        sum += e;
    }
    red[tid] = sum;
    __syncthreads();
    for (int s2 = 128; s2 > 0; s2 >>= 1) {
        if (tid < s2) red[tid] += red[tid + s2];
        __syncthreads();
    }
    float inv = 1.f / red[0];
    for (int m = tid; m < 1024; m += 256) g[(size_t)row * 1024 + m] = sc[m] * inv;
}

__global__ __launch_bounds__(256) void g_split(
    const float* __restrict__ g, __bf16* __restrict__ gh, __bf16* __restrict__ gl)
{
    int i = blockIdx.x * 256 + threadIdx.x;
    if (i >= 2048 * 1024) return;
    float v = g[i];
    __bf16 h = (__bf16)v;
    gh[i] = h;
    gl[i] = (__bf16)(v - (float)h);
}

__global__ __launch_bounds__(256) void gT_kern(
    const float* __restrict__ gf, __bf16* __restrict__ gTh, __bf16* __restrict__ gTl)
{
    __shared__ float tile[32][33];
    int z = blockIdx.z;
    int m0 = blockIdx.y * 32, k0 = blockIdx.x * 32;
    int tx = threadIdx.x & 31, ty = threadIdx.x >> 5;
    for (int r = ty; r < 32; r += 8)
        tile[r][tx] = gf[(size_t)(z * 1024 + m0 + r) * 1024 + k0 + tx];
    __syncthreads();
    for (int r = ty; r < 32; r += 8) {
        float v = tile[tx][r];
        __bf16 h = (__bf16)v;
        size_t o = (size_t)(z * 1024 + k0 + r) * 1024 + m0 + tx;
        gTh[o] = h;
        gTl[o] = (__bf16)(v - (float)h);
    }
}

// effective weight, transposed [cout][KP], padded slots (cpad), hi plane only
__global__ __launch_bounds__(256) void build_weffT(
    const float* __restrict__ W, __bf16* __restrict__ dh,
    int c, int cpad, int cout, int KP)
{
    int idx = blockIdx.x * 256 + threadIdx.x;
    if (idx >= cout * KP) return;
    int o = idx / KP, kk = idx - o * KP;
    float v = 0.f;
    if (kk < 5 * cpad) {
        int s = kk / cpad;
        int i = kk - s * cpad;
        if (i < c) {
            if      (s == 0) v = W[(size_t)(0 * c + i) * cout + o] + W[(size_t)(3 * c + i) * cout + o]
                               - W[(size_t)(2 * c + i) * cout + o] - W[(size_t)(5 * c + i) * cout + o];
            else if (s == 1) v = W[(size_t)(1 * c + i) * cout + o];
            else if (s == 2) v = W[(size_t)(4 * c + i) * cout + o];
            else if (s == 3) v = 2.f * W[(size_t)(2 * c + i) * cout + o];
            else             v = 2.f * W[(size_t)(5 * c + i) * cout + o];
        }
    }
    dh[idx] = (__bf16)v;
}

// attention; writes htc (=dh0 state) AND dh1 copy (fused init)
__global__ __launch_bounds__(64) void attention(
    const float* __restrict__ h, const float* __restrict__ Wq,
    const float* __restrict__ Mem, float* __restrict__ htc, float* __restrict__ htc2)
{
    int r = blockIdx.x;
    int j = threadIdx.x;
    __shared__ float hr[64], q[64], sc[20];
    hr[j] = h[(size_t)r * 64 + j];
    __syncthreads();
    float acc = 0.f;
#pragma unroll 8
    for (int i = 0; i < 64; ++i) acc += hr[i] * Wq[i * 64 + j];
    q[j] = acc;
    __syncthreads();
    if (j < 20) {
        float a = 0.f;
#pragma unroll 8
        for (int d = 0; d < 64; ++d) a += q[d] * Mem[j * 64 + d];
        sc[j] = a;
    }
    __syncthreads();
    if (j == 0) {
        float mx = sc[0];
        for (int m = 1; m < 20; ++m) mx = fmaxf(mx, sc[m]);
        float s = 0.f;
        for (int m = 0; m < 20; ++m) { sc[m] = expf(sc[m] - mx); s += sc[m]; }
        float inv = 1.f / s;
        for (int m = 0; m < 20; ++m) sc[m] *= inv;
    }
    __syncthreads();
    float v = 0.f;
#pragma unroll
    for (int m = 0; m < 20; ++m) v += sc[m] * Mem[m * 64 + j];
    htc[(size_t)r * 128 + j] = hr[j];
    htc[(size_t)r * 128 + 64 + j] = v;
    htc2[(size_t)r * 128 + j] = hr[j];
    htc2[(size_t)r * 128 + 64 + j] = v;
}

__global__ __launch_bounds__(256) void proj_out(
    const float* __restrict__ h1, const float* __restrict__ pw, const float* __restrict__ pb,
    float* __restrict__ go, float* __restrict__ out, int t)
{
    int r = blockIdx.x * 256 + threadIdx.x;
    if (r >= NB) return;
    float acc = pb[0];
    const float* hr = h1 + (size_t)r * 128;
#pragma unroll 8
    for (int i = 0; i < 128; ++i) acc += hr[i] * pw[i];
    go[r] = acc;
    int n = r >> 4, b = r & 15;
    out[((size_t)b * TT + t) * NNODE + n] = acc;
}

// ---------------------------------------------------------------------------
// host
// ---------------------------------------------------------------------------
extern "C" void kernel_launch(void* const* d_in, const int* in_sizes, int n_in,
                              void* d_out, int out_size, void* d_ws, size_t ws_size,
                              hipStream_t stream)
{
    const float* x      = (const float*)d_in[0];
    const float* y_cov  = (const float*)d_in[1];
    const float* Memory = (const float*)d_in[2];
    const float* Wq     = (const float*)d_in[3];
    const float* We1    = (const float*)d_in[4];
    const float* We2    = (const float*)d_in[5];
    const float* e0gw = (const float*)d_in[6];  const float* e0gb = (const float*)d_in[7];
    const float* e0uw = (const float*)d_in[8];  const float* e0ub = (const float*)d_in[9];
    const float* e1gw = (const float*)d_in[10]; const float* e1gb = (const float*)d_in[11];
    const float* e1uw = (const float*)d_in[12]; const float* e1ub = (const float*)d_in[13];
    const float* d0gw = (const float*)d_in[14]; const float* d0gb = (const float*)d_in[15];
    const float* d0uw = (const float*)d_in[16]; const float* d0ub = (const float*)d_in[17];
    const float* d1gw = (const float*)d_in[18]; const float* d1gb = (const float*)d_in[19];
    const float* d1uw = (const float*)d_in[20]; const float* d1ub = (const float*)d_in[21];
    const float* proj_w = (const float*)d_in[22];
    const float* proj_b = (const float*)d_in[23];
    float* out = (float*)d_out;
    (void)in_sizes; (void)n_in; (void)out_size; (void)ws_size;

    char* wsb = (char*)d_ws;
    size_t off = 0;
    auto alloc = [&](size_t bytes) -> void* {
        void* p = wsb + off;
        off += (bytes + 255) & ~(size_t)255;
        return p;
    };

    float*  gf    = (float*) alloc(2048L * 1024 * 4);
    __bf16* gquad = (__bf16*)alloc(4096L * 1024 * 2);   // g1|g2|G2_1|G2_2 (hi)
    __bf16* gsL   = (__bf16*)alloc(2048L * 1024 * 2);
    __bf16* gTh   = (__bf16*)alloc(2048L * 1024 * 2);
    __bf16* gTl   = (__bf16*)alloc(2048L * 1024 * 2);
    float*  ne1   = (float*) alloc(65536L * 4);
    float*  ne2   = (float*) alloc(65536L * 4);
    auto allocWT = [&](int cout, int KP) {
        return (__bf16*)alloc((size_t)cout * KP * 2);
    };
    __bf16* wE0g = allocWT(128, 384);   __bf16* wE0u = allocWT(64, 384);
    __bf16* wE1g = allocWT(128, 640);   __bf16* wE1u = allocWT(64, 640);
    __bf16* wD0g = allocWT(256, 704);   __bf16* wD0u = allocWT(128, 704);
    __bf16* wD1g = allocWT(256, 1280);  __bf16* wD1u = allocWT(128, 1280);
    __bf16* RMh = (__bf16*)alloc((size_t)NB * 1280 * 2);
    __bf16* Th  = (__bf16*)alloc((size_t)4096 * 1024 * 2);
    float* zr  = (float*)alloc((size_t)NB * 256 * 4);
    float* h0e = (float*)alloc((size_t)NB * 64 * 4);
    float* h1e = (float*)alloc((size_t)NB * 64 * 4);
    float* dh0 = (float*)alloc((size_t)NB * 128 * 4);
    float* dh1 = (float*)alloc((size_t)NB * 128 * 4);
    float* gob = (float*)alloc((size_t)NB * 4);

    // ---- setup ----
    compute_ne<<<cdiv(2 * 65536, 256), 256, 0, stream>>>(We1, We2, Memory, ne1, ne2);
    build_g<<<2048, 256, 0, stream>>>(ne1, ne2, gf);
    g_split<<<cdiv(2048 * 1024, 256), 256, 0, stream>>>(gf, gquad, gsL);
    {
        dim3 gt(32, 32, 2);
        gT_kern<<<gt, 256, 0, stream>>>(gf, gTh, gTl);
        // G2_z = g_z @ g_z  (3-pass split), -> gquad rows 2048 + z*1024
        dim3 gg(8, 8, 2);
        mm_kern<128, 128, 64, 2, 2, 0><<<gg, 256, 0, stream>>>(
            gquad, gsL, 1024, (long)1024 * 1024,
            gTh, gTl, (long)1024 * 1024, 1024,
            1024, 16, 16, 1 << 30,
            gquad + (size_t)2048 * 1024, nullptr, 1024, (long)1024 * 1024,
            0, 0, nullptr, nullptr, nullptr);
    }
    build_weffT<<<cdiv(128 * 384, 256), 256, 0, stream>>>(e0gw, wE0g, 65, 72, 128, 384);
    build_weffT<<<cdiv(64 * 384, 256), 256, 0, stream>>>(e0uw, wE0u, 65, 72, 64, 384);
    build_weffT<<<cdiv(128 * 640, 256), 256, 0, stream>>>(e1gw, wE1g, 128, 128, 128, 640);
    build_weffT<<<cdiv(64 * 640, 256), 256, 0, stream>>>(e1uw, wE1u, 128, 128, 64, 640);
    build_weffT<<<cdiv(256 * 704, 256), 256, 0, stream>>>(d0gw, wD0g, 130, 136, 256, 704);
    build_weffT<<<cdiv(128 * 704, 256), 256, 0, stream>>>(d0uw, wD0u, 130, 136, 128, 704);
    build_weffT<<<cdiv(256 * 1280, 256), 256, 0, stream>>>(d1gw, wD1g, 256, 256, 256, 1280);
    build_weffT<<<cdiv(128 * 1280, 256), 256, 0, stream>>>(d1uw, wD1u, 256, 256, 128, 1280);
    hipMemsetAsync(h0e, 0, (size_t)NB * 64 * 4 * 2, stream);   // h0e + h1e adjacent

    // cell core: hop (EPI2, RM direct) + pure-bf16 weight GEMM (PA=PB=1, BM=64)
    auto agcn_core = [&](int c, int cpad, int cin2, int KP,
                         const __bf16* wt, const float* bias, int cout, int epi,
                         float* zrOrOut, float* hptr) {
        int Moff = 16 * cin2, Mv = 16 * c - Moff;
        dim3 gh(32, cdiv(Mv, 128), 1);
        mm_kern<128, 128, 64, 1, 1, 2><<<gh, 256, 0, stream>>>(
            Th + (size_t)Moff * 1024, Th + (size_t)Moff * 1024, 1024, 0,
            gquad, gquad, 0, 1024,
            Mv, 16, 0, 0,
            RMh, nullptr, KP, 0, cpad, Moff,
            nullptr, nullptr, nullptr);
        if (epi == 1) {
            if (cout == 256) {
                dim3 gw(2, 256, 1);
                mm_kern<64, 128, 64, 1, 1, 1><<<gw, 256, 0, stream>>>(
                    RMh, RMh, KP, 0, wt, wt, 0, KP, NB, KP / 64, 0, 0,
                    nullptr, zrOrOut, cout, 0, 0, 0, bias, nullptr, nullptr);
            } else {
                dim3 gw(2, 256, 1);
                mm_kern<64, 64, 64, 1, 1, 1><<<gw, 256, 0, stream>>>(
                    RMh, RMh, KP, 0, wt, wt, 0, KP, NB, KP / 64, 0, 0,
                    nullptr, zrOrOut, cout, 0, 0, 0, bias, nullptr, nullptr);
            }
        } else {
            if (cout == 64) {
                dim3 gw(1, 256, 1);
                mm_kern<64, 64, 64, 1, 1, 3><<<gw, 256, 0, stream>>>(
                    RMh, RMh, KP, 0, wt, wt, 0, KP, NB, KP / 64, 0, 0,
                    nullptr, nullptr, cout, 0, 0, 0, bias, zrOrOut, hptr);
            } else {
                dim3 gw(2, 256, 1);
                mm_kern<64, 64, 64, 1, 1, 3><<<gw, 256, 0, stream>>>(
                    RMh, RMh, KP, 0, wt, wt, 0, KP, NB, KP / 64, 0, 0,
                    nullptr, nullptr, cout, 0, 0, 0, bias, zrOrOut, hptr);
            }
        }
    };

    // ---- encoder ----
    for (int t = 0; t < TT; ++t) {
        xcatT_kern<0><<<dim3(3, 16, 16), 256, 0, stream>>>(RMh, Th, x, nullptr, h0e, nullptr, t, 0, 384);
        agcn_core(65, 72, 0, 384, wE0g, e0gb, 128, 1, zr, nullptr);
        xcatT_kern<1><<<dim3(2, 16, 16), 256, 0, stream>>>(RMh, Th, x, nullptr, h0e, zr, t, 1, 384);
        agcn_core(65, 72, 1, 384, wE0u, e0ub, 64, 3, zr, h0e);
        xcatT_kern<2><<<dim3(4, 16, 16), 256, 0, stream>>>(RMh, Th, h0e, nullptr, h1e, nullptr, t, 0, 640);
        agcn_core(128, 128, 0, 640, wE1g, e1gb, 128, 1, zr, nullptr);
        xcatT_kern<3><<<dim3(2, 16, 16), 256, 0, stream>>>(RMh, Th, h0e, nullptr, h1e, zr, t, 64, 640);
        agcn_core(128, 128, 64, 640, wE1u, e1ub, 64, 3, zr, h1e);
    }

    // ---- memory attention (writes dh0 and dh1) ----
    attention<<<NB, 64, 0, stream>>>(h1e, Wq, Memory, dh0, dh1);
    hipMemsetAsync(gob, 0, (size_t)NB * 4, stream);

    // ---- decoder ----
    for (int t = 0; t < TT; ++t) {
        xcatT_kern<4><<<dim3(5, 16, 16), 256, 0, stream>>>(RMh, Th, gob, y_cov, dh0, nullptr, t, 0, 704);
        agcn_core(130, 136, 0, 704, wD0g, d0gb, 256, 1, zr, nullptr);
        xcatT_kern<5><<<dim3(4, 16, 16), 256, 0, stream>>>(RMh, Th, gob, y_cov, dh0, zr, t, 2, 704);
        agcn_core(130, 136, 2, 704, wD0u, d0ub, 128, 3, zr, dh0);
        xcatT_kern<6><<<dim3(8, 16, 16), 256, 0, stream>>>(RMh, Th, dh0, nullptr, dh1, nullptr, t, 0, 1280);
        agcn_core(256, 256, 0, 1280, wD1g, d1gb, 256, 1, zr, nullptr);
        xcatT_kern<7><<<dim3(4, 16, 16), 256, 0, stream>>>(RMh, Th, dh0, nullptr, dh1, zr, t, 128, 1280);
        agcn_core(256, 256, 128, 1280, wD1u, d1ub, 128, 3, zr, dh1);
        proj_out<<<cdiv(NB, 256), 256, 0, stream>>>(dh1, proj_w, proj_b, gob, out, t);
    }
}